// Round 6
// baseline (850.260 us; speedup 1.0000x reference)
//
#include <hip/hip_runtime.h>
#include <math.h>

#define BB 64
#define SS 21
#define NSAMP 3000
#define HID 500
#define SECN 6
#define NN 2
#define OUTD 128
#define NPROTO 25
#define NCLS 5
#define NHEAD 4
#define BS (BB*SS)          // 1344
#define NSAMPLE (BS*NN)     // 2688

#define C500 (-0.0184206807439523674f)   // -ln(1e4)/500
#define LSCALE 0.00745355992499929898f   // 1/(6*sqrt(500))

// ws float offsets
#define WS_W2HI 5376
#define WS_W2LO 8448
#define WS_W3HI 11520
#define WS_W3LO 23808
#define WS_P3   36096
#define WS_C3   55296
#define WS_XSUM 55424
#define WS_V    727424

typedef __attribute__((ext_vector_type(8))) short short8;
typedef __attribute__((ext_vector_type(4))) float floatx4;

__device__ __forceinline__ short f2bf(float f) {
  unsigned u = __float_as_uint(f);
  u += 0x7FFF + ((u >> 16) & 1);          // RNE to bf16
  return (short)(u >> 16);
}
__device__ __forceinline__ float bf2f(short h) {
  return __uint_as_float(((unsigned)(unsigned short)h) << 16);
}
// lr-clamped shuffles along the pos axis (lr = lane&15)
__device__ __forceinline__ float sdown(float v, int k, int l, int lr) {
  int tgt = (lr + k > 15) ? l : (l + k);
  return __shfl(v, tgt, 64);
}
__device__ __forceinline__ float sup(float v, int k, int l, int lr) {
  int tgt = (lr - k < 0) ? l : (l - k);
  return __shfl(v, tgt, 64);
}

// ---------------- Kernel 0: weight splits + folded-VQ prep (merged) ----------------
__global__ __launch_bounds__(256) void prep_all_kernel(
    const float* __restrict__ w2, const float* __restrict__ w3,
    short* __restrict__ w2hi, short* __restrict__ w2lo,
    short* __restrict__ w3hi, short* __restrict__ w3lo,
    const float* __restrict__ protos, const float* __restrict__ fc2w,
    const float* __restrict__ fcw, const float* __restrict__ fcb,
    const float* __restrict__ fc2b,
    float* __restrict__ P3, float* __restrict__ c3) {
  __shared__ __align__(16) float p2row[256];
  __shared__ float red[256];
  if (blockIdx.x < 120) {
    int idx = blockIdx.x * 256 + threadIdx.x;
    if (idx < 6144) {
      int ic = idx & 31, ck = idx >> 5, k = ck % 3, c = ck / 3;
      float v = w2[c * 96 + ic * 3 + k];
      int dst = c * 96 + k * 32 + ic;
      short hi = f2bf(v);
      short lo = f2bf(v - bf2f(hi));
      w2hi[dst] = hi; w2lo[dst] = lo;
    } else if (idx < 30720) {
      int j = idx - 6144;
      int ic = j & 63, ck = j >> 6, k = ck % 3, c = ck / 3;
      float v = w3[(c * 64 + ic) * 3 + k];
      int dst = c * 192 + k * 64 + ic;
      short hi = f2bf(v);
      short lo = f2bf(v - bf2f(hi));
      w3hi[dst] = hi; w3lo[dst] = lo;
    }
    return;
  }
  const int p = blockIdx.x - 120, j = threadIdx.x;
  {
    const float4* pr = reinterpret_cast<const float4*>(protos + p * 128);
    const float4* wr = reinterpret_cast<const float4*>(fc2w + j * 128);
    float4 a4 = make_float4(0.f, 0.f, 0.f, 0.f);
    for (int c4 = 0; c4 < 32; c4++) {
      float4 a = pr[c4], b = wr[c4];
      a4.x += a.x * b.x; a4.y += a.y * b.y; a4.z += a.z * b.z; a4.w += a.w * b.w;
    }
    float v = (a4.x + a4.y) + (a4.z + a4.w);
    p2row[j] = v;
    float contrib = v * fcb[j];
    if (j < 128) {
      float pv = protos[p * 128 + j];
      contrib += pv * fc2b[j] - 0.5f * pv * pv;
    }
    red[j] = contrib;
  }
  __syncthreads();
  for (int s = 128; s > 0; s >>= 1) {
    if (j < s) red[j] += red[j + s];
    __syncthreads();
  }
  if (j == 0) c3[p] = red[0];
  for (int k = j; k < 768; k += 256) {
    const float4* fr = reinterpret_cast<const float4*>(fcw + k * 256);
    const float4* p2 = reinterpret_cast<const float4*>(p2row);
    float4 a4 = make_float4(0.f, 0.f, 0.f, 0.f);
    for (int j4 = 0; j4 < 64; j4++) {
      float4 a = p2[j4], b = fr[j4];
      a4.x += a.x * b.x; a4.y += a.y * b.y; a4.z += a.z * b.z; a4.w += a.w * b.w;
    }
    P3[p * 768 + k] = (a4.x + a4.y) + (a4.z + a4.w);
  }
}

// ---------------- Kernel 1a: xsum[bs][500] = sum_s x + PE-sum ----------------
__global__ __launch_bounds__(128) void attn_a_kernel(
    const float* __restrict__ x, float* __restrict__ xsum) {
  const int bs = blockIdx.x, t = threadIdx.x;
  if (t >= 125) return;
  const float4* x4 = reinterpret_cast<const float4*>(x) + bs * 750;
  float4 a = x4[t];
#pragma unroll
  for (int s = 1; s < SECN; s++) {
    float4 b = x4[s * 125 + t];
    a.x += b.x; a.y += b.y; a.z += b.z; a.w += b.w;
  }
  float div0 = expf((float)(4 * t) * C500);
  float div1 = expf((float)(4 * t + 2) * C500);
  float s0 = 0.f, c0 = 0.f, s1 = 0.f, c1 = 0.f;
#pragma unroll
  for (int s = 0; s < SECN; s++) {
    float a0 = (float)s * div0, a1 = (float)s * div1;
    s0 += sinf(a0); c0 += cosf(a0);
    s1 += sinf(a1); c1 += cosf(a1);
  }
  a.x += s0; a.y += c0; a.z += s1; a.w += c1;
  reinterpret_cast<float4*>(xsum)[bs * 125 + t] = a;
}

// ---------------- Kernel 1b: ks = xsum@wk ; v[bs][n][500] = wq_n@ks_n ----------------
// MB=4 samples/block, transposed float4 LDS layouts (broadcast b128 reads only)
#define MB 4
__global__ __launch_bounds__(256) void attn_b_kernel(
    const float* __restrict__ xsum, const float* __restrict__ wk,
    const float* __restrict__ wq, float* __restrict__ v) {
  __shared__ __align__(16) float4 xs_t[500];   // [i] -> (m0..m3)
  __shared__ __align__(16) float4 ks_t[256];   // [c] -> (m0..m3)
  const int blk = blockIdx.x, t = threadIdx.x;

  // load + in-register transpose: thread i4 < 125 handles 4 i values
  if (t < 125) {
    float4 f0 = reinterpret_cast<const float4*>(xsum)[(blk * MB + 0) * 125 + t];
    float4 f1 = reinterpret_cast<const float4*>(xsum)[(blk * MB + 1) * 125 + t];
    float4 f2 = reinterpret_cast<const float4*>(xsum)[(blk * MB + 2) * 125 + t];
    float4 f3 = reinterpret_cast<const float4*>(xsum)[(blk * MB + 3) * 125 + t];
    xs_t[4 * t + 0] = make_float4(f0.x, f1.x, f2.x, f3.x);
    xs_t[4 * t + 1] = make_float4(f0.y, f1.y, f2.y, f3.y);
    xs_t[4 * t + 2] = make_float4(f0.z, f1.z, f2.z, f3.z);
    xs_t[4 * t + 3] = make_float4(f0.w, f1.w, f2.w, f3.w);
  }
  __syncthreads();

  // ks phase: thread t owns column t
  {
    float4 a = make_float4(0.f, 0.f, 0.f, 0.f);
    for (int i = 0; i < 500; i++) {
      float w = wk[i * 256 + t];
      float4 xv = xs_t[i];            // broadcast b128
      a.x += xv.x * w; a.y += xv.y * w; a.z += xv.z * w; a.w += xv.w * w;
    }
    ks_t[t] = a;
  }
  __syncthreads();

  // v phase: thread handles h = t and h = t+256 (if < 500); 4 samples each
  {
    int h1 = t + 256;
    bool ok1 = h1 < 500;
    for (int n = 0; n < 2; n++) {
      float4 acc0 = make_float4(0.f, 0.f, 0.f, 0.f);
      float4 acc1 = acc0;
      for (int c4 = 0; c4 < 32; c4++) {
        int c = n * 128 + c4 * 4;
        float4 w0 = *reinterpret_cast<const float4*>(wq + t * 256 + c);
        float4 w1 = ok1 ? *reinterpret_cast<const float4*>(wq + h1 * 256 + c)
                        : make_float4(0.f, 0.f, 0.f, 0.f);
        float4 k0 = ks_t[c + 0], k1 = ks_t[c + 1], k2 = ks_t[c + 2], k3 = ks_t[c + 3];
        acc0.x += w0.x * k0.x + w0.y * k1.x + w0.z * k2.x + w0.w * k3.x;
        acc0.y += w0.x * k0.y + w0.y * k1.y + w0.z * k2.y + w0.w * k3.y;
        acc0.z += w0.x * k0.z + w0.y * k1.z + w0.z * k2.z + w0.w * k3.z;
        acc0.w += w0.x * k0.w + w0.y * k1.w + w0.z * k2.w + w0.w * k3.w;
        acc1.x += w1.x * k0.x + w1.y * k1.x + w1.z * k2.x + w1.w * k3.x;
        acc1.y += w1.x * k0.y + w1.y * k1.y + w1.z * k2.y + w1.w * k3.y;
        acc1.z += w1.x * k0.z + w1.y * k1.z + w1.z * k2.z + w1.w * k3.z;
        acc1.w += w1.x * k0.w + w1.y * k1.w + w1.z * k2.w + w1.w * k3.w;
      }
      const float* a0 = (const float*)&acc0;
      const float* a1 = (const float*)&acc1;
#pragma unroll
      for (int m = 0; m < MB; m++) {
        int base = ((blk * MB + m) * 2 + n) * 500;
        v[base + t] = a0[m];
        if (ok1) v[base + h1] = a1[m];
      }
    }
  }
}

// ---------------- Kernel 1c: logits = (x+pe).v + gumbel -> argmax ----------------
__global__ __launch_bounds__(192) void attn_c_kernel(
    const float* __restrict__ x, const float* __restrict__ v,
    const float* __restrict__ gumbel, int* __restrict__ sec_idx) {
  __shared__ float lgsh[NN][SECN];
  const int bs = blockIdx.x, t = threadIdx.x;
  const int s = t >> 5, lane = t & 31;
  const float4* x4 = reinterpret_cast<const float4*>(x) + bs * 750 + s * 125;
  const float4* v0 = reinterpret_cast<const float4*>(v) + bs * 250;
  const float4* v1 = v0 + 125;
  float a0 = 0.f, a1 = 0.f;
  for (int h4 = lane; h4 < 125; h4 += 32) {
    float4 xv = x4[h4];
    float div0 = expf((float)(4 * h4) * C500);
    float div1 = expf((float)(4 * h4 + 2) * C500);
    float ang0 = (float)s * div0, ang1 = (float)s * div1;
    xv.x += sinf(ang0); xv.y += cosf(ang0);
    xv.z += sinf(ang1); xv.w += cosf(ang1);
    float4 w0 = v0[h4], w1 = v1[h4];
    a0 += xv.x * w0.x + xv.y * w0.y + xv.z * w0.z + xv.w * w0.w;
    a1 += xv.x * w1.x + xv.y * w1.y + xv.z * w1.z + xv.w * w1.w;
  }
#pragma unroll
  for (int m = 16; m >= 1; m >>= 1) {
    a0 += __shfl_xor(a0, m);
    a1 += __shfl_xor(a1, m);
  }
  if (lane == 0) {
    lgsh[0][s] = a0 * LSCALE + gumbel[(bs * 2 + 0) * SECN + s];
    lgsh[1][s] = a1 * LSCALE + gumbel[(bs * 2 + 1) * SECN + s];
  }
  __syncthreads();
  if (t < 2) {
    int best = 0; float bv = lgsh[t][0];
    for (int i = 1; i < SECN; i++) {
      float q = lgsh[t][i];
      if (q > bv) { bv = q; best = i; }
    }
    sec_idx[bs * 2 + t] = best;
  }
}

// ---------------- Kernel 2: conv encoder (MFMA, in-register pooling) + VQ ----------------
// LDS layout:
//  [0,10400)      act1_hi [130][40]   | featsh f32[768] + sc25 (alias, ph5+)
//  [10400,20800)  act1_lo
//  [20800,25696)  act2p_hi [34][72]
//  [25696,30592)  act2p_lo
//  [30592,32640)  in0p f32[512]  | Lbuf f32[8][64] (alias)
//  [32640,34688)  Rbuf f32[8][64]
#define CONV_LDS 34688
__global__ __launch_bounds__(256, 4) void conv_kernel(
    const float* __restrict__ x, const int* __restrict__ sec_idx,
    const float* __restrict__ w1, const float* __restrict__ b1,
    const float* __restrict__ bn1g, const float* __restrict__ bn1b,
    const short* __restrict__ w2hi, const short* __restrict__ w2lo,
    const float* __restrict__ b2,
    const float* __restrict__ bn2g, const float* __restrict__ bn2b,
    const short* __restrict__ w3hi, const short* __restrict__ w3lo,
    const float* __restrict__ b3,
    const float* __restrict__ bn3g, const float* __restrict__ bn3b,
    const float* __restrict__ P3, const float* __restrict__ c3,
    int* __restrict__ proto_idx) {
  __shared__ __align__(16) char smem[CONV_LDS];
  short* act1_hi  = (short*)smem;               // [130][40]
  short* act1_lo  = (short*)(smem + 10400);
  short* act2p_hi = (short*)(smem + 20800);     // [34][72]
  short* act2p_lo = (short*)(smem + 25696);
  float* in0p     = (float*)(smem + 30592);     // [512]
  float* Lbuf     = (float*)(smem + 30592);     // [8][64] (alias in0p)
  float* Rbuf     = (float*)(smem + 32640);     // [8][64]
  float* featsh   = (float*)smem;               // [768] alias act1 (ph5+)
  float* sc25     = (float*)(smem + 3072);      // [25]

  const int sample = blockIdx.x;
  const int t = threadIdx.x;
  const int bsIdx = sample >> 1;
  const float bnscale = rsqrtf(1.0f + 1e-5f);
  const int wv = t >> 6, l = t & 63, lr = l & 15, lg2 = l >> 4;

  // ---- phase 1: load x section; zero act1 + act2p pad rows ----
  {
    int sec = sec_idx[sample];
    const float* src = &x[bsIdx * NSAMP + sec * HID];
    for (int i = t; i < 512; i += 256) in0p[i] = (i >= 1 && i <= 500) ? src[i - 1] : 0.f;
    if (t < 200) {
      int r = t / 40; r = (r == 0) ? 0 : 125 + r;   // rows 0,126..129
      int idx = r * 40 + t % 40;
      act1_hi[idx] = 0; act1_lo[idx] = 0;
    }
    for (int i = t; i < 648; i += 256) {            // act2p rows 0, 26..33
      int r = i / 72; r = (r == 0) ? 0 : 25 + r;
      int idx = r * 72 + i % 72;
      act2p_hi[idx] = 0; act2p_lo[idx] = 0;
    }
  }
  __syncthreads();

  // ---- phase 2: conv1 + relu + pool4 + bn -> act1 hi/lo bf16 [pos+1][ic] ----
  {
    int ic = t & 31;
    float w0 = w1[ic * 3], w1v = w1[ic * 3 + 1], w2v = w1[ic * 3 + 2];
    float bb = b1[ic];
    float g = bn1g[ic] * bnscale, be = bn1b[ic];
    for (int p = t >> 5; p < 125; p += 8) {
      int base = 4 * p;
      float xm1 = in0p[base], x0 = in0p[base + 1], x1 = in0p[base + 2],
            x2 = in0p[base + 3], x3 = in0p[base + 4], x4 = in0p[base + 5];
      float a0 = bb + w0 * xm1 + w1v * x0 + w2v * x1;
      float a1 = bb + w0 * x0  + w1v * x1 + w2v * x2;
      float a2 = bb + w0 * x1  + w1v * x2 + w2v * x3;
      float a3 = bb + w0 * x2  + w1v * x3 + w2v * x4;
      float m = fmaxf(fmaxf(fmaxf(fmaxf(a0, a1), a2), a3), 0.f);
      float v = m * g + be;
      short hi = f2bf(v);
      short lo = f2bf(v - bf2f(hi));
      act1_hi[(p + 1) * 40 + ic] = hi;
      act1_lo[(p + 1) * 40 + ic] = lo;
    }
  }
  __syncthreads();

  // ---- phase 3: conv2 MFMA + in-register pool5 epilogue ----
  {
    floatx4 acc[4][2];
#pragma unroll
    for (int m = 0; m < 4; m++)
#pragma unroll
      for (int nn = 0; nn < 2; nn++) acc[m][nn] = (floatx4){0.f, 0.f, 0.f, 0.f};
#pragma unroll
    for (int s = 0; s < 3; s++) {
      short8 Ah[4], Al[4], Bh[2], Bl[2];
#pragma unroll
      for (int m = 0; m < 4; m++) {
        int aoff = (m * 16 + lr) * 96 + s * 32 + lg2 * 8;
        Ah[m] = *(const short8*)(w2hi + aoff);
        Al[m] = *(const short8*)(w2lo + aoff);
      }
#pragma unroll
      for (int nn = 0; nn < 2; nn++) {
        int boff = ((2 * wv + nn) * 16 + lr + s) * 40 + lg2 * 8;
        Bh[nn] = *(const short8*)(act1_hi + boff);
        Bl[nn] = *(const short8*)(act1_lo + boff);
      }
#pragma unroll
      for (int m = 0; m < 4; m++)
#pragma unroll
        for (int nn = 0; nn < 2; nn++) {
          acc[m][nn] = __builtin_amdgcn_mfma_f32_16x16x32_bf16(Ah[m], Bh[nn], acc[m][nn], 0, 0, 0);
          acc[m][nn] = __builtin_amdgcn_mfma_f32_16x16x32_bf16(Ah[m], Bl[nn], acc[m][nn], 0, 0, 0);
          acc[m][nn] = __builtin_amdgcn_mfma_f32_16x16x32_bf16(Al[m], Bh[nn], acc[m][nn], 0, 0, 0);
        }
    }
    // epilogue: window-of-5 max along pos (= lr within 16-pos tiles)
#pragma unroll
    for (int nn = 0; nn < 2; nn++) {
      int tile = 2 * wv + nn;
      int pos = tile * 16 + lr;
      int r5 = pos % 5;
#pragma unroll
      for (int m = 0; m < 4; m++)
#pragma unroll
        for (int j = 0; j < 4; j++) {
          float vv = acc[m][nn][j];
          float m1 = fmaxf(vv, sdown(vv, 1, l, lr));
          float m4 = fmaxf(m1, sdown(m1, 2, l, lr));
          float m5 = fmaxf(m4, sdown(vv, 4, l, lr));   // max over lr..min(lr+4,15)
          float p1 = fmaxf(vv, sup(vv, 1, l, lr));
          float p2 = fmaxf(p1, sup(p1, 2, l, lr));
          float p4 = fmaxf(p2, sup(vv, 4, l, lr));     // max over max(lr-4,0)..lr
          int ch = m * 16 + lg2 * 4 + j;
          if (r5 == 0) {
            if (lr <= 11) {            // full window inside tile
              int w = pos / 5;
              float val = fmaxf(m5 + b2[ch], 0.f) * (bn2g[ch] * bnscale) + bn2b[ch];
              short hi = f2bf(val);
              short lo = f2bf(val - bf2f(hi));
              act2p_hi[(w + 1) * 72 + ch] = hi;
              act2p_lo[(w + 1) * 72 + ch] = lo;
            } else {
              Lbuf[tile * 64 + ch] = m5;   // suffix max of spanning window
            }
          }
          if (r5 == 4 && lr <= 3) {
            Rbuf[tile * 64 + ch] = p4;     // prefix max of spanning window
          }
        }
    }
  }
  __syncthreads();

  // ---- phase 3b: combine 6 spanning windows ----
  {
    const int wl[6] = {3, 6, 9, 12, 19, 22};
    for (int q = t; q < 384; q += 256) {
      int wi = q >> 6, ch = q & 63;
      int w = wl[wi], lt = (5 * w) >> 4;
      float M = fmaxf(Lbuf[lt * 64 + ch], Rbuf[(lt + 1) * 64 + ch]);
      float val = fmaxf(M + b2[ch], 0.f) * (bn2g[ch] * bnscale) + bn2b[ch];
      short hi = f2bf(val);
      short lo = f2bf(val - bf2f(hi));
      act2p_hi[(w + 1) * 72 + ch] = hi;
      act2p_lo[(w + 1) * 72 + ch] = lo;
    }
  }
  __syncthreads();

  // ---- phase 5: conv3 MFMA + in-register pool4 -> featsh ----
  {
    floatx4 acc[2][2];
#pragma unroll
    for (int mm = 0; mm < 2; mm++)
#pragma unroll
      for (int nn = 0; nn < 2; nn++) acc[mm][nn] = (floatx4){0.f, 0.f, 0.f, 0.f};
#pragma unroll
    for (int s = 0; s < 6; s++) {
      short8 Ah[2], Al[2], Bh[2], Bl[2];
#pragma unroll
      for (int mm = 0; mm < 2; mm++) {
        int aoff = ((wv * 2 + mm) * 16 + lr) * 192 + s * 32 + lg2 * 8;
        Ah[mm] = *(const short8*)(w3hi + aoff);
        Al[mm] = *(const short8*)(w3lo + aoff);
      }
#pragma unroll
      for (int nn = 0; nn < 2; nn++) {
        int boff = (nn * 16 + lr + (s >> 1)) * 72 + (s & 1) * 32 + lg2 * 8;
        Bh[nn] = *(const short8*)(act2p_hi + boff);
        Bl[nn] = *(const short8*)(act2p_lo + boff);
      }
#pragma unroll
      for (int mm = 0; mm < 2; mm++)
#pragma unroll
        for (int nn = 0; nn < 2; nn++) {
          acc[mm][nn] = __builtin_amdgcn_mfma_f32_16x16x32_bf16(Ah[mm], Bh[nn], acc[mm][nn], 0, 0, 0);
          acc[mm][nn] = __builtin_amdgcn_mfma_f32_16x16x32_bf16(Ah[mm], Bl[nn], acc[mm][nn], 0, 0, 0);
          acc[mm][nn] = __builtin_amdgcn_mfma_f32_16x16x32_bf16(Al[mm], Bh[nn], acc[mm][nn], 0, 0, 0);
        }
    }
    __syncthreads();   // act1 region now reused as featsh
    // pool4: windows align with lr groups of 4
#pragma unroll
    for (int nn = 0; nn < 2; nn++) {
      int pos = nn * 16 + lr;
#pragma unroll
      for (int mm = 0; mm < 2; mm++)
#pragma unroll
        for (int j = 0; j < 4; j++) {
          float vv = acc[mm][nn][j];
          float g1 = fmaxf(vv, __shfl_xor(vv, 1, 64));
          float g2 = fmaxf(g1, __shfl_xor(g1, 2, 64));
          if ((lr & 3) == 0 && pos < 24) {
            int pw = pos >> 2;
            int ch = (wv * 2 + mm) * 16 + lg2 * 4 + j;
            float val = fmaxf(g2 + b3[ch], 0.f) * (bn3g[ch] * bnscale) + bn3b[ch];
            featsh[ch * 6 + pw] = val;
          }
        }
    }
  }
  __syncthreads();

  // ---- phase 7: folded VQ scores + argmax -> proto_idx ----
  if (t < NPROTO * 8) {
    int p = t >> 3, part = t & 7;
    const float4* pr = reinterpret_cast<const float4*>(P3 + p * 768 + part * 96);
    const float4* fr = reinterpret_cast<const float4*>(featsh + part * 96);
    float4 a4 = make_float4(0.f, 0.f, 0.f, 0.f);
#pragma unroll
    for (int i = 0; i < 24; i++) {
      float4 w = pr[i], f = fr[i];
      a4.x += w.x * f.x; a4.y += w.y * f.y; a4.z += w.z * f.z; a4.w += w.w * f.w;
    }
    float a = (a4.x + a4.y) + (a4.z + a4.w);
    a += __shfl_xor(a, 1);
    a += __shfl_xor(a, 2);
    a += __shfl_xor(a, 4);
    if (part == 0) sc25[p] = a + c3[p];
  }
  __syncthreads();
  if (t == 0) {
    int best = 0; float bv = sc25[0];
    for (int i = 1; i < NPROTO; i++) {
      float v = sc25[i];
      if (v > bv) { bv = v; best = i; }
    }
    proto_idx[sample] = best;
  }
}

// ---------------- Kernel 3: sequence transformer + classifier ----------------
__global__ __launch_bounds__(512) void seq_kernel(
    const int* __restrict__ proto_idx, const float* __restrict__ protos,
    const float* __restrict__ inw, const float* __restrict__ inb,
    const float* __restrict__ outw, const float* __restrict__ outb,
    const float* __restrict__ ln1g, const float* __restrict__ ln1b,
    const float* __restrict__ ln2g, const float* __restrict__ ln2b,
    const float* __restrict__ ff1w, const float* __restrict__ ff1b,
    const float* __restrict__ ff2w, const float* __restrict__ ff2b,
    const float* __restrict__ clfw, const float* __restrict__ clfb,
    float* __restrict__ out) {
  __shared__ __align__(16) float hsh[SS * OUTD];
  __shared__ __align__(16) float big[SS * 3 * OUTD];
  __shared__ __align__(16) float sc[NHEAD * SS * SS];
  __shared__ __align__(16) float ctx[SS * OUTD];
  __shared__ float rowm[SS], rowv[SS];

  const int b = blockIdx.x;
  const int t = threadIdx.x;

  for (int o = t; o < SS * OUTD; o += 512) {
    int s = o >> 7, d = o & 127;
    int i0 = proto_idx[(b * SS + s) * 2];
    int i1 = proto_idx[(b * SS + s) * 2 + 1];
    float pc = 0.5f * (protos[i0 * OUTD + d] + protos[i1 * OUTD + d]);
    int i = d >> 1;
    float div = expf((float)(2 * i) * -0.07195578415606439f);
    float ang = (float)s * div;
    float pe = (d & 1) ? cosf(ang) : sinf(ang);
    hsh[o] = pc + pe;
  }
  __syncthreads();

  for (int o = t; o < SS * 384; o += 512) {
    int s = o / 384, j = o % 384;
    float4 a4 = make_float4(0.f, 0.f, 0.f, 0.f);
    const float4* hr = reinterpret_cast<const float4*>(&hsh[s * OUTD]);
    for (int d4 = 0; d4 < 32; d4++) {
      float4 h4 = hr[d4];
      int d = d4 * 4;
      a4.x += h4.x * inw[(d + 0) * 384 + j];
      a4.y += h4.y * inw[(d + 1) * 384 + j];
      a4.z += h4.z * inw[(d + 2) * 384 + j];
      a4.w += h4.w * inw[(d + 3) * 384 + j];
    }
    big[o] = inb[j] + ((a4.x + a4.y) + (a4.z + a4.w));
  }
  __syncthreads();

  for (int o = t; o < NHEAD * SS * SS; o += 512) {
    int hd = o / (SS * SS), r = o % (SS * SS), qs = r / SS, ks = r % SS;
    const float4* qp = reinterpret_cast<const float4*>(&big[qs * 384 + hd * 32]);
    const float4* kp = reinterpret_cast<const float4*>(&big[ks * 384 + 128 + hd * 32]);
    float4 a4 = make_float4(0.f, 0.f, 0.f, 0.f);
#pragma unroll
    for (int d4 = 0; d4 < 8; d4++) {
      float4 q4 = qp[d4], k4 = kp[d4];
      a4.x += q4.x * k4.x; a4.y += q4.y * k4.y; a4.z += q4.z * k4.z; a4.w += q4.w * k4.w;
    }
    sc[o] = ((a4.x + a4.y) + (a4.z + a4.w)) * 0.17677669529663689f;
  }
  __syncthreads();
  for (int r = t; r < NHEAD * SS; r += 512) {
    float* row = &sc[r * SS];
    float mx = row[0];
    for (int i = 1; i < SS; i++) mx = fmaxf(mx, row[i]);
    float sum = 0.f;
    for (int i = 0; i < SS; i++) { float e = expf(row[i] - mx); row[i] = e; sum += e; }
    float inv = 1.f / sum;
    for (int i = 0; i < SS; i++) row[i] *= inv;
  }
  __syncthreads();
  for (int o = t; o < SS * OUTD; o += 512) {
    int qs = o >> 7, d = o & 127, hd = d >> 5, dd = d & 31;
    const float* srow = &sc[(hd * SS + qs) * SS];
    float a = 0.f;
    for (int ks = 0; ks < SS; ks++) a += srow[ks] * big[ks * 384 + 256 + hd * 32 + dd];
    ctx[o] = a;
  }
  __syncthreads();
  float* tmp = big;
  for (int o = t; o < SS * OUTD; o += 512) {
    int s = o >> 7, d = o & 127;
    float4 a4 = make_float4(0.f, 0.f, 0.f, 0.f);
    const float4* cr = reinterpret_cast<const float4*>(&ctx[s * OUTD]);
    for (int e4 = 0; e4 < 32; e4++) {
      float4 c4 = cr[e4];
      int e = e4 * 4;
      a4.x += c4.x * outw[(e + 0) * OUTD + d];
      a4.y += c4.y * outw[(e + 1) * OUTD + d];
      a4.z += c4.z * outw[(e + 2) * OUTD + d];
      a4.w += c4.w * outw[(e + 3) * OUTD + d];
    }
    tmp[o] = hsh[o] + outb[d] + ((a4.x + a4.y) + (a4.z + a4.w));
  }
  __syncthreads();
  if (t < SS) {
    const float4* r4 = reinterpret_cast<const float4*>(&tmp[t * OUTD]);
    float4 m4 = make_float4(0.f, 0.f, 0.f, 0.f);
    for (int d4 = 0; d4 < 32; d4++) {
      float4 v = r4[d4];
      m4.x += v.x; m4.y += v.y; m4.z += v.z; m4.w += v.w;
    }
    float m = ((m4.x + m4.y) + (m4.z + m4.w)) * (1.0f / OUTD);
    float4 v4 = make_float4(0.f, 0.f, 0.f, 0.f);
    for (int d4 = 0; d4 < 32; d4++) {
      float4 v = r4[d4];
      float ux = v.x - m, uy = v.y - m, uz = v.z - m, uw = v.w - m;
      v4.x += ux * ux; v4.y += uy * uy; v4.z += uz * uz; v4.w += uw * uw;
    }
    float var = ((v4.x + v4.y) + (v4.z + v4.w)) * (1.0f / OUTD);
    rowm[t] = m; rowv[t] = rsqrtf(var + 1e-5f);
  }
  __syncthreads();
  for (int o = t; o < SS * OUTD; o += 512) {
    int s = o >> 7, d = o & 127;
    hsh[o] = (tmp[o] - rowm[s]) * rowv[s] * ln1g[d] + ln1b[d];
  }
  __syncthreads();
  for (int o = t; o < SS * OUTD; o += 512) {
    int s = o >> 7, d = o & 127;
    float4 a4 = make_float4(0.f, 0.f, 0.f, 0.f);
    const float4* hr = reinterpret_cast<const float4*>(&hsh[s * OUTD]);
    for (int e4 = 0; e4 < 32; e4++) {
      float4 h4 = hr[e4];
      int e = e4 * 4;
      a4.x += h4.x * ff1w[(e + 0) * OUTD + d];
      a4.y += h4.y * ff1w[(e + 1) * OUTD + d];
      a4.z += h4.z * ff1w[(e + 2) * OUTD + d];
      a4.w += h4.w * ff1w[(e + 3) * OUTD + d];
    }
    ctx[o] = fmaxf(ff1b[d] + ((a4.x + a4.y) + (a4.z + a4.w)), 0.f);
  }
  __syncthreads();
  for (int o = t; o < SS * OUTD; o += 512) {
    int s = o >> 7, d = o & 127;
    float4 a4 = make_float4(0.f, 0.f, 0.f, 0.f);
    const float4* cr = reinterpret_cast<const float4*>(&ctx[s * OUTD]);
    for (int e4 = 0; e4 < 32; e4++) {
      float4 c4 = cr[e4];
      int e = e4 * 4;
      a4.x += c4.x * ff2w[(e + 0) * OUTD + d];
      a4.y += c4.y * ff2w[(e + 1) * OUTD + d];
      a4.z += c4.z * ff2w[(e + 2) * OUTD + d];
      a4.w += c4.w * ff2w[(e + 3) * OUTD + d];
    }
    tmp[o] = hsh[o] + ff2b[d] + ((a4.x + a4.y) + (a4.z + a4.w));
  }
  __syncthreads();
  if (t < SS) {
    const float4* r4 = reinterpret_cast<const float4*>(&tmp[t * OUTD]);
    float4 m4 = make_float4(0.f, 0.f, 0.f, 0.f);
    for (int d4 = 0; d4 < 32; d4++) {
      float4 v = r4[d4];
      m4.x += v.x; m4.y += v.y; m4.z += v.z; m4.w += v.w;
    }
    float m = ((m4.x + m4.y) + (m4.z + m4.w)) * (1.0f / OUTD);
    float4 v4 = make_float4(0.f, 0.f, 0.f, 0.f);
    for (int d4 = 0; d4 < 32; d4++) {
      float4 v = r4[d4];
      float ux = v.x - m, uy = v.y - m, uz = v.z - m, uw = v.w - m;
      v4.x += ux * ux; v4.y += uy * uy; v4.z += uz * uz; v4.w += uw * uw;
    }
    float var = ((v4.x + v4.y) + (v4.z + v4.w)) * (1.0f / OUTD);
    rowm[t] = m; rowv[t] = rsqrtf(var + 1e-5f);
  }
  __syncthreads();
  for (int o = t; o < SS * OUTD; o += 512) {
    int s = o >> 7, d = o & 127;
    hsh[o] = (tmp[o] - rowm[s]) * rowv[s] * ln2g[d] + ln2b[d];
  }
  __syncthreads();
  for (int o = t; o < SS * NCLS; o += 512) {
    int s = o / NCLS, c = o % NCLS;
    float4 a4 = make_float4(0.f, 0.f, 0.f, 0.f);
    const float4* hr = reinterpret_cast<const float4*>(&hsh[s * OUTD]);
    for (int d4 = 0; d4 < 32; d4++) {
      float4 h4 = hr[d4];
      int d = d4 * 4;
      a4.x += h4.x * clfw[(d + 0) * NCLS + c];
      a4.y += h4.y * clfw[(d + 1) * NCLS + c];
      a4.z += h4.z * clfw[(d + 2) * NCLS + c];
      a4.w += h4.w * clfw[(d + 3) * NCLS + c];
    }
    out[(b * SS + s) * NCLS + c] = clfb[c] + ((a4.x + a4.y) + (a4.z + a4.w));
  }
}

extern "C" void kernel_launch(void* const* d_in, const int* in_sizes, int n_in,
                              void* d_out, int out_size, void* d_ws, size_t ws_size,
                              hipStream_t stream) {
  const float* x     = (const float*)d_in[0];
  const float* gum   = (const float*)d_in[1];
  const float* wq    = (const float*)d_in[2];
  const float* wk    = (const float*)d_in[3];
  const float* w1    = (const float*)d_in[4];
  const float* b1    = (const float*)d_in[5];
  const float* bn1g  = (const float*)d_in[6];
  const float* bn1b  = (const float*)d_in[7];
  const float* w2    = (const float*)d_in[8];
  const float* b2    = (const float*)d_in[9];
  const float* bn2g  = (const float*)d_in[10];
  const float* bn2b  = (const float*)d_in[11];
  const float* w3    = (const float*)d_in[12];
  const float* b3    = (const float*)d_in[13];
  const float* bn3g  = (const float*)d_in[14];
  const float* bn3b  = (const float*)d_in[15];
  const float* fcw   = (const float*)d_in[16];
  const float* fcb   = (const float*)d_in[17];
  const float* fc2w  = (const float*)d_in[18];
  const float* fc2b  = (const float*)d_in[19];
  const float* prot  = (const float*)d_in[20];
  const float* inw   = (const float*)d_in[21];
  const float* inb   = (const float*)d_in[22];
  const float* outw  = (const float*)d_in[23];
  const float* outb  = (const float*)d_in[24];
  const float* ln1g  = (const float*)d_in[25];
  const float* ln1b  = (const float*)d_in[26];
  const float* ln2g  = (const float*)d_in[27];
  const float* ln2b  = (const float*)d_in[28];
  const float* ff1w  = (const float*)d_in[29];
  const float* ff1b  = (const float*)d_in[30];
  const float* ff2w  = (const float*)d_in[31];
  const float* ff2b  = (const float*)d_in[32];
  const float* clfw  = (const float*)d_in[33];
  const float* clfb  = (const float*)d_in[34];
  float* out = (float*)d_out;

  int* sec_idx   = (int*)d_ws;
  int* proto_idx = sec_idx + NSAMPLE;
  short* w2hi = (short*)((float*)d_ws + WS_W2HI);
  short* w2lo = (short*)((float*)d_ws + WS_W2LO);
  short* w3hi = (short*)((float*)d_ws + WS_W3HI);
  short* w3lo = (short*)((float*)d_ws + WS_W3LO);
  float* P3   = (float*)d_ws + WS_P3;
  float* c3   = (float*)d_ws + WS_C3;
  float* xsum = (float*)d_ws + WS_XSUM;
  float* vbuf = (float*)d_ws + WS_V;

  hipLaunchKernelGGL(prep_all_kernel, dim3(145), dim3(256), 0, stream,
                     w2, w3, w2hi, w2lo, w3hi, w3lo,
                     prot, fc2w, fcw, fcb, fc2b, P3, c3);
  hipLaunchKernelGGL(attn_a_kernel, dim3(BS), dim3(128), 0, stream, x, xsum);
  hipLaunchKernelGGL(attn_b_kernel, dim3(BS / MB), dim3(256), 0, stream,
                     xsum, wk, wq, vbuf);
  hipLaunchKernelGGL(attn_c_kernel, dim3(BS), dim3(192), 0, stream,
                     x, vbuf, gum, sec_idx);
  hipLaunchKernelGGL(conv_kernel, dim3(NSAMPLE), dim3(256), 0, stream,
                     x, sec_idx, w1, b1, bn1g, bn1b, w2hi, w2lo, b2, bn2g, bn2b,
                     w3hi, w3lo, b3, bn3g, bn3b, P3, c3, proto_idx);
  hipLaunchKernelGGL(seq_kernel, dim3(BB), dim3(512), 0, stream,
                     proto_idx, prot, inw, inb, outw, outb,
                     ln1g, ln1b, ln2g, ln2b, ff1w, ff1b, ff2w, ff2b,
                     clfw, clfb, out);
}

// Round 7
// 283.706 us; speedup vs baseline: 2.9970x; 2.9970x over previous
//
#include <hip/hip_runtime.h>
#include <math.h>

#define BB 64
#define SS 21
#define NSAMP 3000
#define HID 500
#define SECN 6
#define NN 2
#define OUTD 128
#define NPROTO 25
#define NCLS 5
#define NHEAD 4
#define BS (BB*SS)          // 1344
#define NSAMPLE (BS*NN)     // 2688

#define C500 (-0.0184206807439523674f)   // -ln(1e4)/500
#define LSCALE 0.00745355992499929898f   // 1/(6*sqrt(500))

// ws float offsets
#define WS_W2HI 5376
#define WS_W2LO 8448
#define WS_W3HI 11520
#define WS_W3LO 23808
#define WS_P3   36096
#define WS_C3   55296
#define WS_WQT  55424
#define WS_V    727424

typedef __attribute__((ext_vector_type(8))) short short8;
typedef __attribute__((ext_vector_type(4))) float floatx4;

__device__ __forceinline__ short f2bf(float f) {
  unsigned u = __float_as_uint(f);
  u += 0x7FFF + ((u >> 16) & 1);          // RNE to bf16
  return (short)(u >> 16);
}
__device__ __forceinline__ float bf2f(short h) {
  return __uint_as_float(((unsigned)(unsigned short)h) << 16);
}
// lr-clamped shuffles along the pos axis (lr = lane&15)
__device__ __forceinline__ float sdown(float v, int k, int l, int lr) {
  int tgt = (lr + k > 15) ? l : (l + k);
  return __shfl(v, tgt, 64);
}
__device__ __forceinline__ float sup(float v, int k, int l, int lr) {
  int tgt = (lr - k < 0) ? l : (l - k);
  return __shfl(v, tgt, 64);
}

// ---------------- Kernel 0: weight splits + folded-VQ prep + wq transpose ----------------
__global__ __launch_bounds__(256) void prep_all_kernel(
    const float* __restrict__ w2, const float* __restrict__ w3,
    short* __restrict__ w2hi, short* __restrict__ w2lo,
    short* __restrict__ w3hi, short* __restrict__ w3lo,
    const float* __restrict__ protos, const float* __restrict__ fc2w,
    const float* __restrict__ fcw, const float* __restrict__ fcb,
    const float* __restrict__ fc2b,
    float* __restrict__ P3, float* __restrict__ c3,
    const float* __restrict__ wq, float* __restrict__ wqT) {
  __shared__ __align__(16) float p2row[256];
  __shared__ float red[256];
  __shared__ float tile[64][65];
  const int t = threadIdx.x;
  if (blockIdx.x < 120) {
    int idx = blockIdx.x * 256 + t;
    if (idx < 6144) {
      int ic = idx & 31, ck = idx >> 5, k = ck % 3, c = ck / 3;
      float v = w2[c * 96 + ic * 3 + k];
      int dst = c * 96 + k * 32 + ic;
      short hi = f2bf(v);
      short lo = f2bf(v - bf2f(hi));
      w2hi[dst] = hi; w2lo[dst] = lo;
    } else if (idx < 30720) {
      int j = idx - 6144;
      int ic = j & 63, ck = j >> 6, k = ck % 3, c = ck / 3;
      float v = w3[(c * 64 + ic) * 3 + k];
      int dst = c * 192 + k * 64 + ic;
      short hi = f2bf(v);
      short lo = f2bf(v - bf2f(hi));
      w3hi[dst] = hi; w3lo[dst] = lo;
    }
    return;
  }
  if (blockIdx.x >= 145) {               // wq transpose: 32 tile-blocks
    int tid = blockIdx.x - 145;
    int h0 = (tid >> 2) * 64, c0 = (tid & 3) * 64;
    for (int e = t; e < 4096; e += 256) {
      int i = e >> 6, j = e & 63;        // i: h-off, j: c-off
      if (h0 + i < 500) tile[j][i] = wq[(h0 + i) * 256 + c0 + j];
    }
    __syncthreads();
    for (int e = t; e < 4096; e += 256) {
      int c = e >> 6, hh = e & 63;
      if (h0 + hh < 500) wqT[(c0 + c) * 500 + h0 + hh] = tile[c][hh];
    }
    return;
  }
  const int p = blockIdx.x - 120, j = t;
  {
    const float4* pr = reinterpret_cast<const float4*>(protos + p * 128);
    const float4* wr = reinterpret_cast<const float4*>(fc2w + j * 128);
    float4 a4 = make_float4(0.f, 0.f, 0.f, 0.f);
    for (int c4 = 0; c4 < 32; c4++) {
      float4 a = pr[c4], b = wr[c4];
      a4.x += a.x * b.x; a4.y += a.y * b.y; a4.z += a.z * b.z; a4.w += a.w * b.w;
    }
    float v = (a4.x + a4.y) + (a4.z + a4.w);
    p2row[j] = v;
    float contrib = v * fcb[j];
    if (j < 128) {
      float pv = protos[p * 128 + j];
      contrib += pv * fc2b[j] - 0.5f * pv * pv;
    }
    red[j] = contrib;
  }
  __syncthreads();
  for (int s = 128; s > 0; s >>= 1) {
    if (j < s) red[j] += red[j + s];
    __syncthreads();
  }
  if (j == 0) c3[p] = red[0];
  for (int k = j; k < 768; k += 256) {
    const float4* fr = reinterpret_cast<const float4*>(fcw + k * 256);
    const float4* p2 = reinterpret_cast<const float4*>(p2row);
    float4 a4 = make_float4(0.f, 0.f, 0.f, 0.f);
    for (int j4 = 0; j4 < 64; j4++) {
      float4 a = p2[j4], b = fr[j4];
      a4.x += a.x * b.x; a4.y += a.y * b.y; a4.z += a.z * b.z; a4.w += a.w * b.w;
    }
    P3[p * 768 + k] = (a4.x + a4.y) + (a4.z + a4.w);
  }
}

// ---------------- Kernel 1b: fused xsum -> ks -> v (16 samples/block) ----------------
#define MB16 16
__global__ __launch_bounds__(512) void attn_b_kernel(
    const float* __restrict__ x, const float* __restrict__ wk,
    const float* __restrict__ wqT, float* __restrict__ v) {
  __shared__ __align__(16) float pesum[500];
  __shared__ __align__(16) float xs[MB16 * 500];
  __shared__ __align__(16) float ks_t[256 * MB16];
  const int blk = blockIdx.x, t = threadIdx.x;

  // PE-sum per h (constant over samples)
  if (t < 125) {
    float div0 = expf((float)(4 * t) * C500);
    float div1 = expf((float)(4 * t + 2) * C500);
    float s0 = 0.f, c0 = 0.f, s1 = 0.f, c1 = 0.f;
#pragma unroll
    for (int s = 0; s < SECN; s++) {
      float a0 = (float)s * div0, a1 = (float)s * div1;
      s0 += sinf(a0); c0 += cosf(a0);
      s1 += sinf(a1); c1 += cosf(a1);
    }
    reinterpret_cast<float4*>(pesum)[t] = make_float4(s0, c0, s1, c1);
  }
  __syncthreads();

  // xs[m][h] = sum_s x[bs][s][h] + pesum[h]
  for (int e = t; e < MB16 * 125; e += 512) {
    int m = e / 125, h4 = e % 125;
    const float4* xr = reinterpret_cast<const float4*>(x) + (blk * MB16 + m) * 750;
    float4 a = xr[h4];
#pragma unroll
    for (int s = 1; s < SECN; s++) {
      float4 b = xr[s * 125 + h4];
      a.x += b.x; a.y += b.y; a.z += b.z; a.w += b.w;
    }
    float4 pe = reinterpret_cast<float4*>(pesum)[h4];
    a.x += pe.x; a.y += pe.y; a.z += pe.z; a.w += pe.w;
    reinterpret_cast<float4*>(xs)[m * 125 + h4] = a;
  }
  __syncthreads();

  // phase A: ks_t[c][m] = sum_i xs[m][i] * wk[i][c]  (coalesced wk, m split 2-way)
  {
    int c = t & 255, mh = t >> 8;
    float acc[8];
#pragma unroll
    for (int m = 0; m < 8; m++) acc[m] = 0.f;
    const float4* xsb = reinterpret_cast<const float4*>(xs) + mh * 8 * 125;
    for (int i4 = 0; i4 < 125; i4++) {
      int i = i4 * 4;
      float w0 = wk[(i + 0) * 256 + c];
      float w1 = wk[(i + 1) * 256 + c];
      float w2 = wk[(i + 2) * 256 + c];
      float w3 = wk[(i + 3) * 256 + c];
#pragma unroll
      for (int m = 0; m < 8; m++) {
        float4 xv = xsb[m * 125 + i4];
        acc[m] += xv.x * w0 + xv.y * w1 + xv.z * w2 + xv.w * w3;
      }
    }
#pragma unroll
    for (int m = 0; m < 8; m++)
      ks_t[c * MB16 + mh * 8 + m] = acc[m];
  }
  __syncthreads();

  // phase B: v[m][n][h] = sum_c wqT[n*128+c][h] * ks_t[n*128+c][m]  (coalesced wqT)
  if (t < 500) {
    int h = t;
#pragma unroll
    for (int n = 0; n < 2; n++) {
      float acc[16];
#pragma unroll
      for (int m = 0; m < 16; m++) acc[m] = 0.f;
      const float* wcol = wqT + (n * 128) * 500 + h;
      const floatx4* ktb = (const floatx4*)ks_t + n * 128 * 4;
      for (int c = 0; c < 128; c++) {
        float w = wcol[c * 500];
        floatx4 k0 = ktb[c * 4 + 0], k1 = ktb[c * 4 + 1];
        floatx4 k2 = ktb[c * 4 + 2], k3 = ktb[c * 4 + 3];
        acc[0]  += w * k0[0]; acc[1]  += w * k0[1]; acc[2]  += w * k0[2]; acc[3]  += w * k0[3];
        acc[4]  += w * k1[0]; acc[5]  += w * k1[1]; acc[6]  += w * k1[2]; acc[7]  += w * k1[3];
        acc[8]  += w * k2[0]; acc[9]  += w * k2[1]; acc[10] += w * k2[2]; acc[11] += w * k2[3];
        acc[12] += w * k3[0]; acc[13] += w * k3[1]; acc[14] += w * k3[2]; acc[15] += w * k3[3];
      }
#pragma unroll
      for (int m = 0; m < 16; m++)
        v[((blk * MB16 + m) * 2 + n) * 500 + h] = acc[m];
    }
  }
}

// ---------------- Kernel 1c: logits = (x+pe).v + gumbel -> argmax ----------------
__global__ __launch_bounds__(192) void attn_c_kernel(
    const float* __restrict__ x, const float* __restrict__ v,
    const float* __restrict__ gumbel, int* __restrict__ sec_idx) {
  __shared__ float lgsh[NN][SECN];
  const int bs = blockIdx.x, t = threadIdx.x;
  const int s = t >> 5, lane = t & 31;
  const float4* x4 = reinterpret_cast<const float4*>(x) + bs * 750 + s * 125;
  const float4* v0 = reinterpret_cast<const float4*>(v) + bs * 250;
  const float4* v1 = v0 + 125;
  float a0 = 0.f, a1 = 0.f;
  for (int h4 = lane; h4 < 125; h4 += 32) {
    float4 xv = x4[h4];
    float div0 = expf((float)(4 * h4) * C500);
    float div1 = expf((float)(4 * h4 + 2) * C500);
    float ang0 = (float)s * div0, ang1 = (float)s * div1;
    xv.x += sinf(ang0); xv.y += cosf(ang0);
    xv.z += sinf(ang1); xv.w += cosf(ang1);
    float4 w0 = v0[h4], w1 = v1[h4];
    a0 += xv.x * w0.x + xv.y * w0.y + xv.z * w0.z + xv.w * w0.w;
    a1 += xv.x * w1.x + xv.y * w1.y + xv.z * w1.z + xv.w * w1.w;
  }
#pragma unroll
  for (int m = 16; m >= 1; m >>= 1) {
    a0 += __shfl_xor(a0, m);
    a1 += __shfl_xor(a1, m);
  }
  if (lane == 0) {
    lgsh[0][s] = a0 * LSCALE + gumbel[(bs * 2 + 0) * SECN + s];
    lgsh[1][s] = a1 * LSCALE + gumbel[(bs * 2 + 1) * SECN + s];
  }
  __syncthreads();
  if (t < 2) {
    int best = 0; float bv = lgsh[t][0];
    for (int i = 1; i < SECN; i++) {
      float q = lgsh[t][i];
      if (q > bv) { bv = q; best = i; }
    }
    sec_idx[bs * 2 + t] = best;
  }
}

// ---------------- Kernel 2: conv encoder (MFMA, in-register pooling) + VQ ----------------
#define CONV_LDS 34688
__global__ __launch_bounds__(256, 4) void conv_kernel(
    const float* __restrict__ x, const int* __restrict__ sec_idx,
    const float* __restrict__ w1, const float* __restrict__ b1,
    const float* __restrict__ bn1g, const float* __restrict__ bn1b,
    const short* __restrict__ w2hi, const short* __restrict__ w2lo,
    const float* __restrict__ b2,
    const float* __restrict__ bn2g, const float* __restrict__ bn2b,
    const short* __restrict__ w3hi, const short* __restrict__ w3lo,
    const float* __restrict__ b3,
    const float* __restrict__ bn3g, const float* __restrict__ bn3b,
    const float* __restrict__ P3, const float* __restrict__ c3,
    int* __restrict__ proto_idx) {
  __shared__ __align__(16) char smem[CONV_LDS];
  short* act1_hi  = (short*)smem;               // [130][40]
  short* act1_lo  = (short*)(smem + 10400);
  short* act2p_hi = (short*)(smem + 20800);     // [34][72]
  short* act2p_lo = (short*)(smem + 25696);
  float* in0p     = (float*)(smem + 30592);     // [512]
  float* Lbuf     = (float*)(smem + 30592);     // [8][64] (alias in0p)
  float* Rbuf     = (float*)(smem + 32640);     // [8][64]
  float* featsh   = (float*)smem;               // [768] alias act1 (ph5+)
  float* sc25     = (float*)(smem + 3072);      // [25]

  const int sample = blockIdx.x;
  const int t = threadIdx.x;
  const int bsIdx = sample >> 1;
  const float bnscale = rsqrtf(1.0f + 1e-5f);
  const int wv = t >> 6, l = t & 63, lr = l & 15, lg2 = l >> 4;

  {
    int sec = sec_idx[sample];
    const float* src = &x[bsIdx * NSAMP + sec * HID];
    for (int i = t; i < 512; i += 256) in0p[i] = (i >= 1 && i <= 500) ? src[i - 1] : 0.f;
    if (t < 200) {
      int r = t / 40; r = (r == 0) ? 0 : 125 + r;
      int idx = r * 40 + t % 40;
      act1_hi[idx] = 0; act1_lo[idx] = 0;
    }
    for (int i = t; i < 648; i += 256) {
      int r = i / 72; r = (r == 0) ? 0 : 25 + r;
      int idx = r * 72 + i % 72;
      act2p_hi[idx] = 0; act2p_lo[idx] = 0;
    }
  }
  __syncthreads();

  {
    int ic = t & 31;
    float w0 = w1[ic * 3], w1v = w1[ic * 3 + 1], w2v = w1[ic * 3 + 2];
    float bb = b1[ic];
    float g = bn1g[ic] * bnscale, be = bn1b[ic];
    for (int p = t >> 5; p < 125; p += 8) {
      int base = 4 * p;
      float xm1 = in0p[base], x0 = in0p[base + 1], x1 = in0p[base + 2],
            x2 = in0p[base + 3], x3 = in0p[base + 4], x4 = in0p[base + 5];
      float a0 = bb + w0 * xm1 + w1v * x0 + w2v * x1;
      float a1 = bb + w0 * x0  + w1v * x1 + w2v * x2;
      float a2 = bb + w0 * x1  + w1v * x2 + w2v * x3;
      float a3 = bb + w0 * x2  + w1v * x3 + w2v * x4;
      float m = fmaxf(fmaxf(fmaxf(fmaxf(a0, a1), a2), a3), 0.f);
      float v = m * g + be;
      short hi = f2bf(v);
      short lo = f2bf(v - bf2f(hi));
      act1_hi[(p + 1) * 40 + ic] = hi;
      act1_lo[(p + 1) * 40 + ic] = lo;
    }
  }
  __syncthreads();

  {
    floatx4 acc[4][2];
#pragma unroll
    for (int m = 0; m < 4; m++)
#pragma unroll
      for (int nn = 0; nn < 2; nn++) acc[m][nn] = (floatx4){0.f, 0.f, 0.f, 0.f};
#pragma unroll
    for (int s = 0; s < 3; s++) {
      short8 Ah[4], Al[4], Bh[2], Bl[2];
#pragma unroll
      for (int m = 0; m < 4; m++) {
        int aoff = (m * 16 + lr) * 96 + s * 32 + lg2 * 8;
        Ah[m] = *(const short8*)(w2hi + aoff);
        Al[m] = *(const short8*)(w2lo + aoff);
      }
#pragma unroll
      for (int nn = 0; nn < 2; nn++) {
        int boff = ((2 * wv + nn) * 16 + lr + s) * 40 + lg2 * 8;
        Bh[nn] = *(const short8*)(act1_hi + boff);
        Bl[nn] = *(const short8*)(act1_lo + boff);
      }
#pragma unroll
      for (int m = 0; m < 4; m++)
#pragma unroll
        for (int nn = 0; nn < 2; nn++) {
          acc[m][nn] = __builtin_amdgcn_mfma_f32_16x16x32_bf16(Ah[m], Bh[nn], acc[m][nn], 0, 0, 0);
          acc[m][nn] = __builtin_amdgcn_mfma_f32_16x16x32_bf16(Ah[m], Bl[nn], acc[m][nn], 0, 0, 0);
          acc[m][nn] = __builtin_amdgcn_mfma_f32_16x16x32_bf16(Al[m], Bh[nn], acc[m][nn], 0, 0, 0);
        }
    }
#pragma unroll
    for (int nn = 0; nn < 2; nn++) {
      int tile = 2 * wv + nn;
      int pos = tile * 16 + lr;
      int r5 = pos % 5;
#pragma unroll
      for (int m = 0; m < 4; m++)
#pragma unroll
        for (int j = 0; j < 4; j++) {
          float vv = acc[m][nn][j];
          float m1 = fmaxf(vv, sdown(vv, 1, l, lr));
          float m4 = fmaxf(m1, sdown(m1, 2, l, lr));
          float m5 = fmaxf(m4, sdown(vv, 4, l, lr));
          float p1 = fmaxf(vv, sup(vv, 1, l, lr));
          float p2 = fmaxf(p1, sup(p1, 2, l, lr));
          float p4 = fmaxf(p2, sup(vv, 4, l, lr));
          int ch = m * 16 + lg2 * 4 + j;
          if (r5 == 0) {
            if (lr <= 11) {
              int w = pos / 5;
              float val = fmaxf(m5 + b2[ch], 0.f) * (bn2g[ch] * bnscale) + bn2b[ch];
              short hi = f2bf(val);
              short lo = f2bf(val - bf2f(hi));
              act2p_hi[(w + 1) * 72 + ch] = hi;
              act2p_lo[(w + 1) * 72 + ch] = lo;
            } else {
              Lbuf[tile * 64 + ch] = m5;
            }
          }
          if (r5 == 4 && lr <= 3) {
            Rbuf[tile * 64 + ch] = p4;
          }
        }
    }
  }
  __syncthreads();

  {
    const int wl[6] = {3, 6, 9, 12, 19, 22};
    for (int q = t; q < 384; q += 256) {
      int wi = q >> 6, ch = q & 63;
      int w = wl[wi], lt = (5 * w) >> 4;
      float M = fmaxf(Lbuf[lt * 64 + ch], Rbuf[(lt + 1) * 64 + ch]);
      float val = fmaxf(M + b2[ch], 0.f) * (bn2g[ch] * bnscale) + bn2b[ch];
      short hi = f2bf(val);
      short lo = f2bf(val - bf2f(hi));
      act2p_hi[(w + 1) * 72 + ch] = hi;
      act2p_lo[(w + 1) * 72 + ch] = lo;
    }
  }
  __syncthreads();

  {
    floatx4 acc[2][2];
#pragma unroll
    for (int mm = 0; mm < 2; mm++)
#pragma unroll
      for (int nn = 0; nn < 2; nn++) acc[mm][nn] = (floatx4){0.f, 0.f, 0.f, 0.f};
#pragma unroll
    for (int s = 0; s < 6; s++) {
      short8 Ah[2], Al[2], Bh[2], Bl[2];
#pragma unroll
      for (int mm = 0; mm < 2; mm++) {
        int aoff = ((wv * 2 + mm) * 16 + lr) * 192 + s * 32 + lg2 * 8;
        Ah[mm] = *(const short8*)(w3hi + aoff);
        Al[mm] = *(const short8*)(w3lo + aoff);
      }
#pragma unroll
      for (int nn = 0; nn < 2; nn++) {
        int boff = (nn * 16 + lr + (s >> 1)) * 72 + (s & 1) * 32 + lg2 * 8;
        Bh[nn] = *(const short8*)(act2p_hi + boff);
        Bl[nn] = *(const short8*)(act2p_lo + boff);
      }
#pragma unroll
      for (int mm = 0; mm < 2; mm++)
#pragma unroll
        for (int nn = 0; nn < 2; nn++) {
          acc[mm][nn] = __builtin_amdgcn_mfma_f32_16x16x32_bf16(Ah[mm], Bh[nn], acc[mm][nn], 0, 0, 0);
          acc[mm][nn] = __builtin_amdgcn_mfma_f32_16x16x32_bf16(Ah[mm], Bl[nn], acc[mm][nn], 0, 0, 0);
          acc[mm][nn] = __builtin_amdgcn_mfma_f32_16x16x32_bf16(Al[mm], Bh[nn], acc[mm][nn], 0, 0, 0);
        }
    }
    __syncthreads();
#pragma unroll
    for (int nn = 0; nn < 2; nn++) {
      int pos = nn * 16 + lr;
#pragma unroll
      for (int mm = 0; mm < 2; mm++)
#pragma unroll
        for (int j = 0; j < 4; j++) {
          float vv = acc[mm][nn][j];
          float g1 = fmaxf(vv, __shfl_xor(vv, 1, 64));
          float g2 = fmaxf(g1, __shfl_xor(g1, 2, 64));
          if ((lr & 3) == 0 && pos < 24) {
            int pw = pos >> 2;
            int ch = (wv * 2 + mm) * 16 + lg2 * 4 + j;
            float val = fmaxf(g2 + b3[ch], 0.f) * (bn3g[ch] * bnscale) + bn3b[ch];
            featsh[ch * 6 + pw] = val;
          }
        }
    }
  }
  __syncthreads();

  if (t < NPROTO * 8) {
    int p = t >> 3, part = t & 7;
    const float4* pr = reinterpret_cast<const float4*>(P3 + p * 768 + part * 96);
    const float4* fr = reinterpret_cast<const float4*>(featsh + part * 96);
    float4 a4 = make_float4(0.f, 0.f, 0.f, 0.f);
#pragma unroll
    for (int i = 0; i < 24; i++) {
      float4 w = pr[i], f = fr[i];
      a4.x += w.x * f.x; a4.y += w.y * f.y; a4.z += w.z * f.z; a4.w += w.w * f.w;
    }
    float a = (a4.x + a4.y) + (a4.z + a4.w);
    a += __shfl_xor(a, 1);
    a += __shfl_xor(a, 2);
    a += __shfl_xor(a, 4);
    if (part == 0) sc25[p] = a + c3[p];
  }
  __syncthreads();
  if (t == 0) {
    int best = 0; float bv = sc25[0];
    for (int i = 1; i < NPROTO; i++) {
      float v = sc25[i];
      if (v > bv) { bv = v; best = i; }
    }
    proto_idx[sample] = best;
  }
}

// ---------------- Kernel 3: sequence transformer + classifier ----------------
__global__ __launch_bounds__(512) void seq_kernel(
    const int* __restrict__ proto_idx, const float* __restrict__ protos,
    const float* __restrict__ inw, const float* __restrict__ inb,
    const float* __restrict__ outw, const float* __restrict__ outb,
    const float* __restrict__ ln1g, const float* __restrict__ ln1b,
    const float* __restrict__ ln2g, const float* __restrict__ ln2b,
    const float* __restrict__ ff1w, const float* __restrict__ ff1b,
    const float* __restrict__ ff2w, const float* __restrict__ ff2b,
    const float* __restrict__ clfw, const float* __restrict__ clfb,
    float* __restrict__ out) {
  __shared__ __align__(16) float hsh[SS * OUTD];
  __shared__ __align__(16) float big[SS * 3 * OUTD];
  __shared__ __align__(16) float sc[NHEAD * SS * SS];
  __shared__ __align__(16) float ctx[SS * OUTD];
  __shared__ float rowm[SS], rowv[SS];

  const int b = blockIdx.x;
  const int t = threadIdx.x;

  for (int o = t; o < SS * OUTD; o += 512) {
    int s = o >> 7, d = o & 127;
    int i0 = proto_idx[(b * SS + s) * 2];
    int i1 = proto_idx[(b * SS + s) * 2 + 1];
    float pc = 0.5f * (protos[i0 * OUTD + d] + protos[i1 * OUTD + d]);
    int i = d >> 1;
    float div = expf((float)(2 * i) * -0.07195578415606439f);
    float ang = (float)s * div;
    float pe = (d & 1) ? cosf(ang) : sinf(ang);
    hsh[o] = pc + pe;
  }
  __syncthreads();

  for (int o = t; o < SS * 384; o += 512) {
    int s = o / 384, j = o % 384;
    float4 a4 = make_float4(0.f, 0.f, 0.f, 0.f);
    const float4* hr = reinterpret_cast<const float4*>(&hsh[s * OUTD]);
    for (int d4 = 0; d4 < 32; d4++) {
      float4 h4 = hr[d4];
      int d = d4 * 4;
      a4.x += h4.x * inw[(d + 0) * 384 + j];
      a4.y += h4.y * inw[(d + 1) * 384 + j];
      a4.z += h4.z * inw[(d + 2) * 384 + j];
      a4.w += h4.w * inw[(d + 3) * 384 + j];
    }
    big[o] = inb[j] + ((a4.x + a4.y) + (a4.z + a4.w));
  }
  __syncthreads();

  for (int o = t; o < NHEAD * SS * SS; o += 512) {
    int hd = o / (SS * SS), r = o % (SS * SS), qs = r / SS, ks = r % SS;
    const float4* qp = reinterpret_cast<const float4*>(&big[qs * 384 + hd * 32]);
    const float4* kp = reinterpret_cast<const float4*>(&big[ks * 384 + 128 + hd * 32]);
    float4 a4 = make_float4(0.f, 0.f, 0.f, 0.f);
#pragma unroll
    for (int d4 = 0; d4 < 8; d4++) {
      float4 q4 = qp[d4], k4 = kp[d4];
      a4.x += q4.x * k4.x; a4.y += q4.y * k4.y; a4.z += q4.z * k4.z; a4.w += q4.w * k4.w;
    }
    sc[o] = ((a4.x + a4.y) + (a4.z + a4.w)) * 0.17677669529663689f;
  }
  __syncthreads();
  for (int r = t; r < NHEAD * SS; r += 512) {
    float* row = &sc[r * SS];
    float mx = row[0];
    for (int i = 1; i < SS; i++) mx = fmaxf(mx, row[i]);
    float sum = 0.f;
    for (int i = 0; i < SS; i++) { float e = expf(row[i] - mx); row[i] = e; sum += e; }
    float inv = 1.f / sum;
    for (int i = 0; i < SS; i++) row[i] *= inv;
  }
  __syncthreads();
  for (int o = t; o < SS * OUTD; o += 512) {
    int qs = o >> 7, d = o & 127, hd = d >> 5, dd = d & 31;
    const float* srow = &sc[(hd * SS + qs) * SS];
    float a = 0.f;
    for (int ks = 0; ks < SS; ks++) a += srow[ks] * big[ks * 384 + 256 + hd * 32 + dd];
    ctx[o] = a;
  }
  __syncthreads();
  float* tmp = big;
  for (int o = t; o < SS * OUTD; o += 512) {
    int s = o >> 7, d = o & 127;
    float4 a4 = make_float4(0.f, 0.f, 0.f, 0.f);
    const float4* cr = reinterpret_cast<const float4*>(&ctx[s * OUTD]);
    for (int e4 = 0; e4 < 32; e4++) {
      float4 c4 = cr[e4];
      int e = e4 * 4;
      a4.x += c4.x * outw[(e + 0) * OUTD + d];
      a4.y += c4.y * outw[(e + 1) * OUTD + d];
      a4.z += c4.z * outw[(e + 2) * OUTD + d];
      a4.w += c4.w * outw[(e + 3) * OUTD + d];
    }
    tmp[o] = hsh[o] + outb[d] + ((a4.x + a4.y) + (a4.z + a4.w));
  }
  __syncthreads();
  if (t < SS) {
    const float4* r4 = reinterpret_cast<const float4*>(&tmp[t * OUTD]);
    float4 m4 = make_float4(0.f, 0.f, 0.f, 0.f);
    for (int d4 = 0; d4 < 32; d4++) {
      float4 v = r4[d4];
      m4.x += v.x; m4.y += v.y; m4.z += v.z; m4.w += v.w;
    }
    float m = ((m4.x + m4.y) + (m4.z + m4.w)) * (1.0f / OUTD);
    float4 v4 = make_float4(0.f, 0.f, 0.f, 0.f);
    for (int d4 = 0; d4 < 32; d4++) {
      float4 v = r4[d4];
      float ux = v.x - m, uy = v.y - m, uz = v.z - m, uw = v.w - m;
      v4.x += ux * ux; v4.y += uy * uy; v4.z += uz * uz; v4.w += uw * uw;
    }
    float var = ((v4.x + v4.y) + (v4.z + v4.w)) * (1.0f / OUTD);
    rowm[t] = m; rowv[t] = rsqrtf(var + 1e-5f);
  }
  __syncthreads();
  for (int o = t; o < SS * OUTD; o += 512) {
    int s = o >> 7, d = o & 127;
    hsh[o] = (tmp[o] - rowm[s]) * rowv[s] * ln1g[d] + ln1b[d];
  }
  __syncthreads();
  for (int o = t; o < SS * OUTD; o += 512) {
    int s = o >> 7, d = o & 127;
    float4 a4 = make_float4(0.f, 0.f, 0.f, 0.f);
    const float4* hr = reinterpret_cast<const float4*>(&hsh[s * OUTD]);
    for (int e4 = 0; e4 < 32; e4++) {
      float4 h4 = hr[e4];
      int e = e4 * 4;
      a4.x += h4.x * ff1w[(e + 0) * OUTD + d];
      a4.y += h4.y * ff1w[(e + 1) * OUTD + d];
      a4.z += h4.z * ff1w[(e + 2) * OUTD + d];
      a4.w += h4.w * ff1w[(e + 3) * OUTD + d];
    }
    ctx[o] = fmaxf(ff1b[d] + ((a4.x + a4.y) + (a4.z + a4.w)), 0.f);
  }
  __syncthreads();
  for (int o = t; o < SS * OUTD; o += 512) {
    int s = o >> 7, d = o & 127;
    float4 a4 = make_float4(0.f, 0.f, 0.f, 0.f);
    const float4* cr = reinterpret_cast<const float4*>(&ctx[s * OUTD]);
    for (int e4 = 0; e4 < 32; e4++) {
      float4 c4 = cr[e4];
      int e = e4 * 4;
      a4.x += c4.x * ff2w[(e + 0) * OUTD + d];
      a4.y += c4.y * ff2w[(e + 1) * OUTD + d];
      a4.z += c4.z * ff2w[(e + 2) * OUTD + d];
      a4.w += c4.w * ff2w[(e + 3) * OUTD + d];
    }
    tmp[o] = hsh[o] + ff2b[d] + ((a4.x + a4.y) + (a4.z + a4.w));
  }
  __syncthreads();
  if (t < SS) {
    const float4* r4 = reinterpret_cast<const float4*>(&tmp[t * OUTD]);
    float4 m4 = make_float4(0.f, 0.f, 0.f, 0.f);
    for (int d4 = 0; d4 < 32; d4++) {
      float4 v = r4[d4];
      m4.x += v.x; m4.y += v.y; m4.z += v.z; m4.w += v.w;
    }
    float m = ((m4.x + m4.y) + (m4.z + m4.w)) * (1.0f / OUTD);
    float4 v4 = make_float4(0.f, 0.f, 0.f, 0.f);
    for (int d4 = 0; d4 < 32; d4++) {
      float4 v = r4[d4];
      float ux = v.x - m, uy = v.y - m, uz = v.z - m, uw = v.w - m;
      v4.x += ux * ux; v4.y += uy * uy; v4.z += uz * uz; v4.w += uw * uw;
    }
    float var = ((v4.x + v4.y) + (v4.z + v4.w)) * (1.0f / OUTD);
    rowm[t] = m; rowv[t] = rsqrtf(var + 1e-5f);
  }
  __syncthreads();
  for (int o = t; o < SS * OUTD; o += 512) {
    int s = o >> 7, d = o & 127;
    hsh[o] = (tmp[o] - rowm[s]) * rowv[s] * ln2g[d] + ln2b[d];
  }
  __syncthreads();
  for (int o = t; o < SS * NCLS; o += 512) {
    int s = o / NCLS, c = o % NCLS;
    float4 a4 = make_float4(0.f, 0.f, 0.f, 0.f);
    const float4* hr = reinterpret_cast<const float4*>(&hsh[s * OUTD]);
    for (int d4 = 0; d4 < 32; d4++) {
      float4 h4 = hr[d4];
      int d = d4 * 4;
      a4.x += h4.x * clfw[(d + 0) * NCLS + c];
      a4.y += h4.y * clfw[(d + 1) * NCLS + c];
      a4.z += h4.z * clfw[(d + 2) * NCLS + c];
      a4.w += h4.w * clfw[(d + 3) * NCLS + c];
    }
    out[(b * SS + s) * NCLS + c] = clfb[c] + ((a4.x + a4.y) + (a4.z + a4.w));
  }
}

extern "C" void kernel_launch(void* const* d_in, const int* in_sizes, int n_in,
                              void* d_out, int out_size, void* d_ws, size_t ws_size,
                              hipStream_t stream) {
  const float* x     = (const float*)d_in[0];
  const float* gum   = (const float*)d_in[1];
  const float* wq    = (const float*)d_in[2];
  const float* wk    = (const float*)d_in[3];
  const float* w1    = (const float*)d_in[4];
  const float* b1    = (const float*)d_in[5];
  const float* bn1g  = (const float*)d_in[6];
  const float* bn1b  = (const float*)d_in[7];
  const float* w2    = (const float*)d_in[8];
  const float* b2    = (const float*)d_in[9];
  const float* bn2g  = (const float*)d_in[10];
  const float* bn2b  = (const float*)d_in[11];
  const float* w3    = (const float*)d_in[12];
  const float* b3    = (const float*)d_in[13];
  const float* bn3g  = (const float*)d_in[14];
  const float* bn3b  = (const float*)d_in[15];
  const float* fcw   = (const float*)d_in[16];
  const float* fcb   = (const float*)d_in[17];
  const float* fc2w  = (const float*)d_in[18];
  const float* fc2b  = (const float*)d_in[19];
  const float* prot  = (const float*)d_in[20];
  const float* inw   = (const float*)d_in[21];
  const float* inb   = (const float*)d_in[22];
  const float* outw  = (const float*)d_in[23];
  const float* outb  = (const float*)d_in[24];
  const float* ln1g  = (const float*)d_in[25];
  const float* ln1b  = (const float*)d_in[26];
  const float* ln2g  = (const float*)d_in[27];
  const float* ln2b  = (const float*)d_in[28];
  const float* ff1w  = (const float*)d_in[29];
  const float* ff1b  = (const float*)d_in[30];
  const float* ff2w  = (const float*)d_in[31];
  const float* ff2b  = (const float*)d_in[32];
  const float* clfw  = (const float*)d_in[33];
  const float* clfb  = (const float*)d_in[34];
  float* out = (float*)d_out;

  int* sec_idx   = (int*)d_ws;
  int* proto_idx = sec_idx + NSAMPLE;
  short* w2hi = (short*)((float*)d_ws + WS_W2HI);
  short* w2lo = (short*)((float*)d_ws + WS_W2LO);
  short* w3hi = (short*)((float*)d_ws + WS_W3HI);
  short* w3lo = (short*)((float*)d_ws + WS_W3LO);
  float* P3   = (float*)d_ws + WS_P3;
  float* c3   = (float*)d_ws + WS_C3;
  float* wqT  = (float*)d_ws + WS_WQT;
  float* vbuf = (float*)d_ws + WS_V;

  hipLaunchKernelGGL(prep_all_kernel, dim3(177), dim3(256), 0, stream,
                     w2, w3, w2hi, w2lo, w3hi, w3lo,
                     prot, fc2w, fcw, fcb, fc2b, P3, c3, wq, wqT);
  hipLaunchKernelGGL(attn_b_kernel, dim3(BS / MB16), dim3(512), 0, stream,
                     x, wk, wqT, vbuf);
  hipLaunchKernelGGL(attn_c_kernel, dim3(BS), dim3(192), 0, stream,
                     x, vbuf, gum, sec_idx);
  hipLaunchKernelGGL(conv_kernel, dim3(NSAMPLE), dim3(256), 0, stream,
                     x, sec_idx, w1, b1, bn1g, bn1b, w2hi, w2lo, b2, bn2g, bn2b,
                     w3hi, w3lo, b3, bn3g, bn3b, P3, c3, proto_idx);
  hipLaunchKernelGGL(seq_kernel, dim3(BB), dim3(512), 0, stream,
                     proto_idx, prot, inw, inb, outw, outb,
                     ln1g, ln1b, ln2g, ln2b, ff1w, ff1b, ff2w, ff2b,
                     clfw, clfb, out);
}

// Round 8
// 246.710 us; speedup vs baseline: 3.4464x; 1.1500x over previous
//
#include <hip/hip_runtime.h>
#include <math.h>

#define BB 64
#define SS 21
#define NSAMP 3000
#define HID 500
#define SECN 6
#define NN 2
#define OUTD 128
#define NPROTO 25
#define NCLS 5
#define NHEAD 4
#define BS (BB*SS)          // 1344
#define NSAMPLE (BS*NN)     // 2688

#define C500 (-0.0184206807439523674f)   // -ln(1e4)/500
#define LSCALE 0.00745355992499929898f   // 1/(6*sqrt(500))

// ws float offsets
#define WS_W2HI 5376
#define WS_W2LO 8448
#define WS_W3HI 11520
#define WS_W3LO 23808
#define WS_P3   36096
#define WS_C3   55296
#define WS_WQT  55424
#define WS_V    727424

typedef __attribute__((ext_vector_type(8))) short short8;
typedef __attribute__((ext_vector_type(4))) float floatx4;

__device__ __forceinline__ short f2bf(float f) {
  unsigned u = __float_as_uint(f);
  u += 0x7FFF + ((u >> 16) & 1);          // RNE to bf16
  return (short)(u >> 16);
}
__device__ __forceinline__ float bf2f(short h) {
  return __uint_as_float(((unsigned)(unsigned short)h) << 16);
}

// ---------------- Kernel 0: weight splits + folded-VQ prep + wq transpose ----------------
__global__ __launch_bounds__(256) void prep_all_kernel(
    const float* __restrict__ w2, const float* __restrict__ w3,
    short* __restrict__ w2hi, short* __restrict__ w2lo,
    short* __restrict__ w3hi, short* __restrict__ w3lo,
    const float* __restrict__ protos, const float* __restrict__ fc2w,
    const float* __restrict__ fcw, const float* __restrict__ fcb,
    const float* __restrict__ fc2b,
    float* __restrict__ P3, float* __restrict__ c3,
    const float* __restrict__ wq, float* __restrict__ wqT) {
  __shared__ __align__(16) float p2row[256];
  __shared__ float red[256];
  __shared__ float tile[64][65];
  const int t = threadIdx.x;
  if (blockIdx.x < 120) {
    int idx = blockIdx.x * 256 + t;
    if (idx < 6144) {
      int ic = idx & 31, ck = idx >> 5, k = ck % 3, c = ck / 3;
      float v = w2[c * 96 + ic * 3 + k];
      int dst = c * 96 + k * 32 + ic;
      short hi = f2bf(v);
      short lo = f2bf(v - bf2f(hi));
      w2hi[dst] = hi; w2lo[dst] = lo;
    } else if (idx < 30720) {
      int j = idx - 6144;
      int ic = j & 63, ck = j >> 6, k = ck % 3, c = ck / 3;
      float v = w3[(c * 64 + ic) * 3 + k];
      int dst = c * 192 + k * 64 + ic;
      short hi = f2bf(v);
      short lo = f2bf(v - bf2f(hi));
      w3hi[dst] = hi; w3lo[dst] = lo;
    }
    return;
  }
  if (blockIdx.x >= 145) {               // wq transpose: 32 tile-blocks
    int tid = blockIdx.x - 145;
    int h0 = (tid >> 2) * 64, c0 = (tid & 3) * 64;
    for (int e = t; e < 4096; e += 256) {
      int i = e >> 6, j = e & 63;        // i: h-off, j: c-off
      if (h0 + i < 500) tile[j][i] = wq[(h0 + i) * 256 + c0 + j];
    }
    __syncthreads();
    for (int e = t; e < 4096; e += 256) {
      int c = e >> 6, hh = e & 63;
      if (h0 + hh < 500) wqT[(c0 + c) * 500 + h0 + hh] = tile[c][hh];
    }
    return;
  }
  const int p = blockIdx.x - 120, j = t;
  {
    const float4* pr = reinterpret_cast<const float4*>(protos + p * 128);
    const float4* wr = reinterpret_cast<const float4*>(fc2w + j * 128);
    float4 a4 = make_float4(0.f, 0.f, 0.f, 0.f);
    for (int c4 = 0; c4 < 32; c4++) {
      float4 a = pr[c4], b = wr[c4];
      a4.x += a.x * b.x; a4.y += a.y * b.y; a4.z += a.z * b.z; a4.w += a.w * b.w;
    }
    float v = (a4.x + a4.y) + (a4.z + a4.w);
    p2row[j] = v;
    float contrib = v * fcb[j];
    if (j < 128) {
      float pv = protos[p * 128 + j];
      contrib += pv * fc2b[j] - 0.5f * pv * pv;
    }
    red[j] = contrib;
  }
  __syncthreads();
  for (int s = 128; s > 0; s >>= 1) {
    if (j < s) red[j] += red[j + s];
    __syncthreads();
  }
  if (j == 0) c3[p] = red[0];
  for (int k = j; k < 768; k += 256) {
    const float4* fr = reinterpret_cast<const float4*>(fcw + k * 256);
    const float4* p2 = reinterpret_cast<const float4*>(p2row);
    float4 a4 = make_float4(0.f, 0.f, 0.f, 0.f);
    for (int j4 = 0; j4 < 64; j4++) {
      float4 a = p2[j4], b = fr[j4];
      a4.x += a.x * b.x; a4.y += a.y * b.y; a4.z += a.z * b.z; a4.w += a.w * b.w;
    }
    P3[p * 768 + k] = (a4.x + a4.y) + (a4.z + a4.w);
  }
}

// ---------------- Kernel 1b: fused xsum -> ks -> v (8 samples/block, 168 blocks) ----------------
#define MBX 8
__global__ __launch_bounds__(512) void attn_b_kernel(
    const float* __restrict__ x, const float* __restrict__ wk,
    const float* __restrict__ wqT, float* __restrict__ v) {
  __shared__ __align__(16) float pesum[500];
  __shared__ __align__(16) float xs[MBX * 500];
  __shared__ __align__(16) float ks_t[256 * MBX];
  const int blk = blockIdx.x, t = threadIdx.x;

  if (t < 125) {
    float div0 = expf((float)(4 * t) * C500);
    float div1 = expf((float)(4 * t + 2) * C500);
    float s0 = 0.f, c0 = 0.f, s1 = 0.f, c1 = 0.f;
#pragma unroll
    for (int s = 0; s < SECN; s++) {
      float a0 = (float)s * div0, a1 = (float)s * div1;
      s0 += sinf(a0); c0 += cosf(a0);
      s1 += sinf(a1); c1 += cosf(a1);
    }
    reinterpret_cast<float4*>(pesum)[t] = make_float4(s0, c0, s1, c1);
  }
  __syncthreads();

  for (int e = t; e < MBX * 125; e += 512) {
    int m = e / 125, h4 = e % 125;
    const float4* xr = reinterpret_cast<const float4*>(x) + (blk * MBX + m) * 750;
    float4 a = xr[h4];
#pragma unroll
    for (int s = 1; s < SECN; s++) {
      float4 b = xr[s * 125 + h4];
      a.x += b.x; a.y += b.y; a.z += b.z; a.w += b.w;
    }
    float4 pe = reinterpret_cast<float4*>(pesum)[h4];
    a.x += pe.x; a.y += pe.y; a.z += pe.z; a.w += pe.w;
    reinterpret_cast<float4*>(xs)[m * 125 + h4] = a;
  }
  __syncthreads();

  // phase A: ks_t[c][m] = sum_i xs[m][i] * wk[i][c]  (coalesced wk, m split 2-way)
  {
    int c = t & 255, mh = t >> 8;
    float acc[4];
#pragma unroll
    for (int m = 0; m < 4; m++) acc[m] = 0.f;
    const float4* xsb = reinterpret_cast<const float4*>(xs) + mh * 4 * 125;
    for (int i4 = 0; i4 < 125; i4++) {
      int i = i4 * 4;
      float w0 = wk[(i + 0) * 256 + c];
      float w1 = wk[(i + 1) * 256 + c];
      float w2 = wk[(i + 2) * 256 + c];
      float w3 = wk[(i + 3) * 256 + c];
#pragma unroll
      for (int m = 0; m < 4; m++) {
        float4 xv = xsb[m * 125 + i4];
        acc[m] += xv.x * w0 + xv.y * w1 + xv.z * w2 + xv.w * w3;
      }
    }
#pragma unroll
    for (int m = 0; m < 4; m++)
      ks_t[c * MBX + mh * 4 + m] = acc[m];
  }
  __syncthreads();

  // phase B: v[m][n][h] = sum_c wqT[n*128+c][h] * ks_t[n*128+c][m]  (coalesced wqT)
  if (t < 500) {
    int h = t;
#pragma unroll
    for (int n = 0; n < 2; n++) {
      float acc[MBX];
#pragma unroll
      for (int m = 0; m < MBX; m++) acc[m] = 0.f;
      const float* wcol = wqT + (n * 128) * 500 + h;
      const floatx4* ktb = (const floatx4*)ks_t + n * 128 * 2;
      for (int c = 0; c < 128; c++) {
        float w = wcol[c * 500];
        floatx4 k0 = ktb[c * 2 + 0], k1 = ktb[c * 2 + 1];
        acc[0] += w * k0[0]; acc[1] += w * k0[1]; acc[2] += w * k0[2]; acc[3] += w * k0[3];
        acc[4] += w * k1[0]; acc[5] += w * k1[1]; acc[6] += w * k1[2]; acc[7] += w * k1[3];
      }
#pragma unroll
      for (int m = 0; m < MBX; m++)
        v[((blk * MBX + m) * 2 + n) * 500 + h] = acc[m];
    }
  }
}

// ---------------- Kernel 1c: logits = (x+pe).v + gumbel -> argmax ----------------
__global__ __launch_bounds__(192) void attn_c_kernel(
    const float* __restrict__ x, const float* __restrict__ v,
    const float* __restrict__ gumbel, int* __restrict__ sec_idx) {
  __shared__ float lgsh[NN][SECN];
  const int bs = blockIdx.x, t = threadIdx.x;
  const int s = t >> 5, lane = t & 31;
  const float4* x4 = reinterpret_cast<const float4*>(x) + bs * 750 + s * 125;
  const float4* v0 = reinterpret_cast<const float4*>(v) + bs * 250;
  const float4* v1 = v0 + 125;
  float a0 = 0.f, a1 = 0.f;
  for (int h4 = lane; h4 < 125; h4 += 32) {
    float4 xv = x4[h4];
    float div0 = expf((float)(4 * h4) * C500);
    float div1 = expf((float)(4 * h4 + 2) * C500);
    float ang0 = (float)s * div0, ang1 = (float)s * div1;
    xv.x += sinf(ang0); xv.y += cosf(ang0);
    xv.z += sinf(ang1); xv.w += cosf(ang1);
    float4 w0 = v0[h4], w1 = v1[h4];
    a0 += xv.x * w0.x + xv.y * w0.y + xv.z * w0.z + xv.w * w0.w;
    a1 += xv.x * w1.x + xv.y * w1.y + xv.z * w1.z + xv.w * w1.w;
  }
#pragma unroll
  for (int m = 16; m >= 1; m >>= 1) {
    a0 += __shfl_xor(a0, m);
    a1 += __shfl_xor(a1, m);
  }
  if (lane == 0) {
    lgsh[0][s] = a0 * LSCALE + gumbel[(bs * 2 + 0) * SECN + s];
    lgsh[1][s] = a1 * LSCALE + gumbel[(bs * 2 + 1) * SECN + s];
  }
  __syncthreads();
  if (t < 2) {
    int best = 0; float bv = lgsh[t][0];
    for (int i = 1; i < SECN; i++) {
      float q = lgsh[t][i];
      if (q > bv) { bv = q; best = i; }
    }
    sec_idx[bs * 2 + t] = best;
  }
}

// ---------------- Kernel 2: conv encoder (MFMA) + folded VQ argmax (R5 proven) ----------------
// LDS: [0,20800) act1 hi/lo -> act2p hi/lo + featsh/sc25 alias
//      [20800, 53568) in0p -> act2t[128][64] (XOR-swizzled) -> act3t[32][132]
#define CONV_LDS 53568
__global__ __launch_bounds__(256, 3) void conv_kernel(
    const float* __restrict__ x, const int* __restrict__ sec_idx,
    const float* __restrict__ w1, const float* __restrict__ b1,
    const float* __restrict__ bn1g, const float* __restrict__ bn1b,
    const short* __restrict__ w2hi, const short* __restrict__ w2lo,
    const float* __restrict__ b2,
    const float* __restrict__ bn2g, const float* __restrict__ bn2b,
    const short* __restrict__ w3hi, const short* __restrict__ w3lo,
    const float* __restrict__ b3,
    const float* __restrict__ bn3g, const float* __restrict__ bn3b,
    const float* __restrict__ P3, const float* __restrict__ c3,
    int* __restrict__ proto_idx) {
  __shared__ __align__(16) char smem[CONV_LDS];
  short* act1_hi  = (short*)smem;               // [130][40]
  short* act1_lo  = (short*)(smem + 10400);     // [130][40]
  short* act2p_hi = (short*)smem;               // [34][72]
  short* act2p_lo = (short*)(smem + 4896);      // [34][72]
  float* featsh   = (float*)(smem + 9792);      // [768] (alias, phases 6-7)
  float* sc25     = (float*)(smem + 12864);     // [25]
  float* in0p  = (float*)(smem + 20800);        // [512]
  float* act2t = (float*)(smem + 20800);        // [128][64] swizzled
  float* act3t = (float*)(smem + 20800);        // [32][132]

  const int sample = blockIdx.x;
  const int t = threadIdx.x;
  const int bsIdx = sample >> 1;
  const float bnscale = rsqrtf(1.0f + 1e-5f);
  const int wv = t >> 6, l = t & 63, lr = l & 15, lg2 = l >> 4;

  // ---- phase 1: load x section (padded), zero act1 pad rows ----
  {
    int sec = sec_idx[sample];
    const float* src = &x[bsIdx * NSAMP + sec * HID];
    for (int i = t; i < 512; i += 256) in0p[i] = (i >= 1 && i <= 500) ? src[i - 1] : 0.f;
    if (t < 200) {
      int r = t / 40; r = (r == 0) ? 0 : 125 + r;   // rows 0,126..129
      int idx = r * 40 + t % 40;
      act1_hi[idx] = 0; act1_lo[idx] = 0;
    }
  }
  __syncthreads();

  // ---- phase 2: conv1 + relu + pool4 + bn -> act1 hi/lo bf16 [pos+1][ic] ----
  {
    int ic = t & 31;
    float w0 = w1[ic * 3], w1v = w1[ic * 3 + 1], w2v = w1[ic * 3 + 2];
    float bb = b1[ic];
    float g = bn1g[ic] * bnscale, be = bn1b[ic];
    for (int p = t >> 5; p < 125; p += 8) {
      int base = 4 * p;
      float xm1 = in0p[base], x0 = in0p[base + 1], x1 = in0p[base + 2],
            x2 = in0p[base + 3], x3 = in0p[base + 4], x4 = in0p[base + 5];
      float a0 = bb + w0 * xm1 + w1v * x0 + w2v * x1;
      float a1 = bb + w0 * x0  + w1v * x1 + w2v * x2;
      float a2 = bb + w0 * x1  + w1v * x2 + w2v * x3;
      float a3 = bb + w0 * x2  + w1v * x3 + w2v * x4;
      float m = fmaxf(fmaxf(fmaxf(fmaxf(a0, a1), a2), a3), 0.f);
      float v = m * g + be;
      short hi = f2bf(v);
      short lo = f2bf(v - bf2f(hi));
      act1_hi[(p + 1) * 40 + ic] = hi;
      act1_lo[(p + 1) * 40 + ic] = lo;
    }
  }
  __syncthreads();

  // ---- phase 3: conv2 MFMA  C[64ch][128pos] = W2[64][96] @ B2 ----
  {
    floatx4 acc[4][2];
#pragma unroll
    for (int m = 0; m < 4; m++)
#pragma unroll
      for (int nn = 0; nn < 2; nn++) acc[m][nn] = (floatx4){0.f, 0.f, 0.f, 0.f};
#pragma unroll
    for (int s = 0; s < 3; s++) {
      short8 Ah[4], Al[4], Bh[2], Bl[2];
#pragma unroll
      for (int m = 0; m < 4; m++) {
        int aoff = (m * 16 + lr) * 96 + s * 32 + lg2 * 8;
        Ah[m] = *(const short8*)(w2hi + aoff);
        Al[m] = *(const short8*)(w2lo + aoff);
      }
#pragma unroll
      for (int nn = 0; nn < 2; nn++) {
        int boff = ((2 * wv + nn) * 16 + lr + s) * 40 + lg2 * 8;
        Bh[nn] = *(const short8*)(act1_hi + boff);
        Bl[nn] = *(const short8*)(act1_lo + boff);
      }
#pragma unroll
      for (int m = 0; m < 4; m++)
#pragma unroll
        for (int nn = 0; nn < 2; nn++) {
          acc[m][nn] = __builtin_amdgcn_mfma_f32_16x16x32_bf16(Ah[m], Bh[nn], acc[m][nn], 0, 0, 0);
          acc[m][nn] = __builtin_amdgcn_mfma_f32_16x16x32_bf16(Ah[m], Bl[nn], acc[m][nn], 0, 0, 0);
          acc[m][nn] = __builtin_amdgcn_mfma_f32_16x16x32_bf16(Al[m], Bh[nn], acc[m][nn], 0, 0, 0);
        }
    }
    // swizzled store: element (pos p, ch m*16+lg2*4+j) at p*64 + ((m*4+lg2)^(p&15))*4 + j
#pragma unroll
    for (int m = 0; m < 4; m++)
#pragma unroll
      for (int nn = 0; nn < 2; nn++) {
        int p = (2 * wv + nn) * 16 + lr;
        int swz = (m * 4 + lg2) ^ lr;    // p&15 == lr
        *(floatx4*)(act2t + p * 64 + swz * 4) = acc[m][nn];
      }
  }
  __syncthreads();

  // ---- phase 4: pool5 + bias + relu + bn -> act2p hi/lo; zero pads ----
  {
    if (t < 162) {
      for (int i = t; i < 648; i += 162) {
        int r = i / 72; r = (r == 0) ? 0 : 25 + r;
        int idx = r * 72 + i % 72;
        act2p_hi[idx] = 0; act2p_lo[idx] = 0;
      }
    }
    int ic = t & 63;
    float bb = b2[ic], g = bn2g[ic] * bnscale, be = bn2b[ic];
#define A2T(r, c) act2t[(r) * 64 + ((((c) >> 2) ^ ((r) & 15)) << 2) + ((c) & 3)]
    for (int pw = t >> 6; pw < 25; pw += 4) {
      int base = 5 * pw;
      float m = A2T(base, ic);
      m = fmaxf(m, A2T(base + 1, ic));
      m = fmaxf(m, A2T(base + 2, ic));
      m = fmaxf(m, A2T(base + 3, ic));
      m = fmaxf(m, A2T(base + 4, ic));
      float v = fmaxf(m + bb, 0.f) * g + be;
      short hi = f2bf(v);
      short lo = f2bf(v - bf2f(hi));
      act2p_hi[(pw + 1) * 72 + ic] = hi;
      act2p_lo[(pw + 1) * 72 + ic] = lo;
    }
#undef A2T
  }
  __syncthreads();

  // ---- phase 5: conv3 MFMA  C[128ch][32pos] = W3[128][192] @ B3 ----
  {
    floatx4 acc[2][2];
#pragma unroll
    for (int mm = 0; mm < 2; mm++)
#pragma unroll
      for (int nn = 0; nn < 2; nn++) acc[mm][nn] = (floatx4){0.f, 0.f, 0.f, 0.f};
#pragma unroll
    for (int s = 0; s < 6; s++) {
      short8 Ah[2], Al[2], Bh[2], Bl[2];
#pragma unroll
      for (int mm = 0; mm < 2; mm++) {
        int aoff = ((wv * 2 + mm) * 16 + lr) * 192 + s * 32 + lg2 * 8;
        Ah[mm] = *(const short8*)(w3hi + aoff);
        Al[mm] = *(const short8*)(w3lo + aoff);
      }
#pragma unroll
      for (int nn = 0; nn < 2; nn++) {
        int boff = (nn * 16 + lr + (s >> 1)) * 72 + (s & 1) * 32 + lg2 * 8;
        Bh[nn] = *(const short8*)(act2p_hi + boff);
        Bl[nn] = *(const short8*)(act2p_lo + boff);
      }
#pragma unroll
      for (int mm = 0; mm < 2; mm++)
#pragma unroll
        for (int nn = 0; nn < 2; nn++) {
          acc[mm][nn] = __builtin_amdgcn_mfma_f32_16x16x32_bf16(Ah[mm], Bh[nn], acc[mm][nn], 0, 0, 0);
          acc[mm][nn] = __builtin_amdgcn_mfma_f32_16x16x32_bf16(Ah[mm], Bl[nn], acc[mm][nn], 0, 0, 0);
          acc[mm][nn] = __builtin_amdgcn_mfma_f32_16x16x32_bf16(Al[mm], Bh[nn], acc[mm][nn], 0, 0, 0);
        }
    }
#pragma unroll
    for (int mm = 0; mm < 2; mm++)
#pragma unroll
      for (int nn = 0; nn < 2; nn++) {
        int p = nn * 16 + lr;
        *(floatx4*)(act3t + p * 132 + (wv * 2 + mm) * 16 + lg2 * 4) = acc[mm][nn];
      }
  }
  __syncthreads();

  // ---- phase 6: pool4(first 24) + bias + relu + bn -> featsh (LDS) ----
  {
    int c = t & 127;
    float bb = b3[c], g = bn3g[c] * bnscale, be = bn3b[c];
    for (int pw = t >> 7; pw < 6; pw += 2) {
      int base = 4 * pw;
      float m = act3t[base * 132 + c];
      m = fmaxf(m, act3t[(base + 1) * 132 + c]);
      m = fmaxf(m, act3t[(base + 2) * 132 + c]);
      m = fmaxf(m, act3t[(base + 3) * 132 + c]);
      float v = fmaxf(m + bb, 0.f) * g + be;
      featsh[c * 6 + pw] = v;
    }
  }
  __syncthreads();

  // ---- phase 7: folded VQ scores + argmax -> proto_idx ----
  if (t < NPROTO * 8) {
    int p = t >> 3, part = t & 7;
    const float4* pr = reinterpret_cast<const float4*>(P3 + p * 768 + part * 96);
    const float4* fr = reinterpret_cast<const float4*>(featsh + part * 96);
    float4 a4 = make_float4(0.f, 0.f, 0.f, 0.f);
#pragma unroll
    for (int i = 0; i < 24; i++) {
      float4 w = pr[i], f = fr[i];
      a4.x += w.x * f.x; a4.y += w.y * f.y; a4.z += w.z * f.z; a4.w += w.w * f.w;
    }
    float a = (a4.x + a4.y) + (a4.z + a4.w);
    a += __shfl_xor(a, 1);
    a += __shfl_xor(a, 2);
    a += __shfl_xor(a, 4);
    if (part == 0) sc25[p] = a + c3[p];
  }
  __syncthreads();
  if (t == 0) {
    int best = 0; float bv = sc25[0];
    for (int i = 1; i < NPROTO; i++) {
      float v = sc25[i];
      if (v > bv) { bv = v; best = i; }
    }
    proto_idx[sample] = best;
  }
}

// ---------------- Kernel 3: sequence transformer + classifier ----------------
__global__ __launch_bounds__(512) void seq_kernel(
    const int* __restrict__ proto_idx, const float* __restrict__ protos,
    const float* __restrict__ inw, const float* __restrict__ inb,
    const float* __restrict__ outw, const float* __restrict__ outb,
    const float* __restrict__ ln1g, const float* __restrict__ ln1b,
    const float* __restrict__ ln2g, const float* __restrict__ ln2b,
    const float* __restrict__ ff1w, const float* __restrict__ ff1b,
    const float* __restrict__ ff2w, const float* __restrict__ ff2b,
    const float* __restrict__ clfw, const float* __restrict__ clfb,
    float* __restrict__ out) {
  __shared__ __align__(16) float hsh[SS * OUTD];
  __shared__ __align__(16) float big[SS * 3 * OUTD];
  __shared__ __align__(16) float sc[NHEAD * SS * SS];
  __shared__ __align__(16) float ctx[SS * OUTD];
  __shared__ float rowm[SS], rowv[SS];

  const int b = blockIdx.x;
  const int t = threadIdx.x;

  for (int o = t; o < SS * OUTD; o += 512) {
    int s = o >> 7, d = o & 127;
    int i0 = proto_idx[(b * SS + s) * 2];
    int i1 = proto_idx[(b * SS + s) * 2 + 1];
    float pc = 0.5f * (protos[i0 * OUTD + d] + protos[i1 * OUTD + d]);
    int i = d >> 1;
    float div = expf((float)(2 * i) * -0.07195578415606439f);
    float ang = (float)s * div;
    float pe = (d & 1) ? cosf(ang) : sinf(ang);
    hsh[o] = pc + pe;
  }
  __syncthreads();

  for (int o = t; o < SS * 384; o += 512) {
    int s = o / 384, j = o % 384;
    float4 a4 = make_float4(0.f, 0.f, 0.f, 0.f);
    const float4* hr = reinterpret_cast<const float4*>(&hsh[s * OUTD]);
    for (int d4 = 0; d4 < 32; d4++) {
      float4 h4 = hr[d4];
      int d = d4 * 4;
      a4.x += h4.x * inw[(d + 0) * 384 + j];
      a4.y += h4.y * inw[(d + 1) * 384 + j];
      a4.z += h4.z * inw[(d + 2) * 384 + j];
      a4.w += h4.w * inw[(d + 3) * 384 + j];
    }
    big[o] = inb[j] + ((a4.x + a4.y) + (a4.z + a4.w));
  }
  __syncthreads();

  for (int o = t; o < NHEAD * SS * SS; o += 512) {
    int hd = o / (SS * SS), r = o % (SS * SS), qs = r / SS, ks = r % SS;
    const float4* qp = reinterpret_cast<const float4*>(&big[qs * 384 + hd * 32]);
    const float4* kp = reinterpret_cast<const float4*>(&big[ks * 384 + 128 + hd * 32]);
    float4 a4 = make_float4(0.f, 0.f, 0.f, 0.f);
#pragma unroll
    for (int d4 = 0; d4 < 8; d4++) {
      float4 q4 = qp[d4], k4 = kp[d4];
      a4.x += q4.x * k4.x; a4.y += q4.y * k4.y; a4.z += q4.z * k4.z; a4.w += q4.w * k4.w;
    }
    sc[o] = ((a4.x + a4.y) + (a4.z + a4.w)) * 0.17677669529663689f;
  }
  __syncthreads();
  for (int r = t; r < NHEAD * SS; r += 512) {
    float* row = &sc[r * SS];
    float mx = row[0];
    for (int i = 1; i < SS; i++) mx = fmaxf(mx, row[i]);
    float sum = 0.f;
    for (int i = 0; i < SS; i++) { float e = expf(row[i] - mx); row[i] = e; sum += e; }
    float inv = 1.f / sum;
    for (int i = 0; i < SS; i++) row[i] *= inv;
  }
  __syncthreads();
  for (int o = t; o < SS * OUTD; o += 512) {
    int qs = o >> 7, d = o & 127, hd = d >> 5, dd = d & 31;
    const float* srow = &sc[(hd * SS + qs) * SS];
    float a = 0.f;
    for (int ks = 0; ks < SS; ks++) a += srow[ks] * big[ks * 384 + 256 + hd * 32 + dd];
    ctx[o] = a;
  }
  __syncthreads();
  float* tmp = big;
  for (int o = t; o < SS * OUTD; o += 512) {
    int s = o >> 7, d = o & 127;
    float4 a4 = make_float4(0.f, 0.f, 0.f, 0.f);
    const float4* cr = reinterpret_cast<const float4*>(&ctx[s * OUTD]);
    for (int e4 = 0; e4 < 32; e4++) {
      float4 c4 = cr[e4];
      int e = e4 * 4;
      a4.x += c4.x * outw[(e + 0) * OUTD + d];
      a4.y += c4.y * outw[(e + 1) * OUTD + d];
      a4.z += c4.z * outw[(e + 2) * OUTD + d];
      a4.w += c4.w * outw[(e + 3) * OUTD + d];
    }
    tmp[o] = hsh[o] + outb[d] + ((a4.x + a4.y) + (a4.z + a4.w));
  }
  __syncthreads();
  if (t < SS) {
    const float4* r4 = reinterpret_cast<const float4*>(&tmp[t * OUTD]);
    float4 m4 = make_float4(0.f, 0.f, 0.f, 0.f);
    for (int d4 = 0; d4 < 32; d4++) {
      float4 v = r4[d4];
      m4.x += v.x; m4.y += v.y; m4.z += v.z; m4.w += v.w;
    }
    float m = ((m4.x + m4.y) + (m4.z + m4.w)) * (1.0f / OUTD);
    float4 v4 = make_float4(0.f, 0.f, 0.f, 0.f);
    for (int d4 = 0; d4 < 32; d4++) {
      float4 v = r4[d4];
      float ux = v.x - m, uy = v.y - m, uz = v.z - m, uw = v.w - m;
      v4.x += ux * ux; v4.y += uy * uy; v4.z += uz * uz; v4.w += uw * uw;
    }
    float var = ((v4.x + v4.y) + (v4.z + v4.w)) * (1.0f / OUTD);
    rowm[t] = m; rowv[t] = rsqrtf(var + 1e-5f);
  }
  __syncthreads();
  for (int o = t; o < SS * OUTD; o += 512) {
    int s = o >> 7, d = o & 127;
    hsh[o] = (tmp[o] - rowm[s]) * rowv[s] * ln1g[d] + ln1b[d];
  }
  __syncthreads();
  for (int o = t; o < SS * OUTD; o += 512) {
    int s = o >> 7, d = o & 127;
    float4 a4 = make_float4(0.f, 0.f, 0.f, 0.f);
    const float4* hr = reinterpret_cast<const float4*>(&hsh[s * OUTD]);
    for (int e4 = 0; e4 < 32; e4++) {
      float4 h4 = hr[e4];
      int e = e4 * 4;
      a4.x += h4.x * ff1w[(e + 0) * OUTD + d];
      a4.y += h4.y * ff1w[(e + 1) * OUTD + d];
      a4.z += h4.z * ff1w[(e + 2) * OUTD + d];
      a4.w += h4.w * ff1w[(e + 3) * OUTD + d];
    }
    ctx[o] = fmaxf(ff1b[d] + ((a4.x + a4.y) + (a4.z + a4.w)), 0.f);
  }
  __syncthreads();
  for (int o = t; o < SS * OUTD; o += 512) {
    int s = o >> 7, d = o & 127;
    float4 a4 = make_float4(0.f, 0.f, 0.f, 0.f);
    const float4* cr = reinterpret_cast<const float4*>(&ctx[s * OUTD]);
    for (int e4 = 0; e4 < 32; e4++) {
      float4 c4 = cr[e4];
      int e = e4 * 4;
      a4.x += c4.x * ff2w[(e + 0) * OUTD + d];
      a4.y += c4.y * ff2w[(e + 1) * OUTD + d];
      a4.z += c4.z * ff2w[(e + 2) * OUTD + d];
      a4.w += c4.w * ff2w[(e + 3) * OUTD + d];
    }
    tmp[o] = hsh[o] + ff2b[d] + ((a4.x + a4.y) + (a4.z + a4.w));
  }
  __syncthreads();
  if (t < SS) {
    const float4* r4 = reinterpret_cast<const float4*>(&tmp[t * OUTD]);
    float4 m4 = make_float4(0.f, 0.f, 0.f, 0.f);
    for (int d4 = 0; d4 < 32; d4++) {
      float4 v = r4[d4];
      m4.x += v.x; m4.y += v.y; m4.z += v.z; m4.w += v.w;
    }
    float m = ((m4.x + m4.y) + (m4.z + m4.w)) * (1.0f / OUTD);
    float4 v4 = make_float4(0.f, 0.f, 0.f, 0.f);
    for (int d4 = 0; d4 < 32; d4++) {
      float4 v = r4[d4];
      float ux = v.x - m, uy = v.y - m, uz = v.z - m, uw = v.w - m;
      v4.x += ux * ux; v4.y += uy * uy; v4.z += uz * uz; v4.w += uw * uw;
    }
    float var = ((v4.x + v4.y) + (v4.z + v4.w)) * (1.0f / OUTD);
    rowm[t] = m; rowv[t] = rsqrtf(var + 1e-5f);
  }
  __syncthreads();
  for (int o = t; o < SS * OUTD; o += 512) {
    int s = o >> 7, d = o & 127;
    hsh[o] = (tmp[o] - rowm[s]) * rowv[s] * ln2g[d] + ln2b[d];
  }
  __syncthreads();
  for (int o = t; o < SS * NCLS; o += 512) {
    int s = o / NCLS, c = o % NCLS;
    float4 a4 = make_float4(0.f, 0.f, 0.f, 0.f);
    const float4* hr = reinterpret_cast<const float4*>(&hsh[s * OUTD]);
    for (int d4 = 0; d4 < 32; d4++) {
      float4 h4 = hr[d4];
      int d = d4 * 4;
      a4.x += h4.x * clfw[(d + 0) * NCLS + c];
      a4.y += h4.y * clfw[(d + 1) * NCLS + c];
      a4.z += h4.z * clfw[(d + 2) * NCLS + c];
      a4.w += h4.w * clfw[(d + 3) * NCLS + c];
    }
    out[(b * SS + s) * NCLS + c] = clfb[c] + ((a4.x + a4.y) + (a4.z + a4.w));
  }
}

extern "C" void kernel_launch(void* const* d_in, const int* in_sizes, int n_in,
                              void* d_out, int out_size, void* d_ws, size_t ws_size,
                              hipStream_t stream) {
  const float* x     = (const float*)d_in[0];
  const float* gum   = (const float*)d_in[1];
  const float* wq    = (const float*)d_in[2];
  const float* wk    = (const float*)d_in[3];
  const float* w1    = (const float*)d_in[4];
  const float* b1    = (const float*)d_in[5];
  const float* bn1g  = (const float*)d_in[6];
  const float* bn1b  = (const float*)d_in[7];
  const float* w2    = (const float*)d_in[8];
  const float* b2    = (const float*)d_in[9];
  const float* bn2g  = (const float*)d_in[10];
  const float* bn2b  = (const float*)d_in[11];
  const float* w3    = (const float*)d_in[12];
  const float* b3    = (const float*)d_in[13];
  const float* bn3g  = (const float*)d_in[14];
  const float* bn3b  = (const float*)d_in[15];
  const float* fcw   = (const float*)d_in[16];
  const float* fcb   = (const float*)d_in[17];
  const float* fc2w  = (const float*)d_in[18];
  const float* fc2b  = (const float*)d_in[19];
  const float* prot  = (const float*)d_in[20];
  const float* inw   = (const float*)d_in[21];
  const float* inb   = (const float*)d_in[22];
  const float* outw  = (const float*)d_in[23];
  const float* outb  = (const float*)d_in[24];
  const float* ln1g  = (const float*)d_in[25];
  const float* ln1b  = (const float*)d_in[26];
  const float* ln2g  = (const float*)d_in[27];
  const float* ln2b  = (const float*)d_in[28];
  const float* ff1w  = (const float*)d_in[29];
  const float* ff1b  = (const float*)d_in[30];
  const float* ff2w  = (const float*)d_in[31];
  const float* ff2b  = (const float*)d_in[32];
  const float* clfw  = (const float*)d_in[33];
  const float* clfb  = (const float*)d_in[34];
  float* out = (float*)d_out;

  int* sec_idx   = (int*)d_ws;
  int* proto_idx = sec_idx + NSAMPLE;
  short* w2hi = (short*)((float*)d_ws + WS_W2HI);
  short* w2lo = (short*)((float*)d_ws + WS_W2LO);
  short* w3hi = (short*)((float*)d_ws + WS_W3HI);
  short* w3lo = (short*)((float*)d_ws + WS_W3LO);
  float* P3   = (float*)d_ws + WS_P3;
  float* c3   = (float*)d_ws + WS_C3;
  float* wqT  = (float*)d_ws + WS_WQT;
  float* vbuf = (float*)d_ws + WS_V;

  hipLaunchKernelGGL(prep_all_kernel, dim3(177), dim3(256), 0, stream,
                     w2, w3, w2hi, w2lo, w3hi, w3lo,
                     prot, fc2w, fcw, fcb, fc2b, P3, c3, wq, wqT);
  hipLaunchKernelGGL(attn_b_kernel, dim3(BS / MBX), dim3(512), 0, stream,
                     x, wk, wqT, vbuf);
  hipLaunchKernelGGL(attn_c_kernel, dim3(BS), dim3(192), 0, stream,
                     x, vbuf, gum, sec_idx);
  hipLaunchKernelGGL(conv_kernel, dim3(NSAMPLE), dim3(256), 0, stream,
                     x, sec_idx, w1, b1, bn1g, bn1b, w2hi, w2lo, b2, bn2g, bn2b,
                     w3hi, w3lo, b3, bn3g, bn3b, P3, c3, proto_idx);
  hipLaunchKernelGGL(seq_kernel, dim3(BB), dim3(512), 0, stream,
                     proto_idx, prot, inw, inb, outw, outb,
                     ln1g, ln1b, ln2g, ln2b, ff1w, ff1b, ff2w, ff2b,
                     clfw, clfb, out);
}

// Round 9
// 226.002 us; speedup vs baseline: 3.7622x; 1.0916x over previous
//
#include <hip/hip_runtime.h>
#include <math.h>

#define BB 64
#define SS 21
#define NSAMP 3000
#define HID 500
#define SECN 6
#define NN 2
#define OUTD 128
#define NPROTO 25
#define NCLS 5
#define NHEAD 4
#define BS (BB*SS)          // 1344
#define NSAMPLE (BS*NN)     // 2688

#define C500 (-0.0184206807439523674f)   // -ln(1e4)/500
#define LSCALE 0.00745355992499929898f   // 1/(6*sqrt(500))

// ws float offsets
#define WS_W2HI 5376
#define WS_W2LO 8448
#define WS_W3HI 11520
#define WS_W3LO 23808
#define WS_P3   36096
#define WS_C3   55296
#define WS_WQT  55424
#define WS_V    727424

typedef __attribute__((ext_vector_type(8))) short short8;
typedef __attribute__((ext_vector_type(4))) float floatx4;

__device__ __forceinline__ short f2bf(float f) {
  unsigned u = __float_as_uint(f);
  u += 0x7FFF + ((u >> 16) & 1);          // RNE to bf16
  return (short)(u >> 16);
}
__device__ __forceinline__ float bf2f(short h) {
  return __uint_as_float(((unsigned)(unsigned short)h) << 16);
}

// ---------------- Kernel 0: weight splits (MFMA-fragment order) + VQ prep + wq transpose ----------------
// w2 layout: [s=3][m=4][lane=64][e=8]  addr = ((s*4+m)*64 + lane)*8 + e
//            lane = lg2*16+lr ; fragment row = m*16+lr ; K = s*32 + lg2*8 + e
// w3 layout: [s=6][g=8][lane=64][e=8]  addr = ((s*8+g)*64 + lane)*8 + e
__global__ __launch_bounds__(256) void prep_all_kernel(
    const float* __restrict__ w2, const float* __restrict__ w3,
    short* __restrict__ w2hi, short* __restrict__ w2lo,
    short* __restrict__ w3hi, short* __restrict__ w3lo,
    const float* __restrict__ protos, const float* __restrict__ fc2w,
    const float* __restrict__ fcw, const float* __restrict__ fcb,
    const float* __restrict__ fc2b,
    float* __restrict__ P3, float* __restrict__ c3,
    const float* __restrict__ wq, float* __restrict__ wqT) {
  __shared__ __align__(16) float p2row[256];
  __shared__ float red[256];
  __shared__ float tile[64][65];
  const int t = threadIdx.x;
  if (blockIdx.x < 120) {
    int idx = blockIdx.x * 256 + t;
    if (idx < 6144) {
      // enumerate (c in 0..63, ic in 0..31, k in 0..2)
      int ic = idx & 31, ck = idx >> 5, k = ck % 3, c = ck / 3;
      float v = w2[c * 96 + ic * 3 + k];
      // s = k, lg2 = ic>>3, e = ic&7, m = c>>4, lr = c&15
      int dst = (((k * 4 + (c >> 4)) * 64) + ((ic >> 3) * 16 + (c & 15))) * 8 + (ic & 7);
      short hi = f2bf(v);
      short lo = f2bf(v - bf2f(hi));
      w2hi[dst] = hi; w2lo[dst] = lo;
    } else if (idx < 30720) {
      int j = idx - 6144;
      // enumerate (c in 0..127, ic in 0..63, k in 0..2)
      int ic = j & 63, ck = j >> 6, k = ck % 3, c = ck / 3;
      float v = w3[(c * 64 + ic) * 3 + k];
      // K = k*64+ic: s = k*2 + (ic>>5), lg2 = (ic&31)>>3, e = ic&7, g = c>>4, lr = c&15
      int s = k * 2 + (ic >> 5);
      int dst = (((s * 8 + (c >> 4)) * 64) + (((ic & 31) >> 3) * 16 + (c & 15))) * 8 + (ic & 7);
      short hi = f2bf(v);
      short lo = f2bf(v - bf2f(hi));
      w3hi[dst] = hi; w3lo[dst] = lo;
    }
    return;
  }
  if (blockIdx.x >= 145) {               // wq transpose: 32 tile-blocks
    int tid = blockIdx.x - 145;
    int h0 = (tid >> 2) * 64, c0 = (tid & 3) * 64;
    for (int e = t; e < 4096; e += 256) {
      int i = e >> 6, j = e & 63;        // i: h-off, j: c-off
      if (h0 + i < 500) tile[j][i] = wq[(h0 + i) * 256 + c0 + j];
    }
    __syncthreads();
    for (int e = t; e < 4096; e += 256) {
      int c = e >> 6, hh = e & 63;
      if (h0 + hh < 500) wqT[(c0 + c) * 500 + h0 + hh] = tile[c][hh];
    }
    return;
  }
  const int p = blockIdx.x - 120, j = t;
  {
    const float4* pr = reinterpret_cast<const float4*>(protos + p * 128);
    const float4* wr = reinterpret_cast<const float4*>(fc2w + j * 128);
    float4 a4 = make_float4(0.f, 0.f, 0.f, 0.f);
    for (int c4 = 0; c4 < 32; c4++) {
      float4 a = pr[c4], b = wr[c4];
      a4.x += a.x * b.x; a4.y += a.y * b.y; a4.z += a.z * b.z; a4.w += a.w * b.w;
    }
    float v = (a4.x + a4.y) + (a4.z + a4.w);
    p2row[j] = v;
    float contrib = v * fcb[j];
    if (j < 128) {
      float pv = protos[p * 128 + j];
      contrib += pv * fc2b[j] - 0.5f * pv * pv;
    }
    red[j] = contrib;
  }
  __syncthreads();
  for (int s = 128; s > 0; s >>= 1) {
    if (j < s) red[j] += red[j + s];
    __syncthreads();
  }
  if (j == 0) c3[p] = red[0];
  for (int k = j; k < 768; k += 256) {
    const float4* fr = reinterpret_cast<const float4*>(fcw + k * 256);
    const float4* p2 = reinterpret_cast<const float4*>(p2row);
    float4 a4 = make_float4(0.f, 0.f, 0.f, 0.f);
    for (int j4 = 0; j4 < 64; j4++) {
      float4 a = p2[j4], b = fr[j4];
      a4.x += a.x * b.x; a4.y += a.y * b.y; a4.z += a.z * b.z; a4.w += a.w * b.w;
    }
    P3[p * 768 + k] = (a4.x + a4.y) + (a4.z + a4.w);
  }
}

// ---------------- Kernel 1b: fused xsum -> ks -> v (8 samples/block, 168 blocks) ----------------
#define MBX 8
__global__ __launch_bounds__(512) void attn_b_kernel(
    const float* __restrict__ x, const float* __restrict__ wk,
    const float* __restrict__ wqT, float* __restrict__ v) {
  __shared__ __align__(16) float pesum[500];
  __shared__ __align__(16) float xs[MBX * 500];
  __shared__ __align__(16) float ks_t[256 * MBX];
  const int blk = blockIdx.x, t = threadIdx.x;

  if (t < 125) {
    float div0 = expf((float)(4 * t) * C500);
    float div1 = expf((float)(4 * t + 2) * C500);
    float s0 = 0.f, c0 = 0.f, s1 = 0.f, c1 = 0.f;
#pragma unroll
    for (int s = 0; s < SECN; s++) {
      float a0 = (float)s * div0, a1 = (float)s * div1;
      s0 += sinf(a0); c0 += cosf(a0);
      s1 += sinf(a1); c1 += cosf(a1);
    }
    reinterpret_cast<float4*>(pesum)[t] = make_float4(s0, c0, s1, c1);
  }
  __syncthreads();

  for (int e = t; e < MBX * 125; e += 512) {
    int m = e / 125, h4 = e % 125;
    const float4* xr = reinterpret_cast<const float4*>(x) + (blk * MBX + m) * 750;
    float4 a = xr[h4];
#pragma unroll
    for (int s = 1; s < SECN; s++) {
      float4 b = xr[s * 125 + h4];
      a.x += b.x; a.y += b.y; a.z += b.z; a.w += b.w;
    }
    float4 pe = reinterpret_cast<float4*>(pesum)[h4];
    a.x += pe.x; a.y += pe.y; a.z += pe.z; a.w += pe.w;
    reinterpret_cast<float4*>(xs)[m * 125 + h4] = a;
  }
  __syncthreads();

  // phase A: ks_t[c][m] = sum_i xs[m][i] * wk[i][c]  (coalesced wk, m split 2-way)
  {
    int c = t & 255, mh = t >> 8;
    float acc[4];
#pragma unroll
    for (int m = 0; m < 4; m++) acc[m] = 0.f;
    const float4* xsb = reinterpret_cast<const float4*>(xs) + mh * 4 * 125;
    for (int i4 = 0; i4 < 125; i4++) {
      int i = i4 * 4;
      float w0 = wk[(i + 0) * 256 + c];
      float w1 = wk[(i + 1) * 256 + c];
      float w2 = wk[(i + 2) * 256 + c];
      float w3 = wk[(i + 3) * 256 + c];
#pragma unroll
      for (int m = 0; m < 4; m++) {
        float4 xv = xsb[m * 125 + i4];
        acc[m] += xv.x * w0 + xv.y * w1 + xv.z * w2 + xv.w * w3;
      }
    }
#pragma unroll
    for (int m = 0; m < 4; m++)
      ks_t[c * MBX + mh * 4 + m] = acc[m];
  }
  __syncthreads();

  // phase B: v[m][n][h] = sum_c wqT[n*128+c][h] * ks_t[n*128+c][m]  (coalesced wqT)
  if (t < 500) {
    int h = t;
#pragma unroll
    for (int n = 0; n < 2; n++) {
      float acc[MBX];
#pragma unroll
      for (int m = 0; m < MBX; m++) acc[m] = 0.f;
      const float* wcol = wqT + (n * 128) * 500 + h;
      const floatx4* ktb = (const floatx4*)ks_t + n * 128 * 2;
      for (int c = 0; c < 128; c++) {
        float w = wcol[c * 500];
        floatx4 k0 = ktb[c * 2 + 0], k1 = ktb[c * 2 + 1];
        acc[0] += w * k0[0]; acc[1] += w * k0[1]; acc[2] += w * k0[2]; acc[3] += w * k0[3];
        acc[4] += w * k1[0]; acc[5] += w * k1[1]; acc[6] += w * k1[2]; acc[7] += w * k1[3];
      }
#pragma unroll
      for (int m = 0; m < MBX; m++)
        v[((blk * MBX + m) * 2 + n) * 500 + h] = acc[m];
    }
  }
}

// ---------------- Kernel 1c: logits = (x+pe).v + gumbel -> argmax ----------------
__global__ __launch_bounds__(192) void attn_c_kernel(
    const float* __restrict__ x, const float* __restrict__ v,
    const float* __restrict__ gumbel, int* __restrict__ sec_idx) {
  __shared__ float lgsh[NN][SECN];
  const int bs = blockIdx.x, t = threadIdx.x;
  const int s = t >> 5, lane = t & 31;
  const float4* x4 = reinterpret_cast<const float4*>(x) + bs * 750 + s * 125;
  const float4* v0 = reinterpret_cast<const float4*>(v) + bs * 250;
  const float4* v1 = v0 + 125;
  float a0 = 0.f, a1 = 0.f;
  for (int h4 = lane; h4 < 125; h4 += 32) {
    float4 xv = x4[h4];
    float div0 = expf((float)(4 * h4) * C500);
    float div1 = expf((float)(4 * h4 + 2) * C500);
    float ang0 = (float)s * div0, ang1 = (float)s * div1;
    xv.x += sinf(ang0); xv.y += cosf(ang0);
    xv.z += sinf(ang1); xv.w += cosf(ang1);
    float4 w0 = v0[h4], w1 = v1[h4];
    a0 += xv.x * w0.x + xv.y * w0.y + xv.z * w0.z + xv.w * w0.w;
    a1 += xv.x * w1.x + xv.y * w1.y + xv.z * w1.z + xv.w * w1.w;
  }
#pragma unroll
  for (int m = 16; m >= 1; m >>= 1) {
    a0 += __shfl_xor(a0, m);
    a1 += __shfl_xor(a1, m);
  }
  if (lane == 0) {
    lgsh[0][s] = a0 * LSCALE + gumbel[(bs * 2 + 0) * SECN + s];
    lgsh[1][s] = a1 * LSCALE + gumbel[(bs * 2 + 1) * SECN + s];
  }
  __syncthreads();
  if (t < 2) {
    int best = 0; float bv = lgsh[t][0];
    for (int i = 1; i < SECN; i++) {
      float q = lgsh[t][i];
      if (q > bv) { bv = q; best = i; }
    }
    sec_idx[bs * 2 + t] = best;
  }
}

// ---------------- Kernel 2: conv encoder (MFMA, coalesced A-fragments) + VQ ----------------
// LDS: [0,20800) act1 hi/lo -> act2p hi/lo + featsh/sc25 alias
//      [20800, 53568) in0p -> act2t[128][64] (XOR-swizzled) -> act3t[32][132]
#define CONV_LDS 53568
__global__ __launch_bounds__(256, 3) void conv_kernel(
    const float* __restrict__ x, const int* __restrict__ sec_idx,
    const float* __restrict__ w1, const float* __restrict__ b1,
    const float* __restrict__ bn1g, const float* __restrict__ bn1b,
    const short* __restrict__ w2hi, const short* __restrict__ w2lo,
    const float* __restrict__ b2,
    const float* __restrict__ bn2g, const float* __restrict__ bn2b,
    const short* __restrict__ w3hi, const short* __restrict__ w3lo,
    const float* __restrict__ b3,
    const float* __restrict__ bn3g, const float* __restrict__ bn3b,
    const float* __restrict__ P3, const float* __restrict__ c3,
    int* __restrict__ proto_idx) {
  __shared__ __align__(16) char smem[CONV_LDS];
  short* act1_hi  = (short*)smem;               // [130][40]
  short* act1_lo  = (short*)(smem + 10400);     // [130][40]
  short* act2p_hi = (short*)smem;               // [34][72]
  short* act2p_lo = (short*)(smem + 4896);      // [34][72]
  float* featsh   = (float*)(smem + 9792);      // [768] (alias, phases 6-7)
  float* sc25     = (float*)(smem + 12864);     // [25]
  float* in0p  = (float*)(smem + 20800);        // [512]
  float* act2t = (float*)(smem + 20800);        // [128][64] swizzled
  float* act3t = (float*)(smem + 20800);        // [32][132]

  const int sample = blockIdx.x;
  const int t = threadIdx.x;
  const int bsIdx = sample >> 1;
  const float bnscale = rsqrtf(1.0f + 1e-5f);
  const int wv = t >> 6, l = t & 63, lr = l & 15, lg2 = l >> 4;

  // ---- phase 1: load x section (padded), zero act1 pad rows ----
  {
    int sec = sec_idx[sample];
    const float* src = &x[bsIdx * NSAMP + sec * HID];
    for (int i = t; i < 512; i += 256) in0p[i] = (i >= 1 && i <= 500) ? src[i - 1] : 0.f;
    if (t < 200) {
      int r = t / 40; r = (r == 0) ? 0 : 125 + r;   // rows 0,126..129
      int idx = r * 40 + t % 40;
      act1_hi[idx] = 0; act1_lo[idx] = 0;
    }
  }
  __syncthreads();

  // ---- phase 2: conv1 + relu + pool4 + bn -> act1 hi/lo bf16 [pos+1][ic] ----
  {
    int ic = t & 31;
    float w0 = w1[ic * 3], w1v = w1[ic * 3 + 1], w2v = w1[ic * 3 + 2];
    float bb = b1[ic];
    float g = bn1g[ic] * bnscale, be = bn1b[ic];
    for (int p = t >> 5; p < 125; p += 8) {
      int base = 4 * p;
      float xm1 = in0p[base], x0 = in0p[base + 1], x1 = in0p[base + 2],
            x2 = in0p[base + 3], x3 = in0p[base + 4], x4 = in0p[base + 5];
      float a0 = bb + w0 * xm1 + w1v * x0 + w2v * x1;
      float a1 = bb + w0 * x0  + w1v * x1 + w2v * x2;
      float a2 = bb + w0 * x1  + w1v * x2 + w2v * x3;
      float a3 = bb + w0 * x2  + w1v * x3 + w2v * x4;
      float m = fmaxf(fmaxf(fmaxf(fmaxf(a0, a1), a2), a3), 0.f);
      float v = m * g + be;
      short hi = f2bf(v);
      short lo = f2bf(v - bf2f(hi));
      act1_hi[(p + 1) * 40 + ic] = hi;
      act1_lo[(p + 1) * 40 + ic] = lo;
    }
  }
  __syncthreads();

  // ---- phase 3: conv2 MFMA  C[64ch][128pos] = W2[64][96] @ B2 ----
  {
    floatx4 acc[4][2];
#pragma unroll
    for (int m = 0; m < 4; m++)
#pragma unroll
      for (int nn = 0; nn < 2; nn++) acc[m][nn] = (floatx4){0.f, 0.f, 0.f, 0.f};
#pragma unroll
    for (int s = 0; s < 3; s++) {
      short8 Ah[4], Al[4], Bh[2], Bl[2];
#pragma unroll
      for (int m = 0; m < 4; m++) {
        int aoff = ((s * 4 + m) * 64 + l) * 8;   // coalesced fragment layout
        Ah[m] = *(const short8*)(w2hi + aoff);
        Al[m] = *(const short8*)(w2lo + aoff);
      }
#pragma unroll
      for (int nn = 0; nn < 2; nn++) {
        int boff = ((2 * wv + nn) * 16 + lr + s) * 40 + lg2 * 8;
        Bh[nn] = *(const short8*)(act1_hi + boff);
        Bl[nn] = *(const short8*)(act1_lo + boff);
      }
#pragma unroll
      for (int m = 0; m < 4; m++)
#pragma unroll
        for (int nn = 0; nn < 2; nn++) {
          acc[m][nn] = __builtin_amdgcn_mfma_f32_16x16x32_bf16(Ah[m], Bh[nn], acc[m][nn], 0, 0, 0);
          acc[m][nn] = __builtin_amdgcn_mfma_f32_16x16x32_bf16(Ah[m], Bl[nn], acc[m][nn], 0, 0, 0);
          acc[m][nn] = __builtin_amdgcn_mfma_f32_16x16x32_bf16(Al[m], Bh[nn], acc[m][nn], 0, 0, 0);
        }
    }
    // swizzled store: element (pos p, ch m*16+lg2*4+j) at p*64 + ((m*4+lg2)^(p&15))*4 + j
#pragma unroll
    for (int m = 0; m < 4; m++)
#pragma unroll
      for (int nn = 0; nn < 2; nn++) {
        int p = (2 * wv + nn) * 16 + lr;
        int swz = (m * 4 + lg2) ^ lr;    // p&15 == lr
        *(floatx4*)(act2t + p * 64 + swz * 4) = acc[m][nn];
      }
  }
  __syncthreads();

  // ---- phase 4: pool5 + bias + relu + bn -> act2p hi/lo; zero pads ----
  {
    if (t < 162) {
      for (int i = t; i < 648; i += 162) {
        int r = i / 72; r = (r == 0) ? 0 : 25 + r;
        int idx = r * 72 + i % 72;
        act2p_hi[idx] = 0; act2p_lo[idx] = 0;
      }
    }
    int ic = t & 63;
    float bb = b2[ic], g = bn2g[ic] * bnscale, be = bn2b[ic];
#define A2T(r, c) act2t[(r) * 64 + ((((c) >> 2) ^ ((r) & 15)) << 2) + ((c) & 3)]
    for (int pw = t >> 6; pw < 25; pw += 4) {
      int base = 5 * pw;
      float m = A2T(base, ic);
      m = fmaxf(m, A2T(base + 1, ic));
      m = fmaxf(m, A2T(base + 2, ic));
      m = fmaxf(m, A2T(base + 3, ic));
      m = fmaxf(m, A2T(base + 4, ic));
      float v = fmaxf(m + bb, 0.f) * g + be;
      short hi = f2bf(v);
      short lo = f2bf(v - bf2f(hi));
      act2p_hi[(pw + 1) * 72 + ic] = hi;
      act2p_lo[(pw + 1) * 72 + ic] = lo;
    }
#undef A2T
  }
  __syncthreads();

  // ---- phase 5: conv3 MFMA  C[128ch][32pos] = W3[128][192] @ B3 ----
  {
    floatx4 acc[2][2];
#pragma unroll
    for (int mm = 0; mm < 2; mm++)
#pragma unroll
      for (int nn = 0; nn < 2; nn++) acc[mm][nn] = (floatx4){0.f, 0.f, 0.f, 0.f};
#pragma unroll
    for (int s = 0; s < 6; s++) {
      short8 Ah[2], Al[2], Bh[2], Bl[2];
#pragma unroll
      for (int mm = 0; mm < 2; mm++) {
        int aoff = ((s * 8 + (wv * 2 + mm)) * 64 + l) * 8;   // coalesced fragment layout
        Ah[mm] = *(const short8*)(w3hi + aoff);
        Al[mm] = *(const short8*)(w3lo + aoff);
      }
#pragma unroll
      for (int nn = 0; nn < 2; nn++) {
        int boff = (nn * 16 + lr + (s >> 1)) * 72 + (s & 1) * 32 + lg2 * 8;
        Bh[nn] = *(const short8*)(act2p_hi + boff);
        Bl[nn] = *(const short8*)(act2p_lo + boff);
      }
#pragma unroll
      for (int mm = 0; mm < 2; mm++)
#pragma unroll
        for (int nn = 0; nn < 2; nn++) {
          acc[mm][nn] = __builtin_amdgcn_mfma_f32_16x16x32_bf16(Ah[mm], Bh[nn], acc[mm][nn], 0, 0, 0);
          acc[mm][nn] = __builtin_amdgcn_mfma_f32_16x16x32_bf16(Ah[mm], Bl[nn], acc[mm][nn], 0, 0, 0);
          acc[mm][nn] = __builtin_amdgcn_mfma_f32_16x16x32_bf16(Al[mm], Bh[nn], acc[mm][nn], 0, 0, 0);
        }
    }
#pragma unroll
    for (int mm = 0; mm < 2; mm++)
#pragma unroll
      for (int nn = 0; nn < 2; nn++) {
        int p = nn * 16 + lr;
        *(floatx4*)(act3t + p * 132 + (wv * 2 + mm) * 16 + lg2 * 4) = acc[mm][nn];
      }
  }
  __syncthreads();

  // ---- phase 6: pool4(first 24) + bias + relu + bn -> featsh (LDS) ----
  {
    int c = t & 127;
    float bb = b3[c], g = bn3g[c] * bnscale, be = bn3b[c];
    for (int pw = t >> 7; pw < 6; pw += 2) {
      int base = 4 * pw;
      float m = act3t[base * 132 + c];
      m = fmaxf(m, act3t[(base + 1) * 132 + c]);
      m = fmaxf(m, act3t[(base + 2) * 132 + c]);
      m = fmaxf(m, act3t[(base + 3) * 132 + c]);
      float v = fmaxf(m + bb, 0.f) * g + be;
      featsh[c * 6 + pw] = v;
    }
  }
  __syncthreads();

  // ---- phase 7: folded VQ scores + argmax -> proto_idx ----
  if (t < NPROTO * 8) {
    int p = t >> 3, part = t & 7;
    const float4* pr = reinterpret_cast<const float4*>(P3 + p * 768 + part * 96);
    const float4* fr = reinterpret_cast<const float4*>(featsh + part * 96);
    float4 a4 = make_float4(0.f, 0.f, 0.f, 0.f);
#pragma unroll
    for (int i = 0; i < 24; i++) {
      float4 w = pr[i], f = fr[i];
      a4.x += w.x * f.x; a4.y += w.y * f.y; a4.z += w.z * f.z; a4.w += w.w * f.w;
    }
    float a = (a4.x + a4.y) + (a4.z + a4.w);
    a += __shfl_xor(a, 1);
    a += __shfl_xor(a, 2);
    a += __shfl_xor(a, 4);
    if (part == 0) sc25[p] = a + c3[p];
  }
  __syncthreads();
  if (t == 0) {
    int best = 0; float bv = sc25[0];
    for (int i = 1; i < NPROTO; i++) {
      float v = sc25[i];
      if (v > bv) { bv = v; best = i; }
    }
    proto_idx[sample] = best;
  }
}

// ---------------- Kernel 3: sequence transformer + classifier ----------------
__global__ __launch_bounds__(512) void seq_kernel(
    const int* __restrict__ proto_idx, const float* __restrict__ protos,
    const float* __restrict__ inw, const float* __restrict__ inb,
    const float* __restrict__ outw, const float* __restrict__ outb,
    const float* __restrict__ ln1g, const float* __restrict__ ln1b,
    const float* __restrict__ ln2g, const float* __restrict__ ln2b,
    const float* __restrict__ ff1w, const float* __restrict__ ff1b,
    const float* __restrict__ ff2w, const float* __restrict__ ff2b,
    const float* __restrict__ clfw, const float* __restrict__ clfb,
    float* __restrict__ out) {
  __shared__ __align__(16) float hsh[SS * OUTD];
  __shared__ __align__(16) float big[SS * 3 * OUTD];
  __shared__ __align__(16) float sc[NHEAD * SS * SS];
  __shared__ __align__(16) float ctx[SS * OUTD];
  __shared__ float rowm[SS], rowv[SS];

  const int b = blockIdx.x;
  const int t = threadIdx.x;

  for (int o = t; o < SS * OUTD; o += 512) {
    int s = o >> 7, d = o & 127;
    int i0 = proto_idx[(b * SS + s) * 2];
    int i1 = proto_idx[(b * SS + s) * 2 + 1];
    float pc = 0.5f * (protos[i0 * OUTD + d] + protos[i1 * OUTD + d]);
    int i = d >> 1;
    float div = expf((float)(2 * i) * -0.07195578415606439f);
    float ang = (float)s * div;
    float pe = (d & 1) ? cosf(ang) : sinf(ang);
    hsh[o] = pc + pe;
  }
  __syncthreads();

  for (int o = t; o < SS * 384; o += 512) {
    int s = o / 384, j = o % 384;
    float4 a4 = make_float4(0.f, 0.f, 0.f, 0.f);
    const float4* hr = reinterpret_cast<const float4*>(&hsh[s * OUTD]);
    for (int d4 = 0; d4 < 32; d4++) {
      float4 h4 = hr[d4];
      int d = d4 * 4;
      a4.x += h4.x * inw[(d + 0) * 384 + j];
      a4.y += h4.y * inw[(d + 1) * 384 + j];
      a4.z += h4.z * inw[(d + 2) * 384 + j];
      a4.w += h4.w * inw[(d + 3) * 384 + j];
    }
    big[o] = inb[j] + ((a4.x + a4.y) + (a4.z + a4.w));
  }
  __syncthreads();

  for (int o = t; o < NHEAD * SS * SS; o += 512) {
    int hd = o / (SS * SS), r = o % (SS * SS), qs = r / SS, ks = r % SS;
    const float4* qp = reinterpret_cast<const float4*>(&big[qs * 384 + hd * 32]);
    const float4* kp = reinterpret_cast<const float4*>(&big[ks * 384 + 128 + hd * 32]);
    float4 a4 = make_float4(0.f, 0.f, 0.f, 0.f);
#pragma unroll
    for (int d4 = 0; d4 < 8; d4++) {
      float4 q4 = qp[d4], k4 = kp[d4];
      a4.x += q4.x * k4.x; a4.y += q4.y * k4.y; a4.z += q4.z * k4.z; a4.w += q4.w * k4.w;
    }
    sc[o] = ((a4.x + a4.y) + (a4.z + a4.w)) * 0.17677669529663689f;
  }
  __syncthreads();
  for (int r = t; r < NHEAD * SS; r += 512) {
    float* row = &sc[r * SS];
    float mx = row[0];
    for (int i = 1; i < SS; i++) mx = fmaxf(mx, row[i]);
    float sum = 0.f;
    for (int i = 0; i < SS; i++) { float e = expf(row[i] - mx); row[i] = e; sum += e; }
    float inv = 1.f / sum;
    for (int i = 0; i < SS; i++) row[i] *= inv;
  }
  __syncthreads();
  for (int o = t; o < SS * OUTD; o += 512) {
    int qs = o >> 7, d = o & 127, hd = d >> 5, dd = d & 31;
    const float* srow = &sc[(hd * SS + qs) * SS];
    float a = 0.f;
    for (int ks = 0; ks < SS; ks++) a += srow[ks] * big[ks * 384 + 256 + hd * 32 + dd];
    ctx[o] = a;
  }
  __syncthreads();
  float* tmp = big;
  for (int o = t; o < SS * OUTD; o += 512) {
    int s = o >> 7, d = o & 127;
    float4 a4 = make_float4(0.f, 0.f, 0.f, 0.f);
    const float4* cr = reinterpret_cast<const float4*>(&ctx[s * OUTD]);
    for (int e4 = 0; e4 < 32; e4++) {
      float4 c4 = cr[e4];
      int e = e4 * 4;
      a4.x += c4.x * outw[(e + 0) * OUTD + d];
      a4.y += c4.y * outw[(e + 1) * OUTD + d];
      a4.z += c4.z * outw[(e + 2) * OUTD + d];
      a4.w += c4.w * outw[(e + 3) * OUTD + d];
    }
    tmp[o] = hsh[o] + outb[d] + ((a4.x + a4.y) + (a4.z + a4.w));
  }
  __syncthreads();
  if (t < SS) {
    const float4* r4 = reinterpret_cast<const float4*>(&tmp[t * OUTD]);
    float4 m4 = make_float4(0.f, 0.f, 0.f, 0.f);
    for (int d4 = 0; d4 < 32; d4++) {
      float4 v = r4[d4];
      m4.x += v.x; m4.y += v.y; m4.z += v.z; m4.w += v.w;
    }
    float m = ((m4.x + m4.y) + (m4.z + m4.w)) * (1.0f / OUTD);
    float4 v4 = make_float4(0.f, 0.f, 0.f, 0.f);
    for (int d4 = 0; d4 < 32; d4++) {
      float4 v = r4[d4];
      float ux = v.x - m, uy = v.y - m, uz = v.z - m, uw = v.w - m;
      v4.x += ux * ux; v4.y += uy * uy; v4.z += uz * uz; v4.w += uw * uw;
    }
    float var = ((v4.x + v4.y) + (v4.z + v4.w)) * (1.0f / OUTD);
    rowm[t] = m; rowv[t] = rsqrtf(var + 1e-5f);
  }
  __syncthreads();
  for (int o = t; o < SS * OUTD; o += 512) {
    int s = o >> 7, d = o & 127;
    hsh[o] = (tmp[o] - rowm[s]) * rowv[s] * ln1g[d] + ln1b[d];
  }
  __syncthreads();
  for (int o = t; o < SS * OUTD; o += 512) {
    int s = o >> 7, d = o & 127;
    float4 a4 = make_float4(0.f, 0.f, 0.f, 0.f);
    const float4* hr = reinterpret_cast<const float4*>(&hsh[s * OUTD]);
    for (int e4 = 0; e4 < 32; e4++) {
      float4 h4 = hr[e4];
      int e = e4 * 4;
      a4.x += h4.x * ff1w[(e + 0) * OUTD + d];
      a4.y += h4.y * ff1w[(e + 1) * OUTD + d];
      a4.z += h4.z * ff1w[(e + 2) * OUTD + d];
      a4.w += h4.w * ff1w[(e + 3) * OUTD + d];
    }
    ctx[o] = fmaxf(ff1b[d] + ((a4.x + a4.y) + (a4.z + a4.w)), 0.f);
  }
  __syncthreads();
  for (int o = t; o < SS * OUTD; o += 512) {
    int s = o >> 7, d = o & 127;
    float4 a4 = make_float4(0.f, 0.f, 0.f, 0.f);
    const float4* cr = reinterpret_cast<const float4*>(&ctx[s * OUTD]);
    for (int e4 = 0; e4 < 32; e4++) {
      float4 c4 = cr[e4];
      int e = e4 * 4;
      a4.x += c4.x * ff2w[(e + 0) * OUTD + d];
      a4.y += c4.y * ff2w[(e + 1) * OUTD + d];
      a4.z += c4.z * ff2w[(e + 2) * OUTD + d];
      a4.w += c4.w * ff2w[(e + 3) * OUTD + d];
    }
    tmp[o] = hsh[o] + ff2b[d] + ((a4.x + a4.y) + (a4.z + a4.w));
  }
  __syncthreads();
  if (t < SS) {
    const float4* r4 = reinterpret_cast<const float4*>(&tmp[t * OUTD]);
    float4 m4 = make_float4(0.f, 0.f, 0.f, 0.f);
    for (int d4 = 0; d4 < 32; d4++) {
      float4 v = r4[d4];
      m4.x += v.x; m4.y += v.y; m4.z += v.z; m4.w += v.w;
    }
    float m = ((m4.x + m4.y) + (m4.z + m4.w)) * (1.0f / OUTD);
    float4 v4 = make_float4(0.f, 0.f, 0.f, 0.f);
    for (int d4 = 0; d4 < 32; d4++) {
      float4 v = r4[d4];
      float ux = v.x - m, uy = v.y - m, uz = v.z - m, uw = v.w - m;
      v4.x += ux * ux; v4.y += uy * uy; v4.z += uz * uz; v4.w += uw * uw;
    }
    float var = ((v4.x + v4.y) + (v4.z + v4.w)) * (1.0f / OUTD);
    rowm[t] = m; rowv[t] = rsqrtf(var + 1e-5f);
  }
  __syncthreads();
  for (int o = t; o < SS * OUTD; o += 512) {
    int s = o >> 7, d = o & 127;
    hsh[o] = (tmp[o] - rowm[s]) * rowv[s] * ln2g[d] + ln2b[d];
  }
  __syncthreads();
  for (int o = t; o < SS * NCLS; o += 512) {
    int s = o / NCLS, c = o % NCLS;
    float4 a4 = make_float4(0.f, 0.f, 0.f, 0.f);
    const float4* hr = reinterpret_cast<const float4*>(&hsh[s * OUTD]);
    for (int d4 = 0; d4 < 32; d4++) {
      float4 h4 = hr[d4];
      int d = d4 * 4;
      a4.x += h4.x * clfw[(d + 0) * NCLS + c];
      a4.y += h4.y * clfw[(d + 1) * NCLS + c];
      a4.z += h4.z * clfw[(d + 2) * NCLS + c];
      a4.w += h4.w * clfw[(d + 3) * NCLS + c];
    }
    out[(b * SS + s) * NCLS + c] = clfb[c] + ((a4.x + a4.y) + (a4.z + a4.w));
  }
}

extern "C" void kernel_launch(void* const* d_in, const int* in_sizes, int n_in,
                              void* d_out, int out_size, void* d_ws, size_t ws_size,
                              hipStream_t stream) {
  const float* x     = (const float*)d_in[0];
  const float* gum   = (const float*)d_in[1];
  const float* wq    = (const float*)d_in[2];
  const float* wk    = (const float*)d_in[3];
  const float* w1    = (const float*)d_in[4];
  const float* b1    = (const float*)d_in[5];
  const float* bn1g  = (const float*)d_in[6];
  const float* bn1b  = (const float*)d_in[7];
  const float* w2    = (const float*)d_in[8];
  const float* b2    = (const float*)d_in[9];
  const float* bn2g  = (const float*)d_in[10];
  const float* bn2b  = (const float*)d_in[11];
  const float* w3    = (const float*)d_in[12];
  const float* b3    = (const float*)d_in[13];
  const float* bn3g  = (const float*)d_in[14];
  const float* bn3b  = (const float*)d_in[15];
  const float* fcw   = (const float*)d_in[16];
  const float* fcb   = (const float*)d_in[17];
  const float* fc2w  = (const float*)d_in[18];
  const float* fc2b  = (const float*)d_in[19];
  const float* prot  = (const float*)d_in[20];
  const float* inw   = (const float*)d_in[21];
  const float* inb   = (const float*)d_in[22];
  const float* outw  = (const float*)d_in[23];
  const float* outb  = (const float*)d_in[24];
  const float* ln1g  = (const float*)d_in[25];
  const float* ln1b  = (const float*)d_in[26];
  const float* ln2g  = (const float*)d_in[27];
  const float* ln2b  = (const float*)d_in[28];
  const float* ff1w  = (const float*)d_in[29];
  const float* ff1b  = (const float*)d_in[30];
  const float* ff2w  = (const float*)d_in[31];
  const float* ff2b  = (const float*)d_in[32];
  const float* clfw  = (const float*)d_in[33];
  const float* clfb  = (const float*)d_in[34];
  float* out = (float*)d_out;

  int* sec_idx   = (int*)d_ws;
  int* proto_idx = sec_idx + NSAMPLE;
  short* w2hi = (short*)((float*)d_ws + WS_W2HI);
  short* w2lo = (short*)((float*)d_ws + WS_W2LO);
  short* w3hi = (short*)((float*)d_ws + WS_W3HI);
  short* w3lo = (short*)((float*)d_ws + WS_W3LO);
  float* P3   = (float*)d_ws + WS_P3;
  float* c3   = (float*)d_ws + WS_C3;
  float* wqT  = (float*)d_ws + WS_WQT;
  float* vbuf = (float*)d_ws + WS_V;

  hipLaunchKernelGGL(prep_all_kernel, dim3(177), dim3(256), 0, stream,
                     w2, w3, w2hi, w2lo, w3hi, w3lo,
                     prot, fc2w, fcw, fcb, fc2b, P3, c3, wq, wqT);
  hipLaunchKernelGGL(attn_b_kernel, dim3(BS / MBX), dim3(512), 0, stream,
                     x, wk, wqT, vbuf);
  hipLaunchKernelGGL(attn_c_kernel, dim3(BS), dim3(192), 0, stream,
                     x, vbuf, gum, sec_idx);
  hipLaunchKernelGGL(conv_kernel, dim3(NSAMPLE), dim3(256), 0, stream,
                     x, sec_idx, w1, b1, bn1g, bn1b, w2hi, w2lo, b2, bn2g, bn2b,
                     w3hi, w3lo, b3, bn3g, bn3b, P3, c3, proto_idx);
  hipLaunchKernelGGL(seq_kernel, dim3(BB), dim3(512), 0, stream,
                     proto_idx, prot, inw, inb, outw, outb,
                     ln1g, ln1b, ln2g, ln2b, ff1w, ff1b, ff2w, ff2b,
                     clfw, clfb, out);
}

// Round 10
// 184.486 us; speedup vs baseline: 4.6088x; 1.2250x over previous
//
#include <hip/hip_runtime.h>
#include <math.h>

#define BB 64
#define SS 21
#define NSAMP 3000
#define HID 500
#define SECN 6
#define NN 2
#define OUTD 128
#define NPROTO 25
#define NCLS 5
#define NHEAD 4
#define BS (BB*SS)          // 1344
#define NSAMPLE (BS*NN)     // 2688

#define C500 (-0.0184206807439523674f)   // -ln(1e4)/500
#define C128 (-0.07195578415606439f)     // -ln(1e4)/128
#define LSCALE 0.00745355992499929898f   // 1/(6*sqrt(500))

// ws float offsets
#define WS_W2HI 5376
#define WS_W2LO 8448
#define WS_W3HI 11520
#define WS_W3LO 23808
#define WS_P3   36096
#define WS_C3   55296
#define WS_WQT  55424
#define WS_V    727424
#define WS_QKV  WS_V                 // reuses vbuf region (attn done before seq)
#define WS_CTX  (WS_V + 520192)

typedef __attribute__((ext_vector_type(8))) short short8;
typedef __attribute__((ext_vector_type(4))) float floatx4;

__device__ __forceinline__ short f2bf(float f) {
  unsigned u = __float_as_uint(f);
  u += 0x7FFF + ((u >> 16) & 1);          // RNE to bf16
  return (short)(u >> 16);
}
__device__ __forceinline__ float bf2f(short h) {
  return __uint_as_float(((unsigned)(unsigned short)h) << 16);
}

// ---------------- Kernel 0: weight splits (MFMA-fragment order) + VQ prep + wq transpose ----------------
__global__ __launch_bounds__(256) void prep_all_kernel(
    const float* __restrict__ w2, const float* __restrict__ w3,
    short* __restrict__ w2hi, short* __restrict__ w2lo,
    short* __restrict__ w3hi, short* __restrict__ w3lo,
    const float* __restrict__ protos, const float* __restrict__ fc2w,
    const float* __restrict__ fcw, const float* __restrict__ fcb,
    const float* __restrict__ fc2b,
    float* __restrict__ P3, float* __restrict__ c3,
    const float* __restrict__ wq, float* __restrict__ wqT) {
  __shared__ __align__(16) float p2row[256];
  __shared__ float red[256];
  __shared__ float tile[64][65];
  const int t = threadIdx.x;
  if (blockIdx.x < 120) {
    int idx = blockIdx.x * 256 + t;
    if (idx < 6144) {
      int ic = idx & 31, ck = idx >> 5, k = ck % 3, c = ck / 3;
      float v = w2[c * 96 + ic * 3 + k];
      int dst = (((k * 4 + (c >> 4)) * 64) + ((ic >> 3) * 16 + (c & 15))) * 8 + (ic & 7);
      short hi = f2bf(v);
      short lo = f2bf(v - bf2f(hi));
      w2hi[dst] = hi; w2lo[dst] = lo;
    } else if (idx < 30720) {
      int j = idx - 6144;
      int ic = j & 63, ck = j >> 6, k = ck % 3, c = ck / 3;
      float v = w3[(c * 64 + ic) * 3 + k];
      int s = k * 2 + (ic >> 5);
      int dst = (((s * 8 + (c >> 4)) * 64) + (((ic & 31) >> 3) * 16 + (c & 15))) * 8 + (ic & 7);
      short hi = f2bf(v);
      short lo = f2bf(v - bf2f(hi));
      w3hi[dst] = hi; w3lo[dst] = lo;
    }
    return;
  }
  if (blockIdx.x >= 145) {               // wq transpose: 32 tile-blocks
    int tid = blockIdx.x - 145;
    int h0 = (tid >> 2) * 64, c0 = (tid & 3) * 64;
    for (int e = t; e < 4096; e += 256) {
      int i = e >> 6, j = e & 63;
      if (h0 + i < 500) tile[j][i] = wq[(h0 + i) * 256 + c0 + j];
    }
    __syncthreads();
    for (int e = t; e < 4096; e += 256) {
      int c = e >> 6, hh = e & 63;
      if (h0 + hh < 500) wqT[(c0 + c) * 500 + h0 + hh] = tile[c][hh];
    }
    return;
  }
  const int p = blockIdx.x - 120, j = t;
  {
    const float4* pr = reinterpret_cast<const float4*>(protos + p * 128);
    const float4* wr = reinterpret_cast<const float4*>(fc2w + j * 128);
    float4 a4 = make_float4(0.f, 0.f, 0.f, 0.f);
    for (int c4 = 0; c4 < 32; c4++) {
      float4 a = pr[c4], b = wr[c4];
      a4.x += a.x * b.x; a4.y += a.y * b.y; a4.z += a.z * b.z; a4.w += a.w * b.w;
    }
    float v = (a4.x + a4.y) + (a4.z + a4.w);
    p2row[j] = v;
    float contrib = v * fcb[j];
    if (j < 128) {
      float pv = protos[p * 128 + j];
      contrib += pv * fc2b[j] - 0.5f * pv * pv;
    }
    red[j] = contrib;
  }
  __syncthreads();
  for (int s = 128; s > 0; s >>= 1) {
    if (j < s) red[j] += red[j + s];
    __syncthreads();
  }
  if (j == 0) c3[p] = red[0];
  for (int k = j; k < 768; k += 256) {
    const float4* fr = reinterpret_cast<const float4*>(fcw + k * 256);
    const float4* p2 = reinterpret_cast<const float4*>(p2row);
    float4 a4 = make_float4(0.f, 0.f, 0.f, 0.f);
    for (int j4 = 0; j4 < 64; j4++) {
      float4 a = p2[j4], b = fr[j4];
      a4.x += a.x * b.x; a4.y += a.y * b.y; a4.z += a.z * b.z; a4.w += a.w * b.w;
    }
    P3[p * 768 + k] = (a4.x + a4.y) + (a4.z + a4.w);
  }
}

// ---------------- Kernel 1b: fused xsum -> ks -> v (4 samples/block, 336 blocks, K-split) ----------------
#define MBX 4
__global__ __launch_bounds__(512) void attn_b_kernel(
    const float* __restrict__ x, const float* __restrict__ wk,
    const float* __restrict__ wqT, float* __restrict__ v) {
  __shared__ __align__(16) float pesum[500];
  __shared__ __align__(16) float xs[MBX * 500];
  __shared__ __align__(16) float ksp[2 * 256 * MBX];
  __shared__ __align__(16) float ks_t[256 * MBX];
  const int blk = blockIdx.x, t = threadIdx.x;

  if (t < 125) {
    float div0 = expf((float)(4 * t) * C500);
    float div1 = expf((float)(4 * t + 2) * C500);
    float s0 = 0.f, c0 = 0.f, s1 = 0.f, c1 = 0.f;
#pragma unroll
    for (int s = 0; s < SECN; s++) {
      float a0 = (float)s * div0, a1 = (float)s * div1;
      s0 += sinf(a0); c0 += cosf(a0);
      s1 += sinf(a1); c1 += cosf(a1);
    }
    reinterpret_cast<float4*>(pesum)[t] = make_float4(s0, c0, s1, c1);
  }
  __syncthreads();

  for (int e = t; e < MBX * 125; e += 512) {
    int m = e / 125, h4 = e % 125;
    const float4* xr = reinterpret_cast<const float4*>(x) + (blk * MBX + m) * 750;
    float4 a = xr[h4];
#pragma unroll
    for (int s = 1; s < SECN; s++) {
      float4 b = xr[s * 125 + h4];
      a.x += b.x; a.y += b.y; a.z += b.z; a.w += b.w;
    }
    float4 pe = reinterpret_cast<float4*>(pesum)[h4];
    a.x += pe.x; a.y += pe.y; a.z += pe.z; a.w += pe.w;
    reinterpret_cast<float4*>(xs)[m * 125 + h4] = a;
  }
  __syncthreads();

  // phase A: ks partials; c = t&255, K-half kh = t>>8
  {
    int c = t & 255, kh = t >> 8;
    float acc[MBX];
#pragma unroll
    for (int m = 0; m < MBX; m++) acc[m] = 0.f;
    int b4 = kh ? 63 : 0, e4 = kh ? 125 : 63;
    const float4* xsb = reinterpret_cast<const float4*>(xs);
    for (int i4 = b4; i4 < e4; i4++) {
      int i = i4 * 4;
      float w0 = wk[(i + 0) * 256 + c];
      float w1 = wk[(i + 1) * 256 + c];
      float w2 = wk[(i + 2) * 256 + c];
      float w3 = wk[(i + 3) * 256 + c];
#pragma unroll
      for (int m = 0; m < MBX; m++) {
        float4 xv = xsb[m * 125 + i4];
        acc[m] += xv.x * w0 + xv.y * w1 + xv.z * w2 + xv.w * w3;
      }
    }
#pragma unroll
    for (int m = 0; m < MBX; m++)
      ksp[(kh * 256 + c) * MBX + m] = acc[m];
  }
  __syncthreads();
  for (int e = t; e < 256 * MBX; e += 512) ks_t[e] = ksp[e] + ksp[256 * MBX + e];
  __syncthreads();

  // phase B: v[m][n][h] = sum_c wqT[n*128+c][h] * ks_t[c][m]
  if (t < 500) {
    int h = t;
#pragma unroll
    for (int n = 0; n < 2; n++) {
      float acc[MBX];
#pragma unroll
      for (int m = 0; m < MBX; m++) acc[m] = 0.f;
      const float* wcol = wqT + (n * 128) * 500 + h;
      const floatx4* ktb = (const floatx4*)ks_t + n * 128;
      for (int c = 0; c < 128; c++) {
        float w = wcol[c * 500];
        floatx4 k0 = ktb[c];
        acc[0] += w * k0[0]; acc[1] += w * k0[1]; acc[2] += w * k0[2]; acc[3] += w * k0[3];
      }
#pragma unroll
      for (int m = 0; m < MBX; m++)
        v[((blk * MBX + m) * 2 + n) * 500 + h] = acc[m];
    }
  }
}

// ---------------- Kernel 1c: logits = (x+pe).v + gumbel -> argmax ----------------
__global__ __launch_bounds__(192) void attn_c_kernel(
    const float* __restrict__ x, const float* __restrict__ v,
    const float* __restrict__ gumbel, int* __restrict__ sec_idx) {
  __shared__ float lgsh[NN][SECN];
  const int bs = blockIdx.x, t = threadIdx.x;
  const int s = t >> 5, lane = t & 31;
  const float4* x4 = reinterpret_cast<const float4*>(x) + bs * 750 + s * 125;
  const float4* v0 = reinterpret_cast<const float4*>(v) + bs * 250;
  const float4* v1 = v0 + 125;
  float a0 = 0.f, a1 = 0.f;
  for (int h4 = lane; h4 < 125; h4 += 32) {
    float4 xv = x4[h4];
    float div0 = expf((float)(4 * h4) * C500);
    float div1 = expf((float)(4 * h4 + 2) * C500);
    float ang0 = (float)s * div0, ang1 = (float)s * div1;
    xv.x += sinf(ang0); xv.y += cosf(ang0);
    xv.z += sinf(ang1); xv.w += cosf(ang1);
    float4 w0 = v0[h4], w1 = v1[h4];
    a0 += xv.x * w0.x + xv.y * w0.y + xv.z * w0.z + xv.w * w0.w;
    a1 += xv.x * w1.x + xv.y * w1.y + xv.z * w1.z + xv.w * w1.w;
  }
#pragma unroll
  for (int m = 16; m >= 1; m >>= 1) {
    a0 += __shfl_xor(a0, m);
    a1 += __shfl_xor(a1, m);
  }
  if (lane == 0) {
    lgsh[0][s] = a0 * LSCALE + gumbel[(bs * 2 + 0) * SECN + s];
    lgsh[1][s] = a1 * LSCALE + gumbel[(bs * 2 + 1) * SECN + s];
  }
  __syncthreads();
  if (t < 2) {
    int best = 0; float bv = lgsh[t][0];
    for (int i = 1; i < SECN; i++) {
      float q = lgsh[t][i];
      if (q > bv) { bv = q; best = i; }
    }
    sec_idx[bs * 2 + t] = best;
  }
}

// ---------------- Kernel 2: conv encoder (MFMA, coalesced A-fragments) + VQ ----------------
#define CONV_LDS 53568
__global__ __launch_bounds__(256, 3) void conv_kernel(
    const float* __restrict__ x, const int* __restrict__ sec_idx,
    const float* __restrict__ w1, const float* __restrict__ b1,
    const float* __restrict__ bn1g, const float* __restrict__ bn1b,
    const short* __restrict__ w2hi, const short* __restrict__ w2lo,
    const float* __restrict__ b2,
    const float* __restrict__ bn2g, const float* __restrict__ bn2b,
    const short* __restrict__ w3hi, const short* __restrict__ w3lo,
    const float* __restrict__ b3,
    const float* __restrict__ bn3g, const float* __restrict__ bn3b,
    const float* __restrict__ P3, const float* __restrict__ c3,
    int* __restrict__ proto_idx) {
  __shared__ __align__(16) char smem[CONV_LDS];
  short* act1_hi  = (short*)smem;               // [130][40]
  short* act1_lo  = (short*)(smem + 10400);     // [130][40]
  short* act2p_hi = (short*)smem;               // [34][72]
  short* act2p_lo = (short*)(smem + 4896);      // [34][72]
  float* featsh   = (float*)(smem + 9792);      // [768] (alias, phases 6-7)
  float* sc25     = (float*)(smem + 12864);     // [25]
  float* in0p  = (float*)(smem + 20800);        // [512]
  float* act2t = (float*)(smem + 20800);        // [128][64] swizzled
  float* act3t = (float*)(smem + 20800);        // [32][132]

  const int sample = blockIdx.x;
  const int t = threadIdx.x;
  const int bsIdx = sample >> 1;
  const float bnscale = rsqrtf(1.0f + 1e-5f);
  const int wv = t >> 6, l = t & 63, lr = l & 15, lg2 = l >> 4;

  {
    int sec = sec_idx[sample];
    const float* src = &x[bsIdx * NSAMP + sec * HID];
    for (int i = t; i < 512; i += 256) in0p[i] = (i >= 1 && i <= 500) ? src[i - 1] : 0.f;
    if (t < 200) {
      int r = t / 40; r = (r == 0) ? 0 : 125 + r;
      int idx = r * 40 + t % 40;
      act1_hi[idx] = 0; act1_lo[idx] = 0;
    }
  }
  __syncthreads();

  {
    int ic = t & 31;
    float w0 = w1[ic * 3], w1v = w1[ic * 3 + 1], w2v = w1[ic * 3 + 2];
    float bb = b1[ic];
    float g = bn1g[ic] * bnscale, be = bn1b[ic];
    for (int p = t >> 5; p < 125; p += 8) {
      int base = 4 * p;
      float xm1 = in0p[base], x0 = in0p[base + 1], x1 = in0p[base + 2],
            x2 = in0p[base + 3], x3 = in0p[base + 4], x4 = in0p[base + 5];
      float a0 = bb + w0 * xm1 + w1v * x0 + w2v * x1;
      float a1 = bb + w0 * x0  + w1v * x1 + w2v * x2;
      float a2 = bb + w0 * x1  + w1v * x2 + w2v * x3;
      float a3 = bb + w0 * x2  + w1v * x3 + w2v * x4;
      float m = fmaxf(fmaxf(fmaxf(fmaxf(a0, a1), a2), a3), 0.f);
      float v = m * g + be;
      short hi = f2bf(v);
      short lo = f2bf(v - bf2f(hi));
      act1_hi[(p + 1) * 40 + ic] = hi;
      act1_lo[(p + 1) * 40 + ic] = lo;
    }
  }
  __syncthreads();

  {
    floatx4 acc[4][2];
#pragma unroll
    for (int m = 0; m < 4; m++)
#pragma unroll
      for (int nn = 0; nn < 2; nn++) acc[m][nn] = (floatx4){0.f, 0.f, 0.f, 0.f};
#pragma unroll
    for (int s = 0; s < 3; s++) {
      short8 Ah[4], Al[4], Bh[2], Bl[2];
#pragma unroll
      for (int m = 0; m < 4; m++) {
        int aoff = ((s * 4 + m) * 64 + l) * 8;
        Ah[m] = *(const short8*)(w2hi + aoff);
        Al[m] = *(const short8*)(w2lo + aoff);
      }
#pragma unroll
      for (int nn = 0; nn < 2; nn++) {
        int boff = ((2 * wv + nn) * 16 + lr + s) * 40 + lg2 * 8;
        Bh[nn] = *(const short8*)(act1_hi + boff);
        Bl[nn] = *(const short8*)(act1_lo + boff);
      }
#pragma unroll
      for (int m = 0; m < 4; m++)
#pragma unroll
        for (int nn = 0; nn < 2; nn++) {
          acc[m][nn] = __builtin_amdgcn_mfma_f32_16x16x32_bf16(Ah[m], Bh[nn], acc[m][nn], 0, 0, 0);
          acc[m][nn] = __builtin_amdgcn_mfma_f32_16x16x32_bf16(Ah[m], Bl[nn], acc[m][nn], 0, 0, 0);
          acc[m][nn] = __builtin_amdgcn_mfma_f32_16x16x32_bf16(Al[m], Bh[nn], acc[m][nn], 0, 0, 0);
        }
    }
#pragma unroll
    for (int m = 0; m < 4; m++)
#pragma unroll
      for (int nn = 0; nn < 2; nn++) {
        int p = (2 * wv + nn) * 16 + lr;
        int swz = (m * 4 + lg2) ^ lr;
        *(floatx4*)(act2t + p * 64 + swz * 4) = acc[m][nn];
      }
  }
  __syncthreads();

  {
    if (t < 162) {
      for (int i = t; i < 648; i += 162) {
        int r = i / 72; r = (r == 0) ? 0 : 25 + r;
        int idx = r * 72 + i % 72;
        act2p_hi[idx] = 0; act2p_lo[idx] = 0;
      }
    }
    int ic = t & 63;
    float bb = b2[ic], g = bn2g[ic] * bnscale, be = bn2b[ic];
#define A2T(r, c) act2t[(r) * 64 + ((((c) >> 2) ^ ((r) & 15)) << 2) + ((c) & 3)]
    for (int pw = t >> 6; pw < 25; pw += 4) {
      int base = 5 * pw;
      float m = A2T(base, ic);
      m = fmaxf(m, A2T(base + 1, ic));
      m = fmaxf(m, A2T(base + 2, ic));
      m = fmaxf(m, A2T(base + 3, ic));
      m = fmaxf(m, A2T(base + 4, ic));
      float v = fmaxf(m + bb, 0.f) * g + be;
      short hi = f2bf(v);
      short lo = f2bf(v - bf2f(hi));
      act2p_hi[(pw + 1) * 72 + ic] = hi;
      act2p_lo[(pw + 1) * 72 + ic] = lo;
    }
#undef A2T
  }
  __syncthreads();

  {
    floatx4 acc[2][2];
#pragma unroll
    for (int mm = 0; mm < 2; mm++)
#pragma unroll
      for (int nn = 0; nn < 2; nn++) acc[mm][nn] = (floatx4){0.f, 0.f, 0.f, 0.f};
#pragma unroll
    for (int s = 0; s < 6; s++) {
      short8 Ah[2], Al[2], Bh[2], Bl[2];
#pragma unroll
      for (int mm = 0; mm < 2; mm++) {
        int aoff = ((s * 8 + (wv * 2 + mm)) * 64 + l) * 8;
        Ah[mm] = *(const short8*)(w3hi + aoff);
        Al[mm] = *(const short8*)(w3lo + aoff);
      }
#pragma unroll
      for (int nn = 0; nn < 2; nn++) {
        int boff = (nn * 16 + lr + (s >> 1)) * 72 + (s & 1) * 32 + lg2 * 8;
        Bh[nn] = *(const short8*)(act2p_hi + boff);
        Bl[nn] = *(const short8*)(act2p_lo + boff);
      }
#pragma unroll
      for (int mm = 0; mm < 2; mm++)
#pragma unroll
        for (int nn = 0; nn < 2; nn++) {
          acc[mm][nn] = __builtin_amdgcn_mfma_f32_16x16x32_bf16(Ah[mm], Bh[nn], acc[mm][nn], 0, 0, 0);
          acc[mm][nn] = __builtin_amdgcn_mfma_f32_16x16x32_bf16(Ah[mm], Bl[nn], acc[mm][nn], 0, 0, 0);
          acc[mm][nn] = __builtin_amdgcn_mfma_f32_16x16x32_bf16(Al[mm], Bh[nn], acc[mm][nn], 0, 0, 0);
        }
    }
#pragma unroll
    for (int mm = 0; mm < 2; mm++)
#pragma unroll
      for (int nn = 0; nn < 2; nn++) {
        int p = nn * 16 + lr;
        *(floatx4*)(act3t + p * 132 + (wv * 2 + mm) * 16 + lg2 * 4) = acc[mm][nn];
      }
  }
  __syncthreads();

  {
    int c = t & 127;
    float bb = b3[c], g = bn3g[c] * bnscale, be = bn3b[c];
    for (int pw = t >> 7; pw < 6; pw += 2) {
      int base = 4 * pw;
      float m = act3t[base * 132 + c];
      m = fmaxf(m, act3t[(base + 1) * 132 + c]);
      m = fmaxf(m, act3t[(base + 2) * 132 + c]);
      m = fmaxf(m, act3t[(base + 3) * 132 + c]);
      float v = fmaxf(m + bb, 0.f) * g + be;
      featsh[c * 6 + pw] = v;
    }
  }
  __syncthreads();

  if (t < NPROTO * 8) {
    int p = t >> 3, part = t & 7;
    const float4* pr = reinterpret_cast<const float4*>(P3 + p * 768 + part * 96);
    const float4* fr = reinterpret_cast<const float4*>(featsh + part * 96);
    float4 a4 = make_float4(0.f, 0.f, 0.f, 0.f);
#pragma unroll
    for (int i = 0; i < 24; i++) {
      float4 w = pr[i], f = fr[i];
      a4.x += w.x * f.x; a4.y += w.y * f.y; a4.z += w.z * f.z; a4.w += w.w * f.w;
    }
    float a = (a4.x + a4.y) + (a4.z + a4.w);
    a += __shfl_xor(a, 1);
    a += __shfl_xor(a, 2);
    a += __shfl_xor(a, 4);
    if (part == 0) sc25[p] = a + c3[p];
  }
  __syncthreads();
  if (t == 0) {
    int best = 0; float bv = sc25[0];
    for (int i = 1; i < NPROTO; i++) {
      float v = sc25[i];
      if (v > bv) { bv = v; best = i; }
    }
    proto_idx[sample] = best;
  }
}

// ---------------- Kernel 3a: qkv GEMV per (b,s) row ----------------
__global__ __launch_bounds__(384) void seq_qkv_kernel(
    const int* __restrict__ proto_idx, const float* __restrict__ protos,
    const float* __restrict__ inw, const float* __restrict__ inb,
    float* __restrict__ qkv) {
  __shared__ __align__(16) float hrow[OUTD];
  const int bs = blockIdx.x, t = threadIdx.x;
  const int s = bs % SS;
  if (t < OUTD) {
    int i0 = proto_idx[bs * 2], i1 = proto_idx[bs * 2 + 1];
    float pc = 0.5f * (protos[i0 * OUTD + t] + protos[i1 * OUTD + t]);
    float div = expf((float)(2 * (t >> 1)) * C128);
    float ang = (float)s * div;
    float pe = (t & 1) ? cosf(ang) : sinf(ang);
    hrow[t] = pc + pe;
  }
  __syncthreads();
  float a = inb[t];
  const float4* hr = reinterpret_cast<const float4*>(hrow);
  for (int d4 = 0; d4 < 32; d4++) {
    float4 h4 = hr[d4];
    int d = d4 * 4;
    a += h4.x * inw[(d + 0) * 384 + t] + h4.y * inw[(d + 1) * 384 + t]
       + h4.z * inw[(d + 2) * 384 + t] + h4.w * inw[(d + 3) * 384 + t];
  }
  qkv[bs * 384 + t] = a;
}

// ---------------- Kernel 3b: attention per (b, head) ----------------
__global__ __launch_bounds__(256) void seq_attn_kernel(
    const float* __restrict__ qkv, float* __restrict__ ctxbuf) {
  __shared__ float qs_[SS][32], ks_[SS][32], vs_[SS][32];
  __shared__ float sc_[SS][SS + 1];
  const int b = blockIdx.x >> 2, hd = blockIdx.x & 3;
  const int t = threadIdx.x;
  for (int e = t; e < SS * 32; e += 256) {
    int s = e >> 5, dd = e & 31;
    const float* base = qkv + (b * SS + s) * 384 + hd * 32 + dd;
    qs_[s][dd] = base[0];
    ks_[s][dd] = base[128];
    vs_[s][dd] = base[256];
  }
  __syncthreads();
  for (int e = t; e < SS * SS; e += 256) {
    int qs = e / SS, ks = e % SS;
    float a = 0.f;
#pragma unroll
    for (int d = 0; d < 32; d++) a += qs_[qs][d] * ks_[ks][d];
    sc_[qs][ks] = a * 0.17677669529663689f;
  }
  __syncthreads();
  if (t < SS) {
    float mx = sc_[t][0];
    for (int i = 1; i < SS; i++) mx = fmaxf(mx, sc_[t][i]);
    float sum = 0.f;
    for (int i = 0; i < SS; i++) { float e = expf(sc_[t][i] - mx); sc_[t][i] = e; sum += e; }
    float inv = 1.f / sum;
    for (int i = 0; i < SS; i++) sc_[t][i] *= inv;
  }
  __syncthreads();
  for (int e = t; e < SS * 32; e += 256) {
    int qs = e >> 5, dd = e & 31;
    float a = 0.f;
#pragma unroll
    for (int ks = 0; ks < SS; ks++) a += sc_[qs][ks] * vs_[ks][dd];
    ctxbuf[(b * SS + qs) * OUTD + hd * 32 + dd] = a;
  }
}

// ---------------- Kernel 3c: out proj + LN1 + FF + LN2 + classifier per (b,s) row ----------------
__global__ __launch_bounds__(128) void seq_tail_kernel(
    const int* __restrict__ proto_idx, const float* __restrict__ protos,
    const float* __restrict__ ctxbuf,
    const float* __restrict__ outw, const float* __restrict__ outb,
    const float* __restrict__ ln1g, const float* __restrict__ ln1b,
    const float* __restrict__ ff1w, const float* __restrict__ ff1b,
    const float* __restrict__ ff2w, const float* __restrict__ ff2b,
    const float* __restrict__ ln2g, const float* __restrict__ ln2b,
    const float* __restrict__ clfw, const float* __restrict__ clfb,
    float* __restrict__ out) {
  __shared__ __align__(16) float rowA[OUTD];
  __shared__ __align__(16) float rowB[OUTD];
  __shared__ float lds2[2];
  const int bs = blockIdx.x, t = threadIdx.x;
  const int s = bs % SS;

  rowA[t] = ctxbuf[bs * OUTD + t];
  __syncthreads();
  // out projection
  float a = outb[t];
  {
    const float4* cr = reinterpret_cast<const float4*>(rowA);
    for (int e4 = 0; e4 < 32; e4++) {
      float4 c4 = cr[e4];
      int e = e4 * 4;
      a += c4.x * outw[(e + 0) * OUTD + t] + c4.y * outw[(e + 1) * OUTD + t]
         + c4.z * outw[(e + 2) * OUTD + t] + c4.w * outw[(e + 3) * OUTD + t];
    }
  }
  // h = protoavg + PE, residual
  float hv;
  {
    int i0 = proto_idx[bs * 2], i1 = proto_idx[bs * 2 + 1];
    float pc = 0.5f * (protos[i0 * OUTD + t] + protos[i1 * OUTD + t]);
    float div = expf((float)(2 * (t >> 1)) * C128);
    float ang = (float)s * div;
    float pe = (t & 1) ? cosf(ang) : sinf(ang);
    hv = pc + pe;
  }
  float tmp = hv + a;
  // LN1
  {
    float v = tmp;
#pragma unroll
    for (int k = 32; k >= 1; k >>= 1) v += __shfl_xor(v, k);
    if ((t & 63) == 0) lds2[t >> 6] = v;
    __syncthreads();
    float m = (lds2[0] + lds2[1]) * (1.0f / OUTD);
    __syncthreads();
    float u = tmp - m;
    float w = u * u;
#pragma unroll
    for (int k = 32; k >= 1; k >>= 1) w += __shfl_xor(w, k);
    if ((t & 63) == 0) lds2[t >> 6] = w;
    __syncthreads();
    float var = (lds2[0] + lds2[1]) * (1.0f / OUTD);
    __syncthreads();
    rowA[t] = u * rsqrtf(var + 1e-5f) * ln1g[t] + ln1b[t];
  }
  __syncthreads();
  // ff1 + relu
  {
    float r = ff1b[t];
    const float4* hr = reinterpret_cast<const float4*>(rowA);
    for (int e4 = 0; e4 < 32; e4++) {
      float4 h4 = hr[e4];
      int e = e4 * 4;
      r += h4.x * ff1w[(e + 0) * OUTD + t] + h4.y * ff1w[(e + 1) * OUTD + t]
         + h4.z * ff1w[(e + 2) * OUTD + t] + h4.w * ff1w[(e + 3) * OUTD + t];
    }
    rowB[t] = fmaxf(r, 0.f);
  }
  __syncthreads();
  // ff2 + residual
  float tmp2;
  {
    float r = ff2b[t];
    const float4* cr = reinterpret_cast<const float4*>(rowB);
    for (int e4 = 0; e4 < 32; e4++) {
      float4 c4 = cr[e4];
      int e = e4 * 4;
      r += c4.x * ff2w[(e + 0) * OUTD + t] + c4.y * ff2w[(e + 1) * OUTD + t]
         + c4.z * ff2w[(e + 2) * OUTD + t] + c4.w * ff2w[(e + 3) * OUTD + t];
    }
    tmp2 = rowA[t] + r;
  }
  __syncthreads();
  // LN2
  {
    float v = tmp2;
#pragma unroll
    for (int k = 32; k >= 1; k >>= 1) v += __shfl_xor(v, k);
    if ((t & 63) == 0) lds2[t >> 6] = v;
    __syncthreads();
    float m = (lds2[0] + lds2[1]) * (1.0f / OUTD);
    __syncthreads();
    float u = tmp2 - m;
    float w = u * u;
#pragma unroll
    for (int k = 32; k >= 1; k >>= 1) w += __shfl_xor(w, k);
    if ((t & 63) == 0) lds2[t >> 6] = w;
    __syncthreads();
    float var = (lds2[0] + lds2[1]) * (1.0f / OUTD);
    rowA[t] = u * rsqrtf(var + 1e-5f) * ln2g[t] + ln2b[t];
  }
  __syncthreads();
  // classifier: 5 outputs
  if (t < NCLS) {
    float acc = clfb[t];
    for (int d = 0; d < OUTD; d++) acc += rowA[d] * clfw[d * NCLS + t];
    out[bs * NCLS + t] = acc;
  }
}

extern "C" void kernel_launch(void* const* d_in, const int* in_sizes, int n_in,
                              void* d_out, int out_size, void* d_ws, size_t ws_size,
                              hipStream_t stream) {
  const float* x     = (const float*)d_in[0];
  const float* gum   = (const float*)d_in[1];
  const float* wq    = (const float*)d_in[2];
  const float* wk    = (const float*)d_in[3];
  const float* w1    = (const float*)d_in[4];
  const float* b1    = (const float*)d_in[5];
  const float* bn1g  = (const float*)d_in[6];
  const float* bn1b  = (const float*)d_in[7];
  const float* w2    = (const float*)d_in[8];
  const float* b2    = (const float*)d_in[9];
  const float* bn2g  = (const float*)d_in[10];
  const float* bn2b  = (const float*)d_in[11];
  const float* w3    = (const float*)d_in[12];
  const float* b3    = (const float*)d_in[13];
  const float* bn3g  = (const float*)d_in[14];
  const float* bn3b  = (const float*)d_in[15];
  const float* fcw   = (const float*)d_in[16];
  const float* fcb   = (const float*)d_in[17];
  const float* fc2w  = (const float*)d_in[18];
  const float* fc2b  = (const float*)d_in[19];
  const float* prot  = (const float*)d_in[20];
  const float* inw   = (const float*)d_in[21];
  const float* inb   = (const float*)d_in[22];
  const float* outw  = (const float*)d_in[23];
  const float* outb  = (const float*)d_in[24];
  const float* ln1g  = (const float*)d_in[25];
  const float* ln1b  = (const float*)d_in[26];
  const float* ln2g  = (const float*)d_in[27];
  const float* ln2b  = (const float*)d_in[28];
  const float* ff1w  = (const float*)d_in[29];
  const float* ff1b  = (const float*)d_in[30];
  const float* ff2w  = (const float*)d_in[31];
  const float* ff2b  = (const float*)d_in[32];
  const float* clfw  = (const float*)d_in[33];
  const float* clfb  = (const float*)d_in[34];
  float* out = (float*)d_out;

  int* sec_idx   = (int*)d_ws;
  int* proto_idx = sec_idx + NSAMPLE;
  short* w2hi = (short*)((float*)d_ws + WS_W2HI);
  short* w2lo = (short*)((float*)d_ws + WS_W2LO);
  short* w3hi = (short*)((float*)d_ws + WS_W3HI);
  short* w3lo = (short*)((float*)d_ws + WS_W3LO);
  float* P3   = (float*)d_ws + WS_P3;
  float* c3   = (float*)d_ws + WS_C3;
  float* wqT  = (float*)d_ws + WS_WQT;
  float* vbuf = (float*)d_ws + WS_V;
  float* qkv  = (float*)d_ws + WS_QKV;
  float* ctxb = (float*)d_ws + WS_CTX;

  hipLaunchKernelGGL(prep_all_kernel, dim3(177), dim3(256), 0, stream,
                     w2, w3, w2hi, w2lo, w3hi, w3lo,
                     prot, fc2w, fcw, fcb, fc2b, P3, c3, wq, wqT);
  hipLaunchKernelGGL(attn_b_kernel, dim3(BS / MBX), dim3(512), 0, stream,
                     x, wk, wqT, vbuf);
  hipLaunchKernelGGL(attn_c_kernel, dim3(BS), dim3(192), 0, stream,
                     x, vbuf, gum, sec_idx);
  hipLaunchKernelGGL(conv_kernel, dim3(NSAMPLE), dim3(256), 0, stream,
                     x, sec_idx, w1, b1, bn1g, bn1b, w2hi, w2lo, b2, bn2g, bn2b,
                     w3hi, w3lo, b3, bn3g, bn3b, P3, c3, proto_idx);
  hipLaunchKernelGGL(seq_qkv_kernel, dim3(BS), dim3(384), 0, stream,
                     proto_idx, prot, inw, inb, qkv);
  hipLaunchKernelGGL(seq_attn_kernel, dim3(BB * NHEAD), dim3(256), 0, stream,
                     qkv, ctxb);
  hipLaunchKernelGGL(seq_tail_kernel, dim3(BS), dim3(128), 0, stream,
                     proto_idx, prot, ctxb, outw, outb, ln1g, ln1b,
                     ff1w, ff1b, ff2w, ff2b, ln2g, ln2b, clfw, clfb, out);
}

// Round 11
// 183.058 us; speedup vs baseline: 4.6447x; 1.0078x over previous
//
#include <hip/hip_runtime.h>
#include <math.h>

#define BB 64
#define SS 21
#define NSAMP 3000
#define HID 500
#define SECN 6
#define NN 2
#define OUTD 128
#define NPROTO 25
#define NCLS 5
#define NHEAD 4
#define BS (BB*SS)          // 1344
#define NSAMPLE (BS*NN)     // 2688

#define C500 (-0.0184206807439523674f)   // -ln(1e4)/500
#define C128 (-0.07195578415606439f)     // -ln(1e4)/128
#define LSCALE 0.00745355992499929898f   // 1/(6*sqrt(500))

// ws float offsets
#define WS_W2HI 5376
#define WS_W2LO 8448
#define WS_W3HI 11520
#define WS_W3LO 23808
#define WS_P3   36096
#define WS_C3   55296
#define WS_WQT  55424
#define WS_V    727424
#define WS_QKV  WS_V
#define WS_CTX  (WS_V + 520192)

typedef __attribute__((ext_vector_type(8))) short short8;
typedef __attribute__((ext_vector_type(4))) float floatx4;

__device__ __forceinline__ short f2bf(float f) {
  unsigned u = __float_as_uint(f);
  u += 0x7FFF + ((u >> 16) & 1);          // RNE to bf16
  return (short)(u >> 16);
}
__device__ __forceinline__ float bf2f(short h) {
  return __uint_as_float(((unsigned)(unsigned short)h) << 16);
}

// ---------------- Kernel 0: weight splits (MFMA-fragment order) + VQ prep + wq transpose ----------------
__global__ __launch_bounds__(256) void prep_all_kernel(
    const float* __restrict__ w2, const float* __restrict__ w3,
    short* __restrict__ w2hi, short* __restrict__ w2lo,
    short* __restrict__ w3hi, short* __restrict__ w3lo,
    const float* __restrict__ protos, const float* __restrict__ fc2w,
    const float* __restrict__ fcw, const float* __restrict__ fcb,
    const float* __restrict__ fc2b,
    float* __restrict__ P3, float* __restrict__ c3,
    const float* __restrict__ wq, float* __restrict__ wqT) {
  __shared__ __align__(16) float p2row[256];
  __shared__ float red[256];
  __shared__ float tile[64][65];
  const int t = threadIdx.x;
  if (blockIdx.x < 120) {
    int idx = blockIdx.x * 256 + t;
    if (idx < 6144) {
      int ic = idx & 31, ck = idx >> 5, k = ck % 3, c = ck / 3;
      float v = w2[c * 96 + ic * 3 + k];
      int dst = (((k * 4 + (c >> 4)) * 64) + ((ic >> 3) * 16 + (c & 15))) * 8 + (ic & 7);
      short hi = f2bf(v);
      short lo = f2bf(v - bf2f(hi));
      w2hi[dst] = hi; w2lo[dst] = lo;
    } else if (idx < 30720) {
      int j = idx - 6144;
      int ic = j & 63, ck = j >> 6, k = ck % 3, c = ck / 3;
      float v = w3[(c * 64 + ic) * 3 + k];
      int s = k * 2 + (ic >> 5);
      int dst = (((s * 8 + (c >> 4)) * 64) + (((ic & 31) >> 3) * 16 + (c & 15))) * 8 + (ic & 7);
      short hi = f2bf(v);
      short lo = f2bf(v - bf2f(hi));
      w3hi[dst] = hi; w3lo[dst] = lo;
    }
    return;
  }
  if (blockIdx.x >= 145) {               // wq transpose: 32 tile-blocks
    int tid = blockIdx.x - 145;
    int h0 = (tid >> 2) * 64, c0 = (tid & 3) * 64;
    for (int e = t; e < 4096; e += 256) {
      int i = e >> 6, j = e & 63;
      if (h0 + i < 500) tile[j][i] = wq[(h0 + i) * 256 + c0 + j];
    }
    __syncthreads();
    for (int e = t; e < 4096; e += 256) {
      int c = e >> 6, hh = e & 63;
      if (h0 + hh < 500) wqT[(c0 + c) * 500 + h0 + hh] = tile[c][hh];
    }
    return;
  }
  const int p = blockIdx.x - 120, j = t;
  {
    const float4* pr = reinterpret_cast<const float4*>(protos + p * 128);
    const float4* wr = reinterpret_cast<const float4*>(fc2w + j * 128);
    float4 a4 = make_float4(0.f, 0.f, 0.f, 0.f);
    for (int c4 = 0; c4 < 32; c4++) {
      float4 a = pr[c4], b = wr[c4];
      a4.x += a.x * b.x; a4.y += a.y * b.y; a4.z += a.z * b.z; a4.w += a.w * b.w;
    }
    float v = (a4.x + a4.y) + (a4.z + a4.w);
    p2row[j] = v;
    float contrib = v * fcb[j];
    if (j < 128) {
      float pv = protos[p * 128 + j];
      contrib += pv * fc2b[j] - 0.5f * pv * pv;
    }
    red[j] = contrib;
  }
  __syncthreads();
  for (int s = 128; s > 0; s >>= 1) {
    if (j < s) red[j] += red[j + s];
    __syncthreads();
  }
  if (j == 0) c3[p] = red[0];
  for (int k = j; k < 768; k += 256) {
    const float4* fr = reinterpret_cast<const float4*>(fcw + k * 256);
    const float4* p2 = reinterpret_cast<const float4*>(p2row);
    float4 a4 = make_float4(0.f, 0.f, 0.f, 0.f);
    for (int j4 = 0; j4 < 64; j4++) {
      float4 a = p2[j4], b = fr[j4];
      a4.x += a.x * b.x; a4.y += a.y * b.y; a4.z += a.z * b.z; a4.w += a.w * b.w;
    }
    P3[p * 768 + k] = (a4.x + a4.y) + (a4.z + a4.w);
  }
}

// ---------------- Kernel 1b: fused xsum -> ks -> v (4 samples/block, 336 blocks, K-split) ----------------
#define MBX 4
__global__ __launch_bounds__(512) void attn_b_kernel(
    const float* __restrict__ x, const float* __restrict__ wk,
    const float* __restrict__ wqT, float* __restrict__ v) {
  __shared__ __align__(16) float pesum[500];
  __shared__ __align__(16) float xs[MBX * 500];
  __shared__ __align__(16) float ksp[2 * 256 * MBX];
  __shared__ __align__(16) float ks_t[256 * MBX];
  const int blk = blockIdx.x, t = threadIdx.x;

  if (t < 125) {
    float div0 = expf((float)(4 * t) * C500);
    float div1 = expf((float)(4 * t + 2) * C500);
    float s0 = 0.f, c0 = 0.f, s1 = 0.f, c1 = 0.f;
#pragma unroll
    for (int s = 0; s < SECN; s++) {
      float a0 = (float)s * div0, a1 = (float)s * div1;
      s0 += sinf(a0); c0 += cosf(a0);
      s1 += sinf(a1); c1 += cosf(a1);
    }
    reinterpret_cast<float4*>(pesum)[t] = make_float4(s0, c0, s1, c1);
  }
  __syncthreads();

  for (int e = t; e < MBX * 125; e += 512) {
    int m = e / 125, h4 = e % 125;
    const float4* xr = reinterpret_cast<const float4*>(x) + (blk * MBX + m) * 750;
    float4 a = xr[h4];
#pragma unroll
    for (int s = 1; s < SECN; s++) {
      float4 b = xr[s * 125 + h4];
      a.x += b.x; a.y += b.y; a.z += b.z; a.w += b.w;
    }
    float4 pe = reinterpret_cast<float4*>(pesum)[h4];
    a.x += pe.x; a.y += pe.y; a.z += pe.z; a.w += pe.w;
    reinterpret_cast<float4*>(xs)[m * 125 + h4] = a;
  }
  __syncthreads();

  {
    int c = t & 255, kh = t >> 8;
    float acc[MBX];
#pragma unroll
    for (int m = 0; m < MBX; m++) acc[m] = 0.f;
    int b4 = kh ? 63 : 0, e4 = kh ? 125 : 63;
    const float4* xsb = reinterpret_cast<const float4*>(xs);
    for (int i4 = b4; i4 < e4; i4++) {
      int i = i4 * 4;
      float w0 = wk[(i + 0) * 256 + c];
      float w1 = wk[(i + 1) * 256 + c];
      float w2 = wk[(i + 2) * 256 + c];
      float w3 = wk[(i + 3) * 256 + c];
#pragma unroll
      for (int m = 0; m < MBX; m++) {
        float4 xv = xsb[m * 125 + i4];
        acc[m] += xv.x * w0 + xv.y * w1 + xv.z * w2 + xv.w * w3;
      }
    }
#pragma unroll
    for (int m = 0; m < MBX; m++)
      ksp[(kh * 256 + c) * MBX + m] = acc[m];
  }
  __syncthreads();
  for (int e = t; e < 256 * MBX; e += 512) ks_t[e] = ksp[e] + ksp[256 * MBX + e];
  __syncthreads();

  if (t < 500) {
    int h = t;
#pragma unroll
    for (int n = 0; n < 2; n++) {
      float acc[MBX];
#pragma unroll
      for (int m = 0; m < MBX; m++) acc[m] = 0.f;
      const float* wcol = wqT + (n * 128) * 500 + h;
      const floatx4* ktb = (const floatx4*)ks_t + n * 128;
      for (int c = 0; c < 128; c++) {
        float w = wcol[c * 500];
        floatx4 k0 = ktb[c];
        acc[0] += w * k0[0]; acc[1] += w * k0[1]; acc[2] += w * k0[2]; acc[3] += w * k0[3];
      }
#pragma unroll
      for (int m = 0; m < MBX; m++)
        v[((blk * MBX + m) * 2 + n) * 500 + h] = acc[m];
    }
  }
}

// ---------------- Kernel 1c: logits = (x+pe).v + gumbel -> argmax ----------------
__global__ __launch_bounds__(192) void attn_c_kernel(
    const float* __restrict__ x, const float* __restrict__ v,
    const float* __restrict__ gumbel, int* __restrict__ sec_idx) {
  __shared__ float lgsh[NN][SECN];
  const int bs = blockIdx.x, t = threadIdx.x;
  const int s = t >> 5, lane = t & 31;
  const float4* x4 = reinterpret_cast<const float4*>(x) + bs * 750 + s * 125;
  const float4* v0 = reinterpret_cast<const float4*>(v) + bs * 250;
  const float4* v1 = v0 + 125;
  float a0 = 0.f, a1 = 0.f;
  for (int h4 = lane; h4 < 125; h4 += 32) {
    float4 xv = x4[h4];
    float div0 = expf((float)(4 * h4) * C500);
    float div1 = expf((float)(4 * h4 + 2) * C500);
    float ang0 = (float)s * div0, ang1 = (float)s * div1;
    xv.x += sinf(ang0); xv.y += cosf(ang0);
    xv.z += sinf(ang1); xv.w += cosf(ang1);
    float4 w0 = v0[h4], w1 = v1[h4];
    a0 += xv.x * w0.x + xv.y * w0.y + xv.z * w0.z + xv.w * w0.w;
    a1 += xv.x * w1.x + xv.y * w1.y + xv.z * w1.z + xv.w * w1.w;
  }
#pragma unroll
  for (int m = 16; m >= 1; m >>= 1) {
    a0 += __shfl_xor(a0, m);
    a1 += __shfl_xor(a1, m);
  }
  if (lane == 0) {
    lgsh[0][s] = a0 * LSCALE + gumbel[(bs * 2 + 0) * SECN + s];
    lgsh[1][s] = a1 * LSCALE + gumbel[(bs * 2 + 1) * SECN + s];
  }
  __syncthreads();
  if (t < 2) {
    int best = 0; float bv = lgsh[t][0];
    for (int i = 1; i < SECN; i++) {
      float q = lgsh[t][i];
      if (q > bv) { bv = q; best = i; }
    }
    sec_idx[bs * 2 + t] = best;
  }
}

// ---------------- Kernel 2: conv encoder (MFMA, 8 waves/block) + VQ ----------------
// Same LDS layout as R10 (proven); work remapped across 512 threads.
#define CONV_LDS 53568
__global__ __launch_bounds__(512, 6) void conv_kernel(
    const float* __restrict__ x, const int* __restrict__ sec_idx,
    const float* __restrict__ w1, const float* __restrict__ b1,
    const float* __restrict__ bn1g, const float* __restrict__ bn1b,
    const short* __restrict__ w2hi, const short* __restrict__ w2lo,
    const float* __restrict__ b2,
    const float* __restrict__ bn2g, const float* __restrict__ bn2b,
    const short* __restrict__ w3hi, const short* __restrict__ w3lo,
    const float* __restrict__ b3,
    const float* __restrict__ bn3g, const float* __restrict__ bn3b,
    const float* __restrict__ P3, const float* __restrict__ c3,
    int* __restrict__ proto_idx) {
  __shared__ __align__(16) char smem[CONV_LDS];
  short* act1_hi  = (short*)smem;               // [130][40]
  short* act1_lo  = (short*)(smem + 10400);     // [130][40]
  short* act2p_hi = (short*)smem;               // [34][72]
  short* act2p_lo = (short*)(smem + 4896);      // [34][72]
  float* featsh   = (float*)(smem + 9792);      // [768] (alias, phases 6-7)
  float* sc25     = (float*)(smem + 12864);     // [25]
  float* in0p  = (float*)(smem + 20800);        // [512]
  float* act2t = (float*)(smem + 20800);        // [128][64] swizzled
  float* act3t = (float*)(smem + 20800);        // [32][132]

  const int sample = blockIdx.x;
  const int t = threadIdx.x;
  const int bsIdx = sample >> 1;
  const float bnscale = rsqrtf(1.0f + 1e-5f);
  const int wv = t >> 6, l = t & 63, lr = l & 15, lg2 = l >> 4;

  // ---- phase 1: load x section (padded), zero act1 pad rows ----
  {
    int sec = sec_idx[sample];
    const float* src = &x[bsIdx * NSAMP + sec * HID];
    if (t < 512) in0p[t] = (t >= 1 && t <= 500) ? src[t - 1] : 0.f;
    if (t < 200) {
      int r = t / 40; r = (r == 0) ? 0 : 125 + r;   // rows 0,126..129
      int idx = r * 40 + t % 40;
      act1_hi[idx] = 0; act1_lo[idx] = 0;
    }
  }
  __syncthreads();

  // ---- phase 2: conv1 + relu + pool4 + bn -> act1 hi/lo bf16 [pos+1][ic] ----
  {
    int ic = t & 31;
    float w0 = w1[ic * 3], w1v = w1[ic * 3 + 1], w2v = w1[ic * 3 + 2];
    float bb = b1[ic];
    float g = bn1g[ic] * bnscale, be = bn1b[ic];
    for (int p = t >> 5; p < 125; p += 16) {
      int base = 4 * p;
      float xm1 = in0p[base], x0 = in0p[base + 1], x1 = in0p[base + 2],
            x2 = in0p[base + 3], x3 = in0p[base + 4], x4 = in0p[base + 5];
      float a0 = bb + w0 * xm1 + w1v * x0 + w2v * x1;
      float a1 = bb + w0 * x0  + w1v * x1 + w2v * x2;
      float a2 = bb + w0 * x1  + w1v * x2 + w2v * x3;
      float a3 = bb + w0 * x2  + w1v * x3 + w2v * x4;
      float m = fmaxf(fmaxf(fmaxf(fmaxf(a0, a1), a2), a3), 0.f);
      float v = m * g + be;
      short hi = f2bf(v);
      short lo = f2bf(v - bf2f(hi));
      act1_hi[(p + 1) * 40 + ic] = hi;
      act1_lo[(p + 1) * 40 + ic] = lo;
    }
  }
  __syncthreads();

  // ---- phase 3: conv2 MFMA — wave wv owns pos-tile wv (16 pos), all 64 ch ----
  {
    floatx4 acc[4];
#pragma unroll
    for (int m = 0; m < 4; m++) acc[m] = (floatx4){0.f, 0.f, 0.f, 0.f};
#pragma unroll
    for (int s = 0; s < 3; s++) {
      short8 Ah[4], Al[4], Bh, Bl;
#pragma unroll
      for (int m = 0; m < 4; m++) {
        int aoff = ((s * 4 + m) * 64 + l) * 8;
        Ah[m] = *(const short8*)(w2hi + aoff);
        Al[m] = *(const short8*)(w2lo + aoff);
      }
      {
        int boff = (wv * 16 + lr + s) * 40 + lg2 * 8;
        Bh = *(const short8*)(act1_hi + boff);
        Bl = *(const short8*)(act1_lo + boff);
      }
#pragma unroll
      for (int m = 0; m < 4; m++) {
        acc[m] = __builtin_amdgcn_mfma_f32_16x16x32_bf16(Ah[m], Bh, acc[m], 0, 0, 0);
        acc[m] = __builtin_amdgcn_mfma_f32_16x16x32_bf16(Ah[m], Bl, acc[m], 0, 0, 0);
        acc[m] = __builtin_amdgcn_mfma_f32_16x16x32_bf16(Al[m], Bh, acc[m], 0, 0, 0);
      }
    }
    // swizzled store: element (pos p, ch m*16+lg2*4+j) at p*64 + ((m*4+lg2)^(p&15))*4 + j
#pragma unroll
    for (int m = 0; m < 4; m++) {
      int p = wv * 16 + lr;
      int swz = (m * 4 + lg2) ^ lr;    // p&15 == lr
      *(floatx4*)(act2t + p * 64 + swz * 4) = acc[m];
    }
  }
  __syncthreads();

  // ---- phase 4: pool5 + bias + relu + bn -> act2p hi/lo; zero pads ----
  {
    if (t < 162) {
      for (int i = t; i < 648; i += 162) {
        int r = i / 72; r = (r == 0) ? 0 : 25 + r;
        int idx = r * 72 + i % 72;
        act2p_hi[idx] = 0; act2p_lo[idx] = 0;
      }
    }
    int ic = t & 63;
    float bb = b2[ic], g = bn2g[ic] * bnscale, be = bn2b[ic];
#define A2T(r, c) act2t[(r) * 64 + ((((c) >> 2) ^ ((r) & 15)) << 2) + ((c) & 3)]
    for (int pw = t >> 6; pw < 25; pw += 8) {
      int base = 5 * pw;
      float m = A2T(base, ic);
      m = fmaxf(m, A2T(base + 1, ic));
      m = fmaxf(m, A2T(base + 2, ic));
      m = fmaxf(m, A2T(base + 3, ic));
      m = fmaxf(m, A2T(base + 4, ic));
      float v = fmaxf(m + bb, 0.f) * g + be;
      short hi = f2bf(v);
      short lo = f2bf(v - bf2f(hi));
      act2p_hi[(pw + 1) * 72 + ic] = hi;
      act2p_lo[(pw + 1) * 72 + ic] = lo;
    }
#undef A2T
  }
  __syncthreads();

  // ---- phase 5: conv3 MFMA — wave wv owns ch-group wv (16 ch), 2 pos-tiles ----
  {
    floatx4 acc[2];
#pragma unroll
    for (int nn = 0; nn < 2; nn++) acc[nn] = (floatx4){0.f, 0.f, 0.f, 0.f};
#pragma unroll
    for (int s = 0; s < 6; s++) {
      short8 Ah, Al, Bh[2], Bl[2];
      {
        int aoff = ((s * 8 + wv) * 64 + l) * 8;
        Ah = *(const short8*)(w3hi + aoff);
        Al = *(const short8*)(w3lo + aoff);
      }
#pragma unroll
      for (int nn = 0; nn < 2; nn++) {
        int boff = (nn * 16 + lr + (s >> 1)) * 72 + (s & 1) * 32 + lg2 * 8;
        Bh[nn] = *(const short8*)(act2p_hi + boff);
        Bl[nn] = *(const short8*)(act2p_lo + boff);
      }
#pragma unroll
      for (int nn = 0; nn < 2; nn++) {
        acc[nn] = __builtin_amdgcn_mfma_f32_16x16x32_bf16(Ah, Bh[nn], acc[nn], 0, 0, 0);
        acc[nn] = __builtin_amdgcn_mfma_f32_16x16x32_bf16(Ah, Bl[nn], acc[nn], 0, 0, 0);
        acc[nn] = __builtin_amdgcn_mfma_f32_16x16x32_bf16(Al, Bh[nn], acc[nn], 0, 0, 0);
      }
    }
#pragma unroll
    for (int nn = 0; nn < 2; nn++) {
      int p = nn * 16 + lr;
      *(floatx4*)(act3t + p * 132 + wv * 16 + lg2 * 4) = acc[nn];
    }
  }
  __syncthreads();

  // ---- phase 6: pool4(first 24) + bias + relu + bn -> featsh (LDS) ----
  {
    int c = t & 127;
    float bb = b3[c], g = bn3g[c] * bnscale, be = bn3b[c];
    for (int pw = t >> 7; pw < 6; pw += 4) {
      int base = 4 * pw;
      float m = act3t[base * 132 + c];
      m = fmaxf(m, act3t[(base + 1) * 132 + c]);
      m = fmaxf(m, act3t[(base + 2) * 132 + c]);
      m = fmaxf(m, act3t[(base + 3) * 132 + c]);
      float v = fmaxf(m + bb, 0.f) * g + be;
      featsh[c * 6 + pw] = v;
    }
  }
  __syncthreads();

  // ---- phase 7: folded VQ scores + argmax -> proto_idx ----
  if (t < NPROTO * 8) {
    int p = t >> 3, part = t & 7;
    const float4* pr = reinterpret_cast<const float4*>(P3 + p * 768 + part * 96);
    const float4* fr = reinterpret_cast<const float4*>(featsh + part * 96);
    float4 a4 = make_float4(0.f, 0.f, 0.f, 0.f);
#pragma unroll
    for (int i = 0; i < 24; i++) {
      float4 w = pr[i], f = fr[i];
      a4.x += w.x * f.x; a4.y += w.y * f.y; a4.z += w.z * f.z; a4.w += w.w * f.w;
    }
    float a = (a4.x + a4.y) + (a4.z + a4.w);
    a += __shfl_xor(a, 1);
    a += __shfl_xor(a, 2);
    a += __shfl_xor(a, 4);
    if (part == 0) sc25[p] = a + c3[p];
  }
  __syncthreads();
  if (t == 0) {
    int best = 0; float bv = sc25[0];
    for (int i = 1; i < NPROTO; i++) {
      float v = sc25[i];
      if (v > bv) { bv = v; best = i; }
    }
    proto_idx[sample] = best;
  }
}

// ---------------- Kernel 3a: qkv GEMV per (b,s) row ----------------
__global__ __launch_bounds__(384) void seq_qkv_kernel(
    const int* __restrict__ proto_idx, const float* __restrict__ protos,
    const float* __restrict__ inw, const float* __restrict__ inb,
    float* __restrict__ qkv) {
  __shared__ __align__(16) float hrow[OUTD];
  const int bs = blockIdx.x, t = threadIdx.x;
  const int s = bs % SS;
  if (t < OUTD) {
    int i0 = proto_idx[bs * 2], i1 = proto_idx[bs * 2 + 1];
    float pc = 0.5f * (protos[i0 * OUTD + t] + protos[i1 * OUTD + t]);
    float div = expf((float)(2 * (t >> 1)) * C128);
    float ang = (float)s * div;
    float pe = (t & 1) ? cosf(ang) : sinf(ang);
    hrow[t] = pc + pe;
  }
  __syncthreads();
  float a = inb[t];
  const float4* hr = reinterpret_cast<const float4*>(hrow);
  for (int d4 = 0; d4 < 32; d4++) {
    float4 h4 = hr[d4];
    int d = d4 * 4;
    a += h4.x * inw[(d + 0) * 384 + t] + h4.y * inw[(d + 1) * 384 + t]
       + h4.z * inw[(d + 2) * 384 + t] + h4.w * inw[(d + 3) * 384 + t];
  }
  qkv[bs * 384 + t] = a;
}

// ---------------- Kernel 3b: attention per (b, head) ----------------
__global__ __launch_bounds__(256) void seq_attn_kernel(
    const float* __restrict__ qkv, float* __restrict__ ctxbuf) {
  __shared__ float qs_[SS][32], ks_[SS][32], vs_[SS][32];
  __shared__ float sc_[SS][SS + 1];
  const int b = blockIdx.x >> 2, hd = blockIdx.x & 3;
  const int t = threadIdx.x;
  for (int e = t; e < SS * 32; e += 256) {
    int s = e >> 5, dd = e & 31;
    const float* base = qkv + (b * SS + s) * 384 + hd * 32 + dd;
    qs_[s][dd] = base[0];
    ks_[s][dd] = base[128];
    vs_[s][dd] = base[256];
  }
  __syncthreads();
  for (int e = t; e < SS * SS; e += 256) {
    int qs = e / SS, ks = e % SS;
    float a = 0.f;
#pragma unroll
    for (int d = 0; d < 32; d++) a += qs_[qs][d] * ks_[ks][d];
    sc_[qs][ks] = a * 0.17677669529663689f;
  }
  __syncthreads();
  if (t < SS) {
    float mx = sc_[t][0];
    for (int i = 1; i < SS; i++) mx = fmaxf(mx, sc_[t][i]);
    float sum = 0.f;
    for (int i = 0; i < SS; i++) { float e = expf(sc_[t][i] - mx); sc_[t][i] = e; sum += e; }
    float inv = 1.f / sum;
    for (int i = 0; i < SS; i++) sc_[t][i] *= inv;
  }
  __syncthreads();
  for (int e = t; e < SS * 32; e += 256) {
    int qs = e >> 5, dd = e & 31;
    float a = 0.f;
#pragma unroll
    for (int ks = 0; ks < SS; ks++) a += sc_[qs][ks] * vs_[ks][dd];
    ctxbuf[(b * SS + qs) * OUTD + hd * 32 + dd] = a;
  }
}

// ---------------- Kernel 3c: out proj + LN1 + FF + LN2 + classifier per (b,s) row ----------------
__global__ __launch_bounds__(128) void seq_tail_kernel(
    const int* __restrict__ proto_idx, const float* __restrict__ protos,
    const float* __restrict__ ctxbuf,
    const float* __restrict__ outw, const float* __restrict__ outb,
    const float* __restrict__ ln1g, const float* __restrict__ ln1b,
    const float* __restrict__ ff1w, const float* __restrict__ ff1b,
    const float* __restrict__ ff2w, const float* __restrict__ ff2b,
    const float* __restrict__ ln2g, const float* __restrict__ ln2b,
    const float* __restrict__ clfw, const float* __restrict__ clfb,
    float* __restrict__ out) {
  __shared__ __align__(16) float rowA[OUTD];
  __shared__ __align__(16) float rowB[OUTD];
  __shared__ float lds2[2];
  const int bs = blockIdx.x, t = threadIdx.x;
  const int s = bs % SS;

  rowA[t] = ctxbuf[bs * OUTD + t];
  __syncthreads();
  float a = outb[t];
  {
    const float4* cr = reinterpret_cast<const float4*>(rowA);
    for (int e4 = 0; e4 < 32; e4++) {
      float4 c4 = cr[e4];
      int e = e4 * 4;
      a += c4.x * outw[(e + 0) * OUTD + t] + c4.y * outw[(e + 1) * OUTD + t]
         + c4.z * outw[(e + 2) * OUTD + t] + c4.w * outw[(e + 3) * OUTD + t];
    }
  }
  float hv;
  {
    int i0 = proto_idx[bs * 2], i1 = proto_idx[bs * 2 + 1];
    float pc = 0.5f * (protos[i0 * OUTD + t] + protos[i1 * OUTD + t]);
    float div = expf((float)(2 * (t >> 1)) * C128);
    float ang = (float)s * div;
    float pe = (t & 1) ? cosf(ang) : sinf(ang);
    hv = pc + pe;
  }
  float tmp = hv + a;
  {
    float v = tmp;
#pragma unroll
    for (int k = 32; k >= 1; k >>= 1) v += __shfl_xor(v, k);
    if ((t & 63) == 0) lds2[t >> 6] = v;
    __syncthreads();
    float m = (lds2[0] + lds2[1]) * (1.0f / OUTD);
    __syncthreads();
    float u = tmp - m;
    float w = u * u;
#pragma unroll
    for (int k = 32; k >= 1; k >>= 1) w += __shfl_xor(w, k);
    if ((t & 63) == 0) lds2[t >> 6] = w;
    __syncthreads();
    float var = (lds2[0] + lds2[1]) * (1.0f / OUTD);
    __syncthreads();
    rowA[t] = u * rsqrtf(var + 1e-5f) * ln1g[t] + ln1b[t];
  }
  __syncthreads();
  {
    float r = ff1b[t];
    const float4* hr = reinterpret_cast<const float4*>(rowA);
    for (int e4 = 0; e4 < 32; e4++) {
      float4 h4 = hr[e4];
      int e = e4 * 4;
      r += h4.x * ff1w[(e + 0) * OUTD + t] + h4.y * ff1w[(e + 1) * OUTD + t]
         + h4.z * ff1w[(e + 2) * OUTD + t] + h4.w * ff1w[(e + 3) * OUTD + t];
    }
    rowB[t] = fmaxf(r, 0.f);
  }
  __syncthreads();
  float tmp2;
  {
    float r = ff2b[t];
    const float4* cr = reinterpret_cast<const float4*>(rowB);
    for (int e4 = 0; e4 < 32; e4++) {
      float4 c4 = cr[e4];
      int e = e4 * 4;
      r += c4.x * ff2w[(e + 0) * OUTD + t] + c4.y * ff2w[(e + 1) * OUTD + t]
         + c4.z * ff2w[(e + 2) * OUTD + t] + c4.w * ff2w[(e + 3) * OUTD + t];
    }
    tmp2 = rowA[t] + r;
  }
  __syncthreads();
  {
    float v = tmp2;
#pragma unroll
    for (int k = 32; k >= 1; k >>= 1) v += __shfl_xor(v, k);
    if ((t & 63) == 0) lds2[t >> 6] = v;
    __syncthreads();
    float m = (lds2[0] + lds2[1]) * (1.0f / OUTD);
    __syncthreads();
    float u = tmp2 - m;
    float w = u * u;
#pragma unroll
    for (int k = 32; k >= 1; k >>= 1) w += __shfl_xor(w, k);
    if ((t & 63) == 0) lds2[t >> 6] = w;
    __syncthreads();
    float var = (lds2[0] + lds2[1]) * (1.0f / OUTD);
    rowA[t] = u * rsqrtf(var + 1e-5f) * ln2g[t] + ln2b[t];
  }
  __syncthreads();
  if (t < NCLS) {
    float acc = clfb[t];
    for (int d = 0; d < OUTD; d++) acc += rowA[d] * clfw[d * NCLS + t];
    out[bs * NCLS + t] = acc;
  }
}

extern "C" void kernel_launch(void* const* d_in, const int* in_sizes, int n_in,
                              void* d_out, int out_size, void* d_ws, size_t ws_size,
                              hipStream_t stream) {
  const float* x     = (const float*)d_in[0];
  const float* gum   = (const float*)d_in[1];
  const float* wq    = (const float*)d_in[2];
  const float* wk    = (const float*)d_in[3];
  const float* w1    = (const float*)d_in[4];
  const float* b1    = (const float*)d_in[5];
  const float* bn1g  = (const float*)d_in[6];
  const float* bn1b  = (const float*)d_in[7];
  const float* w2    = (const float*)d_in[8];
  const float* b2    = (const float*)d_in[9];
  const float* bn2g  = (const float*)d_in[10];
  const float* bn2b  = (const float*)d_in[11];
  const float* w3    = (const float*)d_in[12];
  const float* b3    = (const float*)d_in[13];
  const float* bn3g  = (const float*)d_in[14];
  const float* bn3b  = (const float*)d_in[15];
  const float* fcw   = (const float*)d_in[16];
  const float* fcb   = (const float*)d_in[17];
  const float* fc2w  = (const float*)d_in[18];
  const float* fc2b  = (const float*)d_in[19];
  const float* prot  = (const float*)d_in[20];
  const float* inw   = (const float*)d_in[21];
  const float* inb   = (const float*)d_in[22];
  const float* outw  = (const float*)d_in[23];
  const float* outb  = (const float*)d_in[24];
  const float* ln1g  = (const float*)d_in[25];
  const float* ln1b  = (const float*)d_in[26];
  const float* ln2g  = (const float*)d_in[27];
  const float* ln2b  = (const float*)d_in[28];
  const float* ff1w  = (const float*)d_in[29];
  const float* ff1b  = (const float*)d_in[30];
  const float* ff2w  = (const float*)d_in[31];
  const float* ff2b  = (const float*)d_in[32];
  const float* clfw  = (const float*)d_in[33];
  const float* clfb  = (const float*)d_in[34];
  float* out = (float*)d_out;

  int* sec_idx   = (int*)d_ws;
  int* proto_idx = sec_idx + NSAMPLE;
  short* w2hi = (short*)((float*)d_ws + WS_W2HI);
  short* w2lo = (short*)((float*)d_ws + WS_W2LO);
  short* w3hi = (short*)((float*)d_ws + WS_W3HI);
  short* w3lo = (short*)((float*)d_ws + WS_W3LO);
  float* P3   = (float*)d_ws + WS_P3;
  float* c3   = (float*)d_ws + WS_C3;
  float* wqT  = (float*)d_ws + WS_WQT;
  float* vbuf = (float*)d_ws + WS_V;
  float* qkv  = (float*)d_ws + WS_QKV;
  float* ctxb = (float*)d_ws + WS_CTX;

  hipLaunchKernelGGL(prep_all_kernel, dim3(177), dim3(256), 0, stream,
                     w2, w3, w2hi, w2lo, w3hi, w3lo,
                     prot, fc2w, fcw, fcb, fc2b, P3, c3, wq, wqT);
  hipLaunchKernelGGL(attn_b_kernel, dim3(BS / MBX), dim3(512), 0, stream,
                     x, wk, wqT, vbuf);
  hipLaunchKernelGGL(attn_c_kernel, dim3(BS), dim3(192), 0, stream,
                     x, vbuf, gum, sec_idx);
  hipLaunchKernelGGL(conv_kernel, dim3(NSAMPLE), dim3(512), 0, stream,
                     x, sec_idx, w1, b1, bn1g, bn1b, w2hi, w2lo, b2, bn2g, bn2b,
                     w3hi, w3lo, b3, bn3g, bn3b, P3, c3, proto_idx);
  hipLaunchKernelGGL(seq_qkv_kernel, dim3(BS), dim3(384), 0, stream,
                     proto_idx, prot, inw, inb, qkv);
  hipLaunchKernelGGL(seq_attn_kernel, dim3(BB * NHEAD), dim3(256), 0, stream,
                     qkv, ctxb);
  hipLaunchKernelGGL(seq_tail_kernel, dim3(BS), dim3(128), 0, stream,
                     proto_idx, prot, ctxb, outw, outb, ln1g, ln1b,
                     ff1w, ff1b, ff2w, ff2b, ln2g, ln2b, clfw, clfb, out);
}